// Round 7
// baseline (650.012 us; speedup 1.0000x reference)
//
#include <hip/hip_runtime.h>
#include <math.h>

// Problem constants
static constexpr int Bn    = 4;
static constexpr int Cc    = 128;
static constexpr int Hh    = 128;
static constexpr int Wb    = 128;
static constexpr int Nn    = Hh * Wb;      // 16384
static constexpr int HEADS = 8;
static constexpr int CHh   = 16;
static constexpr int HID   = 340;
static constexpr int HID2  = 680;
static constexpr int NS    = 64;
static constexpr int MPAD  = 704;          // pin M padded (680 -> 44*16)
static constexpr int KPAD2 = 352;          // pout K padded (340 -> 11*32)

typedef unsigned short ushort_t;
typedef __attribute__((ext_vector_type(8))) short short8;
typedef __attribute__((ext_vector_type(4))) float f32x4;

__device__ __forceinline__ ushort_t f2bf(float f) {
    unsigned u = __float_as_uint(f);
    return (ushort_t)((u + 0x7FFFu + ((u >> 16) & 1u)) >> 16);   // RNE
}
__device__ __forceinline__ float bf2f(ushort_t h) {
    return __uint_as_float(((unsigned)h) << 16);
}

// fast tanh: tanh(x) = 1 - 2/(e^{2|x|}+1), sign-restored.
__device__ __forceinline__ float fast_tanh(float x) {
    float a = fabsf(x);
    a = fminf(a, 12.0f);
    float e = __expf(2.0f * a);
    float r = 1.0f - 2.0f * __builtin_amdgcn_rcpf(e + 1.0f);
    return x < 0.0f ? -r : r;
}

// ---------------------------------------------------------------------------
// v8 LDS layouts (all aligned b128; 8-px strips -> lane stride 32 B = 2-way
// bank alias, free on CDNA4):
//   ts[t][20][136]: ts[t][i][c] = t_t(gy0-2+i, c-4); data c=4..131, zeros
//                   c=0..3, 132..135.
//   us[t][18][132]: us[t][i][j] = u_t(gy0-1+i, j-1); j=0..131, u zero-forced
//                   outside gx in [0,127].
// ---------------------------------------------------------------------------

// ---------------------------------------------------------------------------
// LayerNorm over channel axis, f32 out (tier-2). grid: (Nn/256, 1, Bt).
// ---------------------------------------------------------------------------
__global__ __launch_bounds__(256) void ln_kernel(const float* __restrict__ in,
                                                 const float* __restrict__ w,
                                                 const float* __restrict__ bias,
                                                 float* __restrict__ out) {
    int p = blockIdx.x * 256 + threadIdx.x;
    int b = blockIdx.z;
    const float* ib = in + (size_t)b * Cc * Nn + p;
    float s = 0.f, s2 = 0.f;
    #pragma unroll 8
    for (int c = 0; c < Cc; ++c) {
        float v = ib[(size_t)c * Nn];
        s += v; s2 += v * v;
    }
    float mean = s * (1.0f / Cc);
    float var  = s2 * (1.0f / Cc) - mean * mean;
    float inv  = 1.0f / sqrtf(var + 1e-6f);
    float* ob = out + (size_t)b * Cc * Nn + p;
    #pragma unroll 8
    for (int c = 0; c < Cc; ++c) {
        float v = ib[(size_t)c * Nn];
        ob[(size_t)c * Nn] = w[c] * ((v - mean) * inv) + bias[c];
    }
}

// LayerNorm writing bf16 (feeds MFMA GEMMs).
__global__ __launch_bounds__(256) void ln_bf16_kernel(const float* __restrict__ in,
                                                      const float* __restrict__ w,
                                                      const float* __restrict__ bias,
                                                      ushort_t* __restrict__ out) {
    int p = blockIdx.x * 256 + threadIdx.x;
    int b = blockIdx.z;
    const float* ib = in + (size_t)b * Cc * Nn + p;
    float s = 0.f, s2 = 0.f;
    #pragma unroll 8
    for (int c = 0; c < Cc; ++c) {
        float v = ib[(size_t)c * Nn];
        s += v; s2 += v * v;
    }
    float mean = s * (1.0f / Cc);
    float var  = s2 * (1.0f / Cc) - mean * mean;
    float inv  = 1.0f / sqrtf(var + 1e-6f);
    ushort_t* ob = out + (size_t)b * Cc * Nn + p;
    #pragma unroll 8
    for (int c = 0; c < Cc; ++c) {
        float v = ib[(size_t)c * Nn];
        ob[(size_t)c * Nn] = f2bf(w[c] * ((v - mean) * inv) + bias[c]);
    }
}

// ---------------------------------------------------------------------------
// Weight conversion f32 -> bf16 (+ padding variants).
// ---------------------------------------------------------------------------
__global__ __launch_bounds__(256) void wconv_pad_rows_kernel(const float* __restrict__ w,
                                                             ushort_t* __restrict__ o,
                                                             int rows, int K) {
    int idx = blockIdx.x * 256 + threadIdx.x;
    int r = idx / K, k = idx - r * K;
    o[idx] = (r < rows) ? f2bf(w[(size_t)r * K + k]) : (ushort_t)0;
}
__global__ __launch_bounds__(256) void wconv_pad_cols_kernel(const float* __restrict__ w,
                                                             ushort_t* __restrict__ o,
                                                             int K, int Kp) {
    int idx = blockIdx.x * 256 + threadIdx.x;
    int r = idx / Kp, k = idx - r * Kp;
    o[idx] = (k < K) ? f2bf(w[(size_t)r * K + k]) : (ushort_t)0;
}

// Zero a small f32 buffer (for ssq atomics).
__global__ __launch_bounds__(256) void zero_f32_kernel(float* __restrict__ p, int n) {
    int i = blockIdx.x * 256 + threadIdx.x;
    if (i < n) p[i] = 0.f;
}

// ---------------------------------------------------------------------------
// bf16 MFMA GEMM v2: out[b,co,p] = sum_ci W[co,ci] * Z[b,ci,p]
// ---------------------------------------------------------------------------
__global__ __launch_bounds__(256) void gemm_bf16_kernel(const ushort_t* __restrict__ Zh,
                                                        const ushort_t* __restrict__ Wh,
                                                        const float* __restrict__ bias,
                                                        const float* __restrict__ res,
                                                        float* outf,
                                                        ushort_t* outh,
                                                        int Cin, int Kpad, int Mreal,
                                                        int act) {
    const int b    = blockIdx.z;
    const int px0  = blockIdx.x * 128;
    const int co0  = blockIdx.y * 64;
    const int tid  = threadIdx.x;
    const int wv   = tid >> 6;
    const int lane = tid & 63;
    const int n    = lane & 15;
    const int q    = lane >> 4;

    __shared__ ushort_t Bl[128][40];

    const ushort_t* Zb = Zh + (size_t)b * Cin * Nn;

    f32x4 acc[4][2];
    #pragma unroll
    for (int i = 0; i < 4; ++i)
        #pragma unroll
        for (int j = 0; j < 2; ++j) acc[i][j] = (f32x4){0.f, 0.f, 0.f, 0.f};

    for (int k0 = 0; k0 < Kpad; k0 += 32) {
        {
            int r = tid >> 3;        // k row 0..31
            int s = tid & 7;         // 16-px chunk
            int ci = k0 + r;
            ushort_t tmp[16];
            if (ci < Cin) {
                const ushort_t* src = Zb + (size_t)ci * Nn + px0 + s * 16;
                uint4 v0 = *(const uint4*)src;
                uint4 v1 = *(const uint4*)(src + 8);
                tmp[0]  = (ushort_t)(v0.x & 0xFFFF); tmp[1]  = (ushort_t)(v0.x >> 16);
                tmp[2]  = (ushort_t)(v0.y & 0xFFFF); tmp[3]  = (ushort_t)(v0.y >> 16);
                tmp[4]  = (ushort_t)(v0.z & 0xFFFF); tmp[5]  = (ushort_t)(v0.z >> 16);
                tmp[6]  = (ushort_t)(v0.w & 0xFFFF); tmp[7]  = (ushort_t)(v0.w >> 16);
                tmp[8]  = (ushort_t)(v1.x & 0xFFFF); tmp[9]  = (ushort_t)(v1.x >> 16);
                tmp[10] = (ushort_t)(v1.y & 0xFFFF); tmp[11] = (ushort_t)(v1.y >> 16);
                tmp[12] = (ushort_t)(v1.z & 0xFFFF); tmp[13] = (ushort_t)(v1.z >> 16);
                tmp[14] = (ushort_t)(v1.w & 0xFFFF); tmp[15] = (ushort_t)(v1.w >> 16);
            } else {
                #pragma unroll
                for (int i = 0; i < 16; ++i) tmp[i] = 0;
            }
            #pragma unroll
            for (int i = 0; i < 16; ++i) Bl[s * 16 + i][r] = tmp[i];
        }
        __syncthreads();

        short8 bfrag[2];
        #pragma unroll
        for (int px16 = 0; px16 < 2; ++px16)
            bfrag[px16] = *(const short8*)&Bl[wv * 32 + px16 * 16 + n][q * 8];
        #pragma unroll
        for (int mt = 0; mt < 4; ++mt) {
            const ushort_t* wp = Wh + (size_t)(co0 + mt * 16 + n) * Kpad + k0 + q * 8;
            short8 afrag = *(const short8*)wp;
            #pragma unroll
            for (int px16 = 0; px16 < 2; ++px16)
                acc[mt][px16] = __builtin_amdgcn_mfma_f32_16x16x32_bf16(
                    afrag, bfrag[px16], acc[mt][px16], 0, 0, 0);
        }
        __syncthreads();
    }

    #pragma unroll
    for (int px16 = 0; px16 < 2; ++px16) {
        int px = px0 + wv * 32 + px16 * 16 + n;
        #pragma unroll
        for (int mt = 0; mt < 4; ++mt) {
            #pragma unroll
            for (int reg = 0; reg < 4; ++reg) {
                int co = co0 + mt * 16 + q * 4 + reg;
                if (co < Mreal) {
                    float v = acc[mt][px16][reg];
                    if (bias) v += bias[co];
                    if (act == 1) v = fmaxf(v, 0.f);
                    size_t o = ((size_t)b * Mreal + co) * Nn + px;
                    if (res)  v += res[o];
                    if (outf) outf[o] = v;
                    if (outh) outh[o] = f2bf(v);
                }
            }
        }
    }
}

// ---------------------------------------------------------------------------
// Vectorized f32 1x1 conv (tier-2 only).
// ---------------------------------------------------------------------------
template <int TCO>
__global__ __launch_bounds__(256) void conv1x1v_kernel(const float* __restrict__ in,
                                                       const float* __restrict__ wgt,
                                                       int wstride,
                                                       const float* __restrict__ bias,
                                                       const float* __restrict__ res,
                                                       float* __restrict__ out,
                                                       int Cin, int Cout, int act) {
    int pg  = blockIdx.x * 256 + threadIdx.x;
    int b   = blockIdx.z;
    int co0 = blockIdx.y * TCO;

    const float* wrow[TCO];
    #pragma unroll
    for (int i = 0; i < TCO; ++i) {
        int co = co0 + i; if (co > Cout - 1) co = Cout - 1;
        wrow[i] = wgt + (size_t)co * wstride;
    }

    float4 acc[TCO];
    #pragma unroll
    for (int i = 0; i < TCO; ++i) acc[i] = make_float4(0.f, 0.f, 0.f, 0.f);

    const float* ib = in + (size_t)b * Cin * Nn + (size_t)pg * 4;
    #pragma unroll 8
    for (int ci = 0; ci < Cin; ++ci) {
        float4 v = *(const float4*)(ib + (size_t)ci * Nn);
        #pragma unroll
        for (int i = 0; i < TCO; ++i) {
            float w = wrow[i][ci];
            acc[i].x += v.x * w; acc[i].y += v.y * w;
            acc[i].z += v.z * w; acc[i].w += v.w * w;
        }
    }

    #pragma unroll
    for (int i = 0; i < TCO; ++i) {
        int co = co0 + i;
        if (co < Cout) {
            float4 r = acc[i];
            if (bias) { float bb = bias[co]; r.x += bb; r.y += bb; r.z += bb; r.w += bb; }
            if (act == 1) {
                r.x = fmaxf(r.x, 0.f); r.y = fmaxf(r.y, 0.f);
                r.z = fmaxf(r.z, 0.f); r.w = fmaxf(r.w, 0.f);
            }
            size_t o = ((size_t)b * Cout + co) * Nn + (size_t)pg * 4;
            if (res) {
                float4 rv = *(const float4*)(res + o);
                r.x += rv.x; r.y += rv.y; r.z += rv.z; r.w += rv.w;
            }
            *(float4*)(out + o) = r;
        }
    }
}

// ---------------------------------------------------------------------------
// Depthwise 3x3 f32 (tier-2).
// ---------------------------------------------------------------------------
__global__ __launch_bounds__(256) void dw3x3_kernel(const float* __restrict__ in,
                                                    const float* __restrict__ w,
                                                    float* __restrict__ out, int Ct) {
    int p = blockIdx.x * 256 + threadIdx.x;
    int c = blockIdx.y;
    int b = blockIdx.z;
    int y = p >> 7, x = p & (Wb - 1);
    const float* ib = in + ((size_t)b * Ct + c) * Nn;
    float wl[9];
    #pragma unroll
    for (int k = 0; k < 9; ++k) wl[k] = w[c * 9 + k];
    float acc = 0.f;
    #pragma unroll
    for (int dy = 0; dy < 3; ++dy) {
        int yy = y + dy - 1;
        if (yy < 0 || yy >= Hh) continue;
        #pragma unroll
        for (int dx = 0; dx < 3; ++dx) {
            int xx = x + dx - 1;
            if (xx < 0 || xx >= Wb) continue;
            acc += wl[dy * 3 + dx] * ib[yy * Wb + xx];
        }
    }
    out[((size_t)b * Ct + c) * Nn + p] = acc;
}

// ---------------------------------------------------------------------------
// Depthwise 3x3 bf16-in/f32-out v4: 8-px-per-thread, uint4 global loads,
// one compute task per thread, barrier-free ssq.
// Tap: output gx=8k+p, t(gx+dx-1) -> ts col 8k+p+dx+3 -> e[p+dx+3] (e base 8k).
// grid: (Hh/16, Ct, Bt), block 256. LDS 10880 B.
// ---------------------------------------------------------------------------
__global__ __launch_bounds__(256) void dw3x3_bf16_v4_kernel(const ushort_t* __restrict__ in,
                                                            const float* __restrict__ w,
                                                            float* __restrict__ out, int Ct,
                                                            float* __restrict__ ssq,
                                                            int nrmC) {
    const int gy0 = blockIdx.x * 16;
    const int c   = blockIdx.y;
    const int b   = blockIdx.z;
    const int tid = threadIdx.x;

    __shared__ float ts[20][136];

    const ushort_t* ib = in + ((size_t)b * Ct + c) * Nn;
    // stage: 320 tasks, 8-px strips
    for (int idx = tid; idx < 320; idx += 256) {
        int i = idx >> 4;
        int k = idx & 15;
        int gy = gy0 - 2 + i;
        float4 lo, hi;
        lo.x = lo.y = lo.z = lo.w = 0.f;
        hi.x = hi.y = hi.z = hi.w = 0.f;
        if (gy >= 0 && gy < Hh) {
            uint4 u = *(const uint4*)(ib + gy * Wb + 8 * k);
            lo.x = bf2f((ushort_t)(u.x & 0xFFFF)); lo.y = bf2f((ushort_t)(u.x >> 16));
            lo.z = bf2f((ushort_t)(u.y & 0xFFFF)); lo.w = bf2f((ushort_t)(u.y >> 16));
            hi.x = bf2f((ushort_t)(u.z & 0xFFFF)); hi.y = bf2f((ushort_t)(u.z >> 16));
            hi.z = bf2f((ushort_t)(u.w & 0xFFFF)); hi.w = bf2f((ushort_t)(u.w >> 16));
        }
        *(float4*)&ts[i][8 * k + 4] = lo;
        *(float4*)&ts[i][8 * k + 8] = hi;
        if (k == 0)  { float4 z; z.x = z.y = z.z = z.w = 0.f; *(float4*)&ts[i][0]   = z; }
        if (k == 15) { float4 z; z.x = z.y = z.z = z.w = 0.f; *(float4*)&ts[i][132] = z; }
    }
    __syncthreads();

    float wl[9];
    #pragma unroll
    for (int k = 0; k < 9; ++k) wl[k] = w[c * 9 + k];

    const int r = tid >> 4;
    const int k = tid & 15;
    float a[8] = {0.f, 0.f, 0.f, 0.f, 0.f, 0.f, 0.f, 0.f};
    #pragma unroll
    for (int dy = 0; dy < 3; ++dy) {
        const float* row = &ts[r + 1 + dy][8 * k];
        float4 e0 = *(const float4*)row;
        float4 e1 = *(const float4*)(row + 4);
        float4 e2 = *(const float4*)(row + 8);
        float4 e3 = *(const float4*)(row + 12);
        float e[16] = {e0.x, e0.y, e0.z, e0.w, e1.x, e1.y, e1.z, e1.w,
                       e2.x, e2.y, e2.z, e2.w, e3.x, e3.y, e3.z, e3.w};
        float w0 = wl[dy * 3], w1 = wl[dy * 3 + 1], w2 = wl[dy * 3 + 2];
        #pragma unroll
        for (int p = 0; p < 8; ++p)
            a[p] += w0 * e[p + 3] + w1 * e[p + 4] + w2 * e[p + 5];
    }
    float* ob = out + ((size_t)b * Ct + c) * Nn + (gy0 + r) * Wb + 8 * k;
    float4 s0; s0.x = a[0]; s0.y = a[1]; s0.z = a[2]; s0.w = a[3];
    float4 s1; s1.x = a[4]; s1.y = a[5]; s1.z = a[6]; s1.w = a[7];
    *(float4*)ob       = s0;
    *(float4*)(ob + 4) = s1;

    if (ssq != nullptr && c < nrmC) {
        float s2sum = 0.f;
        #pragma unroll
        for (int p = 0; p < 8; ++p) s2sum += a[p] * a[p];
        #pragma unroll
        for (int o = 32; o > 0; o >>= 1) s2sum += __shfl_xor(s2sum, o, 64);
        if ((tid & 63) == 0) atomicAdd(&ssq[(size_t)b * nrmC + c], s2sum);
    }
}

// ---------------------------------------------------------------------------
// L2 normalize along N (in-place, tier-2). grid: (Cc, 1, Bt).
// ---------------------------------------------------------------------------
__global__ __launch_bounds__(256) void l2norm_kernel(float* __restrict__ data, int cstride) {
    int b = blockIdx.z, c = blockIdx.x;
    float* ptr = data + ((size_t)b * cstride + c) * Nn;
    int t = threadIdx.x;
    float s = 0.f;
    for (int i = t; i < Nn; i += 256) { float v = ptr[i]; s += v * v; }
    __shared__ float red[256];
    red[t] = s; __syncthreads();
    for (int st = 128; st > 0; st >>= 1) { if (t < st) red[t] += red[t + st]; __syncthreads(); }
    float scale = 1.0f / fmaxf(sqrtf(red[0]), 1e-12f);
    for (int i = t; i < Nn; i += 256) ptr[i] *= scale;
}

// ---------------------------------------------------------------------------
// Gate stage 2 + final.
// ---------------------------------------------------------------------------
__global__ __launch_bounds__(256) void gate2_kernel(const float* __restrict__ gmid,
                                                    const float* __restrict__ w2,
                                                    const float* __restrict__ b2,
                                                    float* __restrict__ blocksums,
                                                    int out_off) {
    int p = blockIdx.x * 256 + threadIdx.x;
    int b = blockIdx.z;
    float acc = b2[0];
    const float* ib = gmid + (size_t)b * 64 * Nn + p;
    #pragma unroll 8
    for (int ci = 0; ci < 64; ++ci) acc += ib[(size_t)ci * Nn] * w2[ci];
    float g = 1.0f / (1.0f + expf(-acc));
    __shared__ float red[256];
    int t = threadIdx.x;
    red[t] = g; __syncthreads();
    for (int st = 128; st > 0; st >>= 1) { if (t < st) red[t] += red[t + st]; __syncthreads(); }
    if (t == 0) blocksums[out_off + b * 64 + blockIdx.x] = red[0];
}

__global__ void gate_final_kernel(const float* __restrict__ blocksums,
                                  int* __restrict__ dk_out) {
    __shared__ double sred[256];
    int t = threadIdx.x;
    sred[t] = (double)blocksums[t];
    __syncthreads();
    for (int st = 128; st > 0; st >>= 1) { if (t < st) sred[t] += sred[t + st]; __syncthreads(); }
    if (t == 0) {
        double mean = sred[0] / (double)(Bn * Nn);
        float val = 16.0f * (float)mean;
        int dk = (int)val;
        if (dk < 1) dk = 1;
        if (dk > 16) dk = 16;
        *dk_out = dk;
    }
}

// ---------------------------------------------------------------------------
// QK^T partial (f32). grid: (NS, HEADS, Bt).
// ---------------------------------------------------------------------------
__global__ __launch_bounds__(256) void attn_qk_partial_kernel(const float* __restrict__ q,
                                                              const float* __restrict__ k,
                                                              int kstride,
                                                              float* __restrict__ partial) {
    int ns = blockIdx.x, h = blockIdx.y, b = blockIdx.z;
    int t = threadIdx.x;
    int c = t >> 4, d = t & 15;
    __shared__ float qs[16][65];
    __shared__ float ks[16][65];
    const float* qb = q + ((size_t)b * Cc + h * CHh) * Nn;
    const float* kb = k + ((size_t)b * kstride + h * CHh) * Nn;
    float acc = 0.f;
    int nbeg = ns * (Nn / NS);
    for (int n0 = nbeg; n0 < nbeg + (Nn / NS); n0 += 64) {
        for (int idx = t; idx < 1024; idx += 256) {
            int r = idx >> 6, col = idx & 63;
            qs[r][col] = qb[(size_t)r * Nn + n0 + col];
            ks[r][col] = kb[(size_t)r * Nn + n0 + col];
        }
        __syncthreads();
        #pragma unroll
        for (int j = 0; j < 64; ++j) acc += qs[c][j] * ks[d][j];
        __syncthreads();
    }
    partial[(((size_t)(b * HEADS + h)) * NS + ns) * 256 + t] = acc;
}

// reduce + temperature + (optional) fused L2-norm scaling.
__global__ __launch_bounds__(256) void attn_reduce_kernel(const float* __restrict__ partial,
                                                          const float* __restrict__ temp,
                                                          const float* __restrict__ qss,
                                                          const float* __restrict__ kss,
                                                          float* __restrict__ attnp) {
    int bh = blockIdx.x;
    int h = bh % HEADS;
    int t = threadIdx.x;
    const float* pp = partial + (size_t)bh * NS * 256 + t;
    float s = 0.f;
    #pragma unroll 8
    for (int ns = 0; ns < NS; ++ns) s += pp[(size_t)ns * 256];
    float scale = temp[h];
    if (qss != nullptr) {
        int b  = bh / HEADS;
        int cQ = h * CHh + (t >> 4);
        int cK = h * CHh + (t & 15);
        float nq = fmaxf(sqrtf(qss[(size_t)b * Cc + cQ]), 1e-12f);
        float nk = fmaxf(sqrtf(kss[(size_t)b * Cc + cK]), 1e-12f);
        scale = scale / (nq * nk);
    }
    attnp[(size_t)bh * 256 + t] = s * scale;
}

__global__ void topk_softmax_kernel(float* __restrict__ attnp, const int* __restrict__ dkp) {
    int bh = blockIdx.x;
    int c = threadIdx.x;
    if (c >= 16) return;
    float* row = attnp + ((size_t)bh * CHh + c) * CHh;
    float a[16];
    #pragma unroll
    for (int d = 0; d < 16; ++d) a[d] = row[d];
    int dk = *dkp;
    unsigned keep = 0;
    float m = -INFINITY;
    #pragma unroll
    for (int d = 0; d < 16; ++d) {
        int rank = 0;
        #pragma unroll
        for (int j = 0; j < 16; ++j)
            rank += (a[j] > a[d]) || (a[j] == a[d] && j < d);
        if (rank < dk) { keep |= (1u << d); m = fmaxf(m, a[d]); }
    }
    float e[16]; float s = 0.f;
    #pragma unroll
    for (int d = 0; d < 16; ++d) {
        e[d] = (keep >> d & 1u) ? expf(a[d] - m) : 0.f;
        s += e[d];
    }
    float invs = 1.0f / s;
    #pragma unroll
    for (int d = 0; d < 16; ++d) row[d] = e[d] * invs;
}

// attn_v: f32 out (tier-2)
__global__ __launch_bounds__(256) void attn_v_kernel(const float* __restrict__ attnp,
                                                     const float* __restrict__ v,
                                                     float* __restrict__ out) {
    int p = blockIdx.x * 256 + threadIdx.x;
    int cg = blockIdx.y;
    int b = blockIdx.z;
    int h = cg >> 4, cr = cg & 15;
    const float* arow = attnp + (((size_t)b * HEADS + h) * CHh + cr) * CHh;
    const float* vb = v + ((size_t)b * Cc + h * CHh) * Nn + p;
    float acc = 0.f;
    #pragma unroll
    for (int d = 0; d < 16; ++d) acc += arow[d] * vb[(size_t)d * Nn];
    out[((size_t)b * Cc + cg) * Nn + p] = acc;
}

// attn_v: bf16 out.
__global__ __launch_bounds__(256) void attn_v_bf16_kernel(const float* __restrict__ attnp,
                                                          const float* __restrict__ v,
                                                          int vstride, int voff,
                                                          ushort_t* __restrict__ out) {
    int p = blockIdx.x * 256 + threadIdx.x;
    int cg = blockIdx.y;
    int b = blockIdx.z;
    int h = cg >> 4, cr = cg & 15;
    const float* arow = attnp + (((size_t)b * HEADS + h) * CHh + cr) * CHh;
    const float* vb = v + ((size_t)b * vstride + voff + h * CHh) * Nn + p;
    float acc = 0.f;
    #pragma unroll
    for (int d = 0; d < 16; ++d) acc += arow[d] * vb[(size_t)d * Nn];
    out[((size_t)b * Cc + cg) * Nn + p] = f2bf(acc);
}

// ---------------------------------------------------------------------------
// Fused IEL tail v8: both tensors in one pass, 8-px strips, 2 barriers.
//   u = conv3x3(t, dw); s = conv3x3(u, dw1/dw2)
//   out = (tanh(s1)+u1) * (tanh(s2)+u2)
// LDS 40768 B -> 4 blocks/CU. grid: (Hh/16, HID, Bt), block 256.
// ---------------------------------------------------------------------------
__global__ __launch_bounds__(256) void iel_tail_v8_kernel(const ushort_t* __restrict__ Th,
                                                          const float* __restrict__ dww,
                                                          const float* __restrict__ dw1p,
                                                          const float* __restrict__ dw2p,
                                                          ushort_t* __restrict__ PRh) {
    const int gy0 = blockIdx.x * 16;
    const int c   = blockIdx.y;
    const int b   = blockIdx.z;
    const int tid = threadIdx.x;

    __shared__ float ts[2][20][136];   // 21760 B
    __shared__ float us[2][18][132];   // 19008 B

    const ushort_t* t1 = Th + ((size_t)b * HID2 + c) * Nn;
    const ushort_t* t2 = Th + ((size_t)b * HID2 + HID + c) * Nn;

    // ---- phase 1: stage both tensors (640 tasks, 8-px strips) ----
    for (int idx = tid; idx < 640; idx += 256) {
        int i2 = idx >> 4;           // 0..39
        int k  = idx & 15;
        int t  = (i2 >= 20) ? 1 : 0;
        int i  = i2 - 20 * t;
        int gy = gy0 - 2 + i;
        const ushort_t* tp = t ? t2 : t1;
        float4 lo, hi;
        lo.x = lo.y = lo.z = lo.w = 0.f;
        hi.x = hi.y = hi.z = hi.w = 0.f;
        if (gy >= 0 && gy < Hh) {
            uint4 u = *(const uint4*)(tp + gy * Wb + 8 * k);
            lo.x = bf2f((ushort_t)(u.x & 0xFFFF)); lo.y = bf2f((ushort_t)(u.x >> 16));
            lo.z = bf2f((ushort_t)(u.y & 0xFFFF)); lo.w = bf2f((ushort_t)(u.y >> 16));
            hi.x = bf2f((ushort_t)(u.z & 0xFFFF)); hi.y = bf2f((ushort_t)(u.z >> 16));
            hi.z = bf2f((ushort_t)(u.w & 0xFFFF)); hi.w = bf2f((ushort_t)(u.w >> 16));
        }
        *(float4*)&ts[t][i][8 * k + 4] = lo;
        *(float4*)&ts[t][i][8 * k + 8] = hi;
        if (k == 0)  { float4 z; z.x = z.y = z.z = z.w = 0.f; *(float4*)&ts[t][i][0]   = z; }
        if (k == 15) { float4 z; z.x = z.y = z.z = z.w = 0.f; *(float4*)&ts[t][i][132] = z; }
    }

    // weights (uniform)
    float wA[9], wB[9], w1[9], w2[9];
    #pragma unroll
    for (int k = 0; k < 9; ++k) {
        wA[k] = dww[(size_t)c * 9 + k];
        wB[k] = dww[(size_t)(HID + c) * 9 + k];
        w1[k] = dw1p[(size_t)c * 9 + k];
        w2[k] = dw2p[(size_t)c * 9 + k];
    }
    __syncthreads();

    // ---- phase 2: u = conv3x3(t, w) both tensors ----
    // main 576 tasks (8-px strips, cols 0..127) + 36 edge tasks (col 128..131).
    // us[t][i][j] = u(gy0-1+i, j-1). Main strip k: u px gx = 8k-1..8k+6;
    // tap t(gx+dx-1) -> ts col 8k+p+dx+2 -> e[p+dx+2], e base ts col 8k.
    for (int idx = tid; idx < 612; idx += 256) {
        if (idx < 576) {
            int i3 = idx >> 4;       // 0..35
            int k  = idx & 15;
            int t  = (i3 >= 18) ? 1 : 0;
            int i  = i3 - 18 * t;
            int gy = gy0 - 1 + i;
            float a[8] = {0.f, 0.f, 0.f, 0.f, 0.f, 0.f, 0.f, 0.f};
            if (gy >= 0 && gy < Hh) {
                #pragma unroll
                for (int dy = 0; dy < 3; ++dy) {
                    const float* row = &ts[t][i + dy][8 * k];
                    float4 e0 = *(const float4*)row;
                    float4 e1 = *(const float4*)(row + 4);
                    float4 e2 = *(const float4*)(row + 8);
                    float e[12] = {e0.x, e0.y, e0.z, e0.w, e1.x, e1.y, e1.z, e1.w,
                                   e2.x, e2.y, e2.z, e2.w};
                    float w0 = t ? wB[dy * 3]     : wA[dy * 3];
                    float w1t = t ? wB[dy * 3 + 1] : wA[dy * 3 + 1];
                    float w2t = t ? wB[dy * 3 + 2] : wA[dy * 3 + 2];
                    #pragma unroll
                    for (int p = 0; p < 8; ++p)
                        a[p] += w0 * e[p + 2] + w1t * e[p + 3] + w2t * e[p + 4];
                }
                if (k == 0) a[0] = 0.f;   // gx = -1 pad
            }
            float4 o0; o0.x = a[0]; o0.y = a[1]; o0.z = a[2]; o0.w = a[3];
            float4 o1; o1.x = a[4]; o1.y = a[5]; o1.z = a[6]; o1.w = a[7];
            *(float4*)&us[t][i][8 * k]     = o0;
            *(float4*)&us[t][i][8 * k + 4] = o1;
        } else {
            int e2i = idx - 576;     // 0..35
            int t = (e2i >= 18) ? 1 : 0;
            int i = e2i - 18 * t;
            int gy = gy0 - 1 + i;
            float u127 = 0.f;
            if (gy >= 0 && gy < Hh) {
                #pragma unroll
                for (int dy = 0; dy < 3; ++dy) {
                    const float* row = &ts[t][i + dy][128];
                    float4 r0 = *(const float4*)row;        // cols 128..131
                    float4 r1 = *(const float4*)(row + 4);  // cols 132..135 (zeros)
                    float w0 = t ? wB[dy * 3]     : wA[dy * 3];
                    float w1t = t ? wB[dy * 3 + 1] : wA[dy * 3 + 1];
                    float w2t = t ? wB[dy * 3 + 2] : wA[dy * 3 + 2];
                    u127 += w0 * r0.z + w1t * r0.w + w2t * r1.x;
                }
            }
            float4 o; o.x = u127; o.y = 0.f; o.z = 0.f; o.w = 0.f;
            *(float4*)&us[t][i][128] = o;
        }
    }
    __syncthreads();

    // ---- phase 3: outer conv + gate + packed store (1 task/thread) ----
    {
        const int r = tid >> 4;
        const int k = tid & 15;
        float res[2][8];
        #pragma unroll
        for (int t = 0; t < 2; ++t) {
            float aa[8] = {0.f, 0.f, 0.f, 0.f, 0.f, 0.f, 0.f, 0.f};
            float ctr[8];
            #pragma unroll
            for (int dy = 0; dy < 3; ++dy) {
                const float* row = &us[t][r + dy][8 * k];
                float4 e0 = *(const float4*)row;
                float4 e1 = *(const float4*)(row + 4);
                float4 e2 = *(const float4*)(row + 8);
                float e[12] = {e0.x, e0.y, e0.z, e0.w, e1.x, e1.y, e1.z, e1.w,
                               e2.x, e2.y, e2.z, e2.w};
                float w0 = t ? w2[dy * 3]     : w1[dy * 3];
                float w1t = t ? w2[dy * 3 + 1] : w1[dy * 3 + 1];
                float w2t = t ? w2[dy * 3 + 2] : w1[dy * 3 + 2];
                #pragma unroll
                for (int p = 0; p < 8; ++p)
                    aa[p] += w0 * e[p] + w1t * e[p + 1] + w2t * e[p + 2];
                if (dy == 1) {
                    #pragma unroll
                    for (int p = 0; p < 8; ++p) ctr[p] = e[p + 1];
                }
            }
            #pragma unroll
            for (int p = 0; p < 8; ++p) res[t][p] = fast_tanh(aa[p]) + ctr[p];
        }
        ushort_t* outp = PRh + ((size_t)b * HID + c) * Nn + (gy0 + r) * Wb + 8 * k;
        float v[8];
        #pragma unroll
        for (int p = 0; p < 8; ++p) v[p] = res[0][p] * res[1][p];
        uint4 pk;
        pk.x = (unsigned)f2bf(v[0]) | ((unsigned)f2bf(v[1]) << 16);
        pk.y = (unsigned)f2bf(v[2]) | ((unsigned)f2bf(v[3]) << 16);
        pk.z = (unsigned)f2bf(v[4]) | ((unsigned)f2bf(v[5]) << 16);
        pk.w = (unsigned)f2bf(v[6]) | ((unsigned)f2bf(v[7]) << 16);
        *(uint4*)outp = pk;
    }
}

// f32 IEL tail (tier-2 fallback; per-chunk layout).
__global__ __launch_bounds__(256) void iel_tail_f32_kernel(const float* __restrict__ t1p,
                                                           const float* __restrict__ t2p,
                                                           const float* __restrict__ dwA,
                                                           const float* __restrict__ dwB,
                                                           const float* __restrict__ dw1p,
                                                           const float* __restrict__ dw2p,
                                                           float* __restrict__ prod) {
    const int c = blockIdx.y;
    const int tilesx = Wb / 16;
    const int ty0 = (blockIdx.x / tilesx) * 16;
    const int tx0 = (blockIdx.x % tilesx) * 16;
    const int tid = threadIdx.x;

    __shared__ float ts[2][20][24];
    __shared__ float us[2][18][24];

    const float* t1 = t1p + (size_t)c * Nn;
    const float* t2 = t2p + (size_t)c * Nn;

    for (int idx = tid; idx < 400; idx += 256) {
        int i = idx / 20, j = idx % 20;
        int gy = ty0 - 2 + i, gx = tx0 - 2 + j;
        bool ok = (gy >= 0 && gy < Hh && gx >= 0 && gx < Wb);
        ts[0][i][j] = ok ? t1[gy * Wb + gx] : 0.f;
        ts[1][i][j] = ok ? t2[gy * Wb + gx] : 0.f;
    }
    __syncthreads();

    float wA[9], wB[9], w1[9], w2[9];
    #pragma unroll
    for (int k = 0; k < 9; ++k) {
        wA[k] = dwA[c * 9 + k];
        wB[k] = dwB[c * 9 + k];
        w1[k] = dw1p[c * 9 + k];
        w2[k] = dw2p[c * 9 + k];
    }

    for (int idx = tid; idx < 324; idx += 256) {
        int i = idx / 18, j = idx % 18;
        int gy = ty0 - 1 + i, gx = tx0 - 1 + j;
        float a0 = 0.f, a1 = 0.f;
        if (gy >= 0 && gy < Hh && gx >= 0 && gx < Wb) {
            #pragma unroll
            for (int dy = 0; dy < 3; ++dy)
                #pragma unroll
                for (int dx = 0; dx < 3; ++dx) {
                    a0 += wA[dy * 3 + dx] * ts[0][i + dy][j + dx];
                    a1 += wB[dy * 3 + dx] * ts[1][i + dy][j + dx];
                }
        }
        us[0][i][j] = a0;
        us[1][i][j] = a1;
    }
    __syncthreads();

    int ty = tid >> 4, tx = tid & 15;
    float c1 = us[0][ty + 1][tx + 1];
    float c2 = us[1][ty + 1][tx + 1];
    float s1 = 0.f, s2 = 0.f;
    #pragma unroll
    for (int dy = 0; dy < 3; ++dy)
        #pragma unroll
        for (int dx = 0; dx < 3; ++dx) {
            s1 += w1[dy * 3 + dx] * us[0][ty + dy][tx + dx];
            s2 += w2[dy * 3 + dx] * us[1][ty + dy][tx + dx];
        }
    float x1t = tanhf(s1) + c1;
    float x2t = tanhf(s2) + c2;
    prod[(size_t)c * Nn + (ty0 + ty) * Wb + (tx0 + tx)] = x1t * x2t;
}

// ---------------------------------------------------------------------------
// Host launcher
// ---------------------------------------------------------------------------
extern "C" void kernel_launch(void* const* d_in, const int* in_sizes, int n_in,
                              void* d_out, int out_size, void* d_ws, size_t ws_size,
                              hipStream_t stream) {
    const float* x      = (const float*)d_in[0];
    const float* y      = (const float*)d_in[1];
    const float* ln_w   = (const float*)d_in[2];
    const float* ln_b   = (const float*)d_in[3];
    const float* temp   = (const float*)d_in[4];
    const float* q_w    = (const float*)d_in[5];
    const float* qdw_w  = (const float*)d_in[6];
    const float* kv_w   = (const float*)d_in[7];
    const float* kvdw_w = (const float*)d_in[8];
    const float* po_w   = (const float*)d_in[9];
    const float* g1_w   = (const float*)d_in[10];
    const float* g1_b   = (const float*)d_in[11];
    const float* g2_w   = (const float*)d_in[12];
    const float* g2_b   = (const float*)d_in[13];
    const float* pin_w  = (const float*)d_in[14];
    const float* dw_w   = (const float*)d_in[15];
    const float* dw1_w  = (const float*)d_in[16];
    const float* dw2_w  = (const float*)d_in[17];
    const float* pout_w = (const float*)d_in[18];
    float* out = (float*)d_out;

    // smalls in first 1 MiB
    char* ws = (char*)d_ws;
    float* attn      = (float*)ws;                        // 32 KB
    float* blocksums = (float*)(ws + 32768);              // 1 KB
    int*   dk        = (int*)(ws + 33792);
    ushort_t* qWh  = (ushort_t*)(ws + 34816);             // 128x128
    ushort_t* kvWh = qWh + 16384;                         // 256x128
    ushort_t* poWh = kvWh + 32768;                        // 128x128
    ushort_t* g1Wh = poWh + 16384;                        // 64x128
    ushort_t* Wh1  = g1Wh + 8192;                         // 704x128
    ushort_t* Wh2  = Wh1 + (size_t)MPAD * Cc;             // 128x352
    float* qss = (float*)(ws + 458752);                   // [Bn][128] sumsq(q)
    float* kss = (float*)(ws + 460800);                   // [Bn][128] sumsq(k)
    float* pool    = (float*)(ws + (1u << 20));

    const size_t CN    = (size_t)Cc * Nn;
    const size_t SLOT1 = (size_t)Bn * CN;
    const size_t TIER1_NEED = 65536 + 6 * SLOT1 * 4;

    dim3 blk(256);
    const int PGX = Nn / 1024;

    if (ws_size >= TIER1_NEED) {
        // ---- buffers ----
        float* S3 = pool;                                  // q2 f32 [B][128][Nn]
        float* S4 = pool + 8 * 1024 * 1024;                // k2+v2 f32 [B][256][Nn]
        ushort_t* XNh  = (ushort_t*)(pool + 24 * 1024 * 1024);
        ushort_t* YNh  = XNh + Bn * CN;
        ushort_t* KV1h = YNh + Bn * CN;
        ushort_t* Q1h  = KV1h + 2 * Bn * CN;
        float* gmid    = (float*)Q1h;
        float* partial = gmid;
        ushort_t* AOh  = XNh;

        wconv_pad_rows_kernel<<<dim3(64), blk, 0, stream>>>(q_w, qWh, 128, Cc);
        wconv_pad_rows_kernel<<<dim3(128), blk, 0, stream>>>(kv_w, kvWh, 256, Cc);
        wconv_pad_rows_kernel<<<dim3(64), blk, 0, stream>>>(po_w, poWh, 128, Cc);
        wconv_pad_rows_kernel<<<dim3(32), blk, 0, stream>>>(g1_w, g1Wh, 64, Cc);
        wconv_pad_rows_kernel<<<dim3(MPAD * Cc / 256), blk, 0, stream>>>(pin_w, Wh1, HID2, Cc);
        wconv_pad_cols_kernel<<<dim3(Cc * KPAD2 / 256), blk, 0, stream>>>(pout_w, Wh2, HID, KPAD2);
        zero_f32_kernel<<<dim3(4), blk, 0, stream>>>(qss, 2 * Bn * Cc);  // qss+kss contiguous

        // ---- Phase A ----
        ln_bf16_kernel<<<dim3(Nn / 256, 1, Bn), blk, 0, stream>>>(x, ln_w, ln_b, XNh);
        ln_bf16_kernel<<<dim3(Nn / 256, 1, Bn), blk, 0, stream>>>(y, ln_w, ln_b, YNh);

        gemm_bf16_kernel<<<dim3(Nn / 128, 2, Bn), blk, 0, stream>>>(
            XNh, qWh, nullptr, nullptr, nullptr, Q1h, Cc, Cc, Cc, 0);
        dw3x3_bf16_v4_kernel<<<dim3(Hh / 16, Cc, Bn), blk, 0, stream>>>(
            Q1h, qdw_w, S3, Cc, qss, Cc);

        gemm_bf16_kernel<<<dim3(Nn / 128, 4, Bn), blk, 0, stream>>>(
            YNh, kvWh, nullptr, nullptr, nullptr, KV1h, Cc, Cc, 2 * Cc, 0);
        dw3x3_bf16_v4_kernel<<<dim3(Hh / 16, 2 * Cc, Bn), blk, 0, stream>>>(
            KV1h, kvdw_w, S4, 2 * Cc, kss, Cc);

        gemm_bf16_kernel<<<dim3(Nn / 128, 1, Bn), blk, 0, stream>>>(
            XNh, g1Wh, g1_b, nullptr, gmid, nullptr, Cc, Cc, 64, 1);
        gate2_kernel<<<dim3(Nn / 256, 1, Bn), blk, 0, stream>>>(gmid, g2_w, g2_b, blocksums, 0);
        gate_final_kernel<<<dim3(1), blk, 0, stream>>>(blocksums, dk);

        // L2 norms folded into attn_reduce via qss/kss (no l2norm passes).
        attn_qk_partial_kernel<<<dim3(NS, HEADS, Bn), blk, 0, stream>>>(S3, S4, 2 * Cc, partial);
        attn_reduce_kernel<<<dim3(Bn * HEADS), blk, 0, stream>>>(partial, temp, qss, kss, attn);
        topk_softmax_kernel<<<dim3(Bn * HEADS), dim3(16), 0, stream>>>(attn, dk);
        attn_v_bf16_kernel<<<dim3(Nn / 256, Cc, Bn), blk, 0, stream>>>(
            attn, S4, 2 * Cc, Cc, AOh);

        gemm_bf16_kernel<<<dim3(Nn / 128, 2, Bn), blk, 0, stream>>>(
            AOh, poWh, nullptr, x, out, nullptr, Cc, Cc, Cc, 0);

        // ---- Phase B ----
        ushort_t* ZNh = (ushort_t*)pool;
        ushort_t* Th  = ZNh + Bn * CN;
        ushort_t* PRh = Th + (size_t)Bn * HID2 * Nn;

        ln_bf16_kernel<<<dim3(Nn / 256, 1, Bn), blk, 0, stream>>>(out, ln_w, ln_b, ZNh);

        gemm_bf16_kernel<<<dim3(Nn / 128, MPAD / 64, Bn), blk, 0, stream>>>(
            ZNh, Wh1, nullptr, nullptr, nullptr, Th, Cc, Cc, HID2, 0);

        iel_tail_v8_kernel<<<dim3(Hh / 16, HID, Bn), blk, 0, stream>>>(
            Th, dw_w, dw1_w, dw2_w, PRh);

        gemm_bf16_kernel<<<dim3(Nn / 128, 2, Bn), blk, 0, stream>>>(
            PRh, Wh2, nullptr, out, out, nullptr, HID, KPAD2, Cc, 0);
    } else {
        // ================= Tier 2: per-batch f32 fallback ===================
        float* s0 = pool;
        float* s1 = pool + 1 * CN;
        float* s2 = pool + 2 * CN;
        float* s3 = pool + 3 * CN;
        float* s4 = pool + 4 * CN;
        float* s5 = pool + 5 * CN;

        for (int b = 0; b < Bn; ++b) {
            const float* xb = x + (size_t)b * CN;
            ln_kernel<<<dim3(Nn / 256, 1, 1), blk, 0, stream>>>(xb, ln_w, ln_b, s0);
            conv1x1v_kernel<4><<<dim3(PGX, 16, 1), blk, 0, stream>>>(
                s0, g1_w, Cc, g1_b, nullptr, s1, Cc, 64, 1);
            gate2_kernel<<<dim3(Nn / 256, 1, 1), blk, 0, stream>>>(
                s1, g2_w, g2_b, blocksums, b * 64);
        }
        gate_final_kernel<<<dim3(1), blk, 0, stream>>>(blocksums, dk);

        for (int b = 0; b < Bn; ++b) {
            const float* xb = x + (size_t)b * CN;
            const float* yb = y + (size_t)b * CN;
            float* outb = out + (size_t)b * CN;
            float* attnb = attn + (size_t)b * HEADS * CHh * CHh;

            ln_kernel<<<dim3(Nn / 256, 1, 1), blk, 0, stream>>>(xb, ln_w, ln_b, s0);
            ln_kernel<<<dim3(Nn / 256, 1, 1), blk, 0, stream>>>(yb, ln_w, ln_b, s1);

            conv1x1v_kernel<8><<<dim3(PGX, 16, 1), blk, 0, stream>>>(
                s0, q_w, Cc, nullptr, nullptr, s2, Cc, Cc, 0);
            dw3x3_kernel<<<dim3(Nn / 256, Cc, 1), blk, 0, stream>>>(s2, qdw_w, s3, Cc);
            l2norm_kernel<<<dim3(Cc, 1, 1), blk, 0, stream>>>(s3, Cc);

            conv1x1v_kernel<8><<<dim3(PGX, 16, 1), blk, 0, stream>>>(
                s1, kv_w, Cc, nullptr, nullptr, s2, Cc, Cc, 0);
            dw3x3_kernel<<<dim3(Nn / 256, Cc, 1), blk, 0, stream>>>(s2, kvdw_w, s4, Cc);
            l2norm_kernel<<<dim3(Cc, 1, 1), blk, 0, stream>>>(s4, Cc);

            conv1x1v_kernel<8><<<dim3(PGX, 16, 1), blk, 0, stream>>>(
                s1, kv_w + 128 * 128, Cc, nullptr, nullptr, s2, Cc, Cc, 0);
            dw3x3_kernel<<<dim3(Nn / 256, Cc, 1), blk, 0, stream>>>(s2, kvdw_w + 128 * 9, s5, Cc);

            attn_qk_partial_kernel<<<dim3(NS, HEADS, 1), blk, 0, stream>>>(s3, s4, Cc, s2);
            attn_reduce_kernel<<<dim3(HEADS), blk, 0, stream>>>(s2, temp, nullptr, nullptr, attnb);
            topk_softmax_kernel<<<dim3(HEADS), dim3(16), 0, stream>>>(attnb, dk);
            attn_v_kernel<<<dim3(Nn / 256, Cc, 1), blk, 0, stream>>>(attnb, s5, s2);

            conv1x1v_kernel<8><<<dim3(PGX, 16, 1), blk, 0, stream>>>(
                s2, po_w, Cc, nullptr, xb, outb, Cc, Cc, 0);
        }

        const int CHUNK = 170;
        const size_t TCH = (size_t)CHUNK * Nn;
        float* zn   = pool;
        float* T1   = pool + CN;
        float* T2   = T1 + TCH;
        float* prod = T2 + TCH;
        for (int b = 0; b < Bn; ++b) {
            float* outb = out + (size_t)b * CN;
            ln_kernel<<<dim3(Nn / 256, 1, 1), blk, 0, stream>>>(outb, ln_w, ln_b, zn);
            for (int c0 = 0; c0 < HID; c0 += CHUNK) {
                conv1x1v_kernel<20><<<dim3(PGX, 9, 1), blk, 0, stream>>>(
                    zn, pin_w + (size_t)c0 * Cc, Cc, nullptr, nullptr, T1, Cc, CHUNK, 0);
                conv1x1v_kernel<20><<<dim3(PGX, 9, 1), blk, 0, stream>>>(
                    zn, pin_w + (size_t)(HID + c0) * Cc, Cc, nullptr, nullptr, T2, Cc, CHUNK, 0);
                iel_tail_f32_kernel<<<dim3(64, CHUNK, 1), blk, 0, stream>>>(
                    T1, T2, dw_w + c0 * 9, dw_w + (HID + c0) * 9,
                    dw1_w + c0 * 9, dw2_w + c0 * 9, prod);
                conv1x1v_kernel<8><<<dim3(PGX, 16, 1), blk, 0, stream>>>(
                    prod, pout_w + c0, HID, nullptr, outb, outb, CHUNK, Cc, 0);
            }
        }
    }
}

// Round 8
// 628.983 us; speedup vs baseline: 1.0334x; 1.0334x over previous
//
#include <hip/hip_runtime.h>
#include <math.h>

// Problem constants
static constexpr int Bn    = 4;
static constexpr int Cc    = 128;
static constexpr int Hh    = 128;
static constexpr int Wb    = 128;
static constexpr int Nn    = Hh * Wb;      // 16384
static constexpr int HEADS = 8;
static constexpr int CHh   = 16;
static constexpr int HID   = 340;
static constexpr int HID2  = 680;
static constexpr int NS    = 64;
static constexpr int MPAD  = 704;          // pin M padded (680 -> 44*16)
static constexpr int KPAD2 = 352;          // pout K padded (340 -> 11*32)

typedef unsigned short ushort_t;
typedef __attribute__((ext_vector_type(8))) short short8;
typedef __attribute__((ext_vector_type(4))) float f32x4;

__device__ __forceinline__ ushort_t f2bf(float f) {
    unsigned u = __float_as_uint(f);
    return (ushort_t)((u + 0x7FFFu + ((u >> 16) & 1u)) >> 16);   // RNE
}
__device__ __forceinline__ float bf2f(ushort_t h) {
    return __uint_as_float(((unsigned)h) << 16);
}

// fast tanh: tanh(x) = 1 - 2/(e^{2|x|}+1), sign-restored.
__device__ __forceinline__ float fast_tanh(float x) {
    float a = fabsf(x);
    a = fminf(a, 12.0f);
    float e = __expf(2.0f * a);
    float r = 1.0f - 2.0f * __builtin_amdgcn_rcpf(e + 1.0f);
    return x < 0.0f ? -r : r;
}

// ---------------------------------------------------------------------------
// Conflict-free staging helper (from v7, used by dw3x3_v3):
//   ts[20][136]: ts[i][c] = t(gy0-2+i, c-4), data c = 4..131, zeros at
//   c=0..3 and 132..135. Aligned float4, lane stride 16 B.
// ---------------------------------------------------------------------------
__device__ __forceinline__ void iel7_stage(float (*ts)[136], const ushort_t* __restrict__ tp,
                                           int gy0, int tid) {
    for (int idx = tid; idx < 640; idx += 256) {
        int i = idx >> 5;
        int s = idx & 31;
        int gy = gy0 - 2 + i;
        float4 v; v.x = 0.f; v.y = 0.f; v.z = 0.f; v.w = 0.f;
        if (gy >= 0 && gy < Hh) {
            uint2 u = *(const uint2*)(tp + gy * Wb + 4 * s);
            v.x = bf2f((ushort_t)(u.x & 0xFFFF)); v.y = bf2f((ushort_t)(u.x >> 16));
            v.z = bf2f((ushort_t)(u.y & 0xFFFF)); v.w = bf2f((ushort_t)(u.y >> 16));
        }
        *(float4*)&ts[i][4 + 4 * s] = v;
        if (s == 0) {
            float4 z; z.x = 0.f; z.y = 0.f; z.z = 0.f; z.w = 0.f;
            *(float4*)&ts[i][0] = z;
        }
        if (s == 31) {
            float4 z; z.x = 0.f; z.y = 0.f; z.z = 0.f; z.w = 0.f;
            *(float4*)&ts[i][132] = z;
        }
    }
}

// ---------------------------------------------------------------------------
// LayerNorm over channel axis, f32 out (tier-2). grid: (Nn/256, 1, Bt).
// ---------------------------------------------------------------------------
__global__ __launch_bounds__(256) void ln_kernel(const float* __restrict__ in,
                                                 const float* __restrict__ w,
                                                 const float* __restrict__ bias,
                                                 float* __restrict__ out) {
    int p = blockIdx.x * 256 + threadIdx.x;
    int b = blockIdx.z;
    const float* ib = in + (size_t)b * Cc * Nn + p;
    float s = 0.f, s2 = 0.f;
    #pragma unroll 8
    for (int c = 0; c < Cc; ++c) {
        float v = ib[(size_t)c * Nn];
        s += v; s2 += v * v;
    }
    float mean = s * (1.0f / Cc);
    float var  = s2 * (1.0f / Cc) - mean * mean;
    float inv  = 1.0f / sqrtf(var + 1e-6f);
    float* ob = out + (size_t)b * Cc * Nn + p;
    #pragma unroll 8
    for (int c = 0; c < Cc; ++c) {
        float v = ib[(size_t)c * Nn];
        ob[(size_t)c * Nn] = w[c] * ((v - mean) * inv) + bias[c];
    }
}

// LayerNorm writing bf16 (feeds MFMA GEMMs).
__global__ __launch_bounds__(256) void ln_bf16_kernel(const float* __restrict__ in,
                                                      const float* __restrict__ w,
                                                      const float* __restrict__ bias,
                                                      ushort_t* __restrict__ out) {
    int p = blockIdx.x * 256 + threadIdx.x;
    int b = blockIdx.z;
    const float* ib = in + (size_t)b * Cc * Nn + p;
    float s = 0.f, s2 = 0.f;
    #pragma unroll 8
    for (int c = 0; c < Cc; ++c) {
        float v = ib[(size_t)c * Nn];
        s += v; s2 += v * v;
    }
    float mean = s * (1.0f / Cc);
    float var  = s2 * (1.0f / Cc) - mean * mean;
    float inv  = 1.0f / sqrtf(var + 1e-6f);
    ushort_t* ob = out + (size_t)b * Cc * Nn + p;
    #pragma unroll 8
    for (int c = 0; c < Cc; ++c) {
        float v = ib[(size_t)c * Nn];
        ob[(size_t)c * Nn] = f2bf(w[c] * ((v - mean) * inv) + bias[c]);
    }
}

// ---------------------------------------------------------------------------
// Weight conversion f32 -> bf16 (+ padding variants).
// ---------------------------------------------------------------------------
__global__ __launch_bounds__(256) void wconv_pad_rows_kernel(const float* __restrict__ w,
                                                             ushort_t* __restrict__ o,
                                                             int rows, int K) {
    int idx = blockIdx.x * 256 + threadIdx.x;
    int r = idx / K, k = idx - r * K;
    o[idx] = (r < rows) ? f2bf(w[(size_t)r * K + k]) : (ushort_t)0;
}
__global__ __launch_bounds__(256) void wconv_pad_cols_kernel(const float* __restrict__ w,
                                                             ushort_t* __restrict__ o,
                                                             int K, int Kp) {
    int idx = blockIdx.x * 256 + threadIdx.x;
    int r = idx / Kp, k = idx - r * Kp;
    o[idx] = (k < K) ? f2bf(w[(size_t)r * K + k]) : (ushort_t)0;
}

// Zero a small f32 buffer (for ssq atomics).
__global__ __launch_bounds__(256) void zero_f32_kernel(float* __restrict__ p, int n) {
    int i = blockIdx.x * 256 + threadIdx.x;
    if (i < n) p[i] = 0.f;
}

// ---------------------------------------------------------------------------
// bf16 MFMA GEMM v2: out[b,co,p] = sum_ci W[co,ci] * Z[b,ci,p]
// ---------------------------------------------------------------------------
__global__ __launch_bounds__(256) void gemm_bf16_kernel(const ushort_t* __restrict__ Zh,
                                                        const ushort_t* __restrict__ Wh,
                                                        const float* __restrict__ bias,
                                                        const float* __restrict__ res,
                                                        float* outf,
                                                        ushort_t* outh,
                                                        int Cin, int Kpad, int Mreal,
                                                        int act) {
    const int b    = blockIdx.z;
    const int px0  = blockIdx.x * 128;
    const int co0  = blockIdx.y * 64;
    const int tid  = threadIdx.x;
    const int wv   = tid >> 6;
    const int lane = tid & 63;
    const int n    = lane & 15;
    const int q    = lane >> 4;

    __shared__ ushort_t Bl[128][40];

    const ushort_t* Zb = Zh + (size_t)b * Cin * Nn;

    f32x4 acc[4][2];
    #pragma unroll
    for (int i = 0; i < 4; ++i)
        #pragma unroll
        for (int j = 0; j < 2; ++j) acc[i][j] = (f32x4){0.f, 0.f, 0.f, 0.f};

    for (int k0 = 0; k0 < Kpad; k0 += 32) {
        {
            int r = tid >> 3;        // k row 0..31
            int s = tid & 7;         // 16-px chunk
            int ci = k0 + r;
            ushort_t tmp[16];
            if (ci < Cin) {
                const ushort_t* src = Zb + (size_t)ci * Nn + px0 + s * 16;
                uint4 v0 = *(const uint4*)src;
                uint4 v1 = *(const uint4*)(src + 8);
                tmp[0]  = (ushort_t)(v0.x & 0xFFFF); tmp[1]  = (ushort_t)(v0.x >> 16);
                tmp[2]  = (ushort_t)(v0.y & 0xFFFF); tmp[3]  = (ushort_t)(v0.y >> 16);
                tmp[4]  = (ushort_t)(v0.z & 0xFFFF); tmp[5]  = (ushort_t)(v0.z >> 16);
                tmp[6]  = (ushort_t)(v0.w & 0xFFFF); tmp[7]  = (ushort_t)(v0.w >> 16);
                tmp[8]  = (ushort_t)(v1.x & 0xFFFF); tmp[9]  = (ushort_t)(v1.x >> 16);
                tmp[10] = (ushort_t)(v1.y & 0xFFFF); tmp[11] = (ushort_t)(v1.y >> 16);
                tmp[12] = (ushort_t)(v1.z & 0xFFFF); tmp[13] = (ushort_t)(v1.z >> 16);
                tmp[14] = (ushort_t)(v1.w & 0xFFFF); tmp[15] = (ushort_t)(v1.w >> 16);
            } else {
                #pragma unroll
                for (int i = 0; i < 16; ++i) tmp[i] = 0;
            }
            #pragma unroll
            for (int i = 0; i < 16; ++i) Bl[s * 16 + i][r] = tmp[i];
        }
        __syncthreads();

        short8 bfrag[2];
        #pragma unroll
        for (int px16 = 0; px16 < 2; ++px16)
            bfrag[px16] = *(const short8*)&Bl[wv * 32 + px16 * 16 + n][q * 8];
        #pragma unroll
        for (int mt = 0; mt < 4; ++mt) {
            const ushort_t* wp = Wh + (size_t)(co0 + mt * 16 + n) * Kpad + k0 + q * 8;
            short8 afrag = *(const short8*)wp;
            #pragma unroll
            for (int px16 = 0; px16 < 2; ++px16)
                acc[mt][px16] = __builtin_amdgcn_mfma_f32_16x16x32_bf16(
                    afrag, bfrag[px16], acc[mt][px16], 0, 0, 0);
        }
        __syncthreads();
    }

    #pragma unroll
    for (int px16 = 0; px16 < 2; ++px16) {
        int px = px0 + wv * 32 + px16 * 16 + n;
        #pragma unroll
        for (int mt = 0; mt < 4; ++mt) {
            #pragma unroll
            for (int reg = 0; reg < 4; ++reg) {
                int co = co0 + mt * 16 + q * 4 + reg;
                if (co < Mreal) {
                    float v = acc[mt][px16][reg];
                    if (bias) v += bias[co];
                    if (act == 1) v = fmaxf(v, 0.f);
                    size_t o = ((size_t)b * Mreal + co) * Nn + px;
                    if (res)  v += res[o];
                    if (outf) outf[o] = v;
                    if (outh) outh[o] = f2bf(v);
                }
            }
        }
    }
}

// ---------------------------------------------------------------------------
// Vectorized f32 1x1 conv (tier-2 only).
// ---------------------------------------------------------------------------
template <int TCO>
__global__ __launch_bounds__(256) void conv1x1v_kernel(const float* __restrict__ in,
                                                       const float* __restrict__ wgt,
                                                       int wstride,
                                                       const float* __restrict__ bias,
                                                       const float* __restrict__ res,
                                                       float* __restrict__ out,
                                                       int Cin, int Cout, int act) {
    int pg  = blockIdx.x * 256 + threadIdx.x;
    int b   = blockIdx.z;
    int co0 = blockIdx.y * TCO;

    const float* wrow[TCO];
    #pragma unroll
    for (int i = 0; i < TCO; ++i) {
        int co = co0 + i; if (co > Cout - 1) co = Cout - 1;
        wrow[i] = wgt + (size_t)co * wstride;
    }

    float4 acc[TCO];
    #pragma unroll
    for (int i = 0; i < TCO; ++i) acc[i] = make_float4(0.f, 0.f, 0.f, 0.f);

    const float* ib = in + (size_t)b * Cin * Nn + (size_t)pg * 4;
    #pragma unroll 8
    for (int ci = 0; ci < Cin; ++ci) {
        float4 v = *(const float4*)(ib + (size_t)ci * Nn);
        #pragma unroll
        for (int i = 0; i < TCO; ++i) {
            float w = wrow[i][ci];
            acc[i].x += v.x * w; acc[i].y += v.y * w;
            acc[i].z += v.z * w; acc[i].w += v.w * w;
        }
    }

    #pragma unroll
    for (int i = 0; i < TCO; ++i) {
        int co = co0 + i;
        if (co < Cout) {
            float4 r = acc[i];
            if (bias) { float bb = bias[co]; r.x += bb; r.y += bb; r.z += bb; r.w += bb; }
            if (act == 1) {
                r.x = fmaxf(r.x, 0.f); r.y = fmaxf(r.y, 0.f);
                r.z = fmaxf(r.z, 0.f); r.w = fmaxf(r.w, 0.f);
            }
            size_t o = ((size_t)b * Cout + co) * Nn + (size_t)pg * 4;
            if (res) {
                float4 rv = *(const float4*)(res + o);
                r.x += rv.x; r.y += rv.y; r.z += rv.z; r.w += rv.w;
            }
            *(float4*)(out + o) = r;
        }
    }
}

// ---------------------------------------------------------------------------
// Depthwise 3x3 f32 (tier-2).
// ---------------------------------------------------------------------------
__global__ __launch_bounds__(256) void dw3x3_kernel(const float* __restrict__ in,
                                                    const float* __restrict__ w,
                                                    float* __restrict__ out, int Ct) {
    int p = blockIdx.x * 256 + threadIdx.x;
    int c = blockIdx.y;
    int b = blockIdx.z;
    int y = p >> 7, x = p & (Wb - 1);
    const float* ib = in + ((size_t)b * Ct + c) * Nn;
    float wl[9];
    #pragma unroll
    for (int k = 0; k < 9; ++k) wl[k] = w[c * 9 + k];
    float acc = 0.f;
    #pragma unroll
    for (int dy = 0; dy < 3; ++dy) {
        int yy = y + dy - 1;
        if (yy < 0 || yy >= Hh) continue;
        #pragma unroll
        for (int dx = 0; dx < 3; ++dx) {
            int xx = x + dx - 1;
            if (xx < 0 || xx >= Wb) continue;
            acc += wl[dy * 3 + dx] * ib[yy * Wb + xx];
        }
    }
    out[((size_t)b * Ct + c) * Nn + p] = acc;
}

// ---------------------------------------------------------------------------
// Depthwise 3x3 bf16-in/f32-out v3: conflict-free 4-px-per-lane LDS pattern.
// Thread (r,s): output row gy0+r, px gx = 4s..4s+3. Reads ts[r+1+dy][4s..4s+11]
// (3 aligned b128). Tap t(4s+p+dx-1) -> ts col 4s+p+dx+3 -> e[p+dx+3].
// grid: (Hh/16, Ct, Bt), block 256. LDS 10880 B. Barrier-free ssq.
// ---------------------------------------------------------------------------
__global__ __launch_bounds__(256) void dw3x3_bf16_v3_kernel(const ushort_t* __restrict__ in,
                                                            const float* __restrict__ w,
                                                            float* __restrict__ out, int Ct,
                                                            float* __restrict__ ssq,
                                                            int nrmC) {
    const int gy0 = blockIdx.x * 16;
    const int c   = blockIdx.y;
    const int b   = blockIdx.z;
    const int tid = threadIdx.x;

    __shared__ float ts[20][136];

    const ushort_t* ib = in + ((size_t)b * Ct + c) * Nn;
    iel7_stage(ts, ib, gy0, tid);
    __syncthreads();

    float wl[9];
    #pragma unroll
    for (int k = 0; k < 9; ++k) wl[k] = w[c * 9 + k];

    float* ob = out + ((size_t)b * Ct + c) * Nn;
    float s2sum = 0.f;
    #pragma unroll
    for (int it = 0; it < 2; ++it) {
        int idx = tid + it * 256;
        int r = idx >> 5;            // 0..15
        int s = idx & 31;            // 4-px strip
        float a[4] = {0.f, 0.f, 0.f, 0.f};
        #pragma unroll
        for (int dy = 0; dy < 3; ++dy) {
            const float* row = &ts[r + 1 + dy][4 * s];
            float4 e0 = *(const float4*)row;
            float4 e1 = *(const float4*)(row + 4);
            float4 e2 = *(const float4*)(row + 8);
            float e[12] = {e0.x, e0.y, e0.z, e0.w, e1.x, e1.y, e1.z, e1.w,
                           e2.x, e2.y, e2.z, e2.w};
            float w0 = wl[dy * 3], w1 = wl[dy * 3 + 1], w2 = wl[dy * 3 + 2];
            #pragma unroll
            for (int p = 0; p < 4; ++p)
                a[p] += w0 * e[p + 3] + w1 * e[p + 4] + w2 * e[p + 5];
        }
        float4 st; st.x = a[0]; st.y = a[1]; st.z = a[2]; st.w = a[3];
        *(float4*)(ob + (gy0 + r) * Wb + 4 * s) = st;
        s2sum += a[0] * a[0] + a[1] * a[1] + a[2] * a[2] + a[3] * a[3];
    }

    if (ssq != nullptr && c < nrmC) {
        #pragma unroll
        for (int o = 32; o > 0; o >>= 1) s2sum += __shfl_xor(s2sum, o, 64);
        if ((tid & 63) == 0) atomicAdd(&ssq[(size_t)b * nrmC + c], s2sum);
    }
}

// ---------------------------------------------------------------------------
// L2 normalize along N (in-place, tier-2). grid: (Cc, 1, Bt).
// ---------------------------------------------------------------------------
__global__ __launch_bounds__(256) void l2norm_kernel(float* __restrict__ data, int cstride) {
    int b = blockIdx.z, c = blockIdx.x;
    float* ptr = data + ((size_t)b * cstride + c) * Nn;
    int t = threadIdx.x;
    float s = 0.f;
    for (int i = t; i < Nn; i += 256) { float v = ptr[i]; s += v * v; }
    __shared__ float red[256];
    red[t] = s; __syncthreads();
    for (int st = 128; st > 0; st >>= 1) { if (t < st) red[t] += red[t + st]; __syncthreads(); }
    float scale = 1.0f / fmaxf(sqrtf(red[0]), 1e-12f);
    for (int i = t; i < Nn; i += 256) ptr[i] *= scale;
}

// ---------------------------------------------------------------------------
// Gate stage 2 + final.
// ---------------------------------------------------------------------------
__global__ __launch_bounds__(256) void gate2_kernel(const float* __restrict__ gmid,
                                                    const float* __restrict__ w2,
                                                    const float* __restrict__ b2,
                                                    float* __restrict__ blocksums,
                                                    int out_off) {
    int p = blockIdx.x * 256 + threadIdx.x;
    int b = blockIdx.z;
    float acc = b2[0];
    const float* ib = gmid + (size_t)b * 64 * Nn + p;
    #pragma unroll 8
    for (int ci = 0; ci < 64; ++ci) acc += ib[(size_t)ci * Nn] * w2[ci];
    float g = 1.0f / (1.0f + expf(-acc));
    __shared__ float red[256];
    int t = threadIdx.x;
    red[t] = g; __syncthreads();
    for (int st = 128; st > 0; st >>= 1) { if (t < st) red[t] += red[t + st]; __syncthreads(); }
    if (t == 0) blocksums[out_off + b * 64 + blockIdx.x] = red[0];
}

__global__ void gate_final_kernel(const float* __restrict__ blocksums,
                                  int* __restrict__ dk_out) {
    __shared__ double sred[256];
    int t = threadIdx.x;
    sred[t] = (double)blocksums[t];
    __syncthreads();
    for (int st = 128; st > 0; st >>= 1) { if (t < st) sred[t] += sred[t + st]; __syncthreads(); }
    if (t == 0) {
        double mean = sred[0] / (double)(Bn * Nn);
        float val = 16.0f * (float)mean;
        int dk = (int)val;
        if (dk < 1) dk = 1;
        if (dk > 16) dk = 16;
        *dk_out = dk;
    }
}

// ---------------------------------------------------------------------------
// QK^T partial (f32). grid: (NS, HEADS, Bt).
// ---------------------------------------------------------------------------
__global__ __launch_bounds__(256) void attn_qk_partial_kernel(const float* __restrict__ q,
                                                              const float* __restrict__ k,
                                                              int kstride,
                                                              float* __restrict__ partial) {
    int ns = blockIdx.x, h = blockIdx.y, b = blockIdx.z;
    int t = threadIdx.x;
    int c = t >> 4, d = t & 15;
    __shared__ float qs[16][65];
    __shared__ float ks[16][65];
    const float* qb = q + ((size_t)b * Cc + h * CHh) * Nn;
    const float* kb = k + ((size_t)b * kstride + h * CHh) * Nn;
    float acc = 0.f;
    int nbeg = ns * (Nn / NS);
    for (int n0 = nbeg; n0 < nbeg + (Nn / NS); n0 += 64) {
        for (int idx = t; idx < 1024; idx += 256) {
            int r = idx >> 6, col = idx & 63;
            qs[r][col] = qb[(size_t)r * Nn + n0 + col];
            ks[r][col] = kb[(size_t)r * Nn + n0 + col];
        }
        __syncthreads();
        #pragma unroll
        for (int j = 0; j < 64; ++j) acc += qs[c][j] * ks[d][j];
        __syncthreads();
    }
    partial[(((size_t)(b * HEADS + h)) * NS + ns) * 256 + t] = acc;
}

// reduce + temperature + (optional) fused L2-norm scaling.
__global__ __launch_bounds__(256) void attn_reduce_kernel(const float* __restrict__ partial,
                                                          const float* __restrict__ temp,
                                                          const float* __restrict__ qss,
                                                          const float* __restrict__ kss,
                                                          float* __restrict__ attnp) {
    int bh = blockIdx.x;
    int h = bh % HEADS;
    int t = threadIdx.x;
    const float* pp = partial + (size_t)bh * NS * 256 + t;
    float s = 0.f;
    #pragma unroll 8
    for (int ns = 0; ns < NS; ++ns) s += pp[(size_t)ns * 256];
    float scale = temp[h];
    if (qss != nullptr) {
        int b  = bh / HEADS;
        int cQ = h * CHh + (t >> 4);
        int cK = h * CHh + (t & 15);
        float nq = fmaxf(sqrtf(qss[(size_t)b * Cc + cQ]), 1e-12f);
        float nk = fmaxf(sqrtf(kss[(size_t)b * Cc + cK]), 1e-12f);
        scale = scale / (nq * nk);
    }
    attnp[(size_t)bh * 256 + t] = s * scale;
}

__global__ void topk_softmax_kernel(float* __restrict__ attnp, const int* __restrict__ dkp) {
    int bh = blockIdx.x;
    int c = threadIdx.x;
    if (c >= 16) return;
    float* row = attnp + ((size_t)bh * CHh + c) * CHh;
    float a[16];
    #pragma unroll
    for (int d = 0; d < 16; ++d) a[d] = row[d];
    int dk = *dkp;
    unsigned keep = 0;
    float m = -INFINITY;
    #pragma unroll
    for (int d = 0; d < 16; ++d) {
        int rank = 0;
        #pragma unroll
        for (int j = 0; j < 16; ++j)
            rank += (a[j] > a[d]) || (a[j] == a[d] && j < d);
        if (rank < dk) { keep |= (1u << d); m = fmaxf(m, a[d]); }
    }
    float e[16]; float s = 0.f;
    #pragma unroll
    for (int d = 0; d < 16; ++d) {
        e[d] = (keep >> d & 1u) ? expf(a[d] - m) : 0.f;
        s += e[d];
    }
    float invs = 1.0f / s;
    #pragma unroll
    for (int d = 0; d < 16; ++d) row[d] = e[d] * invs;
}

// attn_v: f32 out (tier-2)
__global__ __launch_bounds__(256) void attn_v_kernel(const float* __restrict__ attnp,
                                                     const float* __restrict__ v,
                                                     float* __restrict__ out) {
    int p = blockIdx.x * 256 + threadIdx.x;
    int cg = blockIdx.y;
    int b = blockIdx.z;
    int h = cg >> 4, cr = cg & 15;
    const float* arow = attnp + (((size_t)b * HEADS + h) * CHh + cr) * CHh;
    const float* vb = v + ((size_t)b * Cc + h * CHh) * Nn + p;
    float acc = 0.f;
    #pragma unroll
    for (int d = 0; d < 16; ++d) acc += arow[d] * vb[(size_t)d * Nn];
    out[((size_t)b * Cc + cg) * Nn + p] = acc;
}

// attn_v: bf16 out.
__global__ __launch_bounds__(256) void attn_v_bf16_kernel(const float* __restrict__ attnp,
                                                          const float* __restrict__ v,
                                                          int vstride, int voff,
                                                          ushort_t* __restrict__ out) {
    int p = blockIdx.x * 256 + threadIdx.x;
    int cg = blockIdx.y;
    int b = blockIdx.z;
    int h = cg >> 4, cr = cg & 15;
    const float* arow = attnp + (((size_t)b * HEADS + h) * CHh + cr) * CHh;
    const float* vb = v + ((size_t)b * vstride + voff + h * CHh) * Nn + p;
    float acc = 0.f;
    #pragma unroll
    for (int d = 0; d < 16; ++d) acc += arow[d] * vb[(size_t)d * Nn];
    out[((size_t)b * Cc + cg) * Nn + p] = f2bf(acc);
}

// ---------------------------------------------------------------------------
// Fused IEL tail v4 + fast_tanh: the proven 94.6 µs structure (round 0),
// with ocml tanhf replaced by exp-based fast_tanh (VALU saving).
// ts col j <-> gx = j-1 (j 0..129 valid; j=0 & 129 zero). stride 132.
// us col j <-> gx = j-1.
// grid: (Hh/16, HID, Bt), block 256. LDS ~40 KB.
// ---------------------------------------------------------------------------
__global__ __launch_bounds__(256) void iel_tail_v4_kernel(const ushort_t* __restrict__ Th,
                                                          const float* __restrict__ dww,
                                                          const float* __restrict__ dw1p,
                                                          const float* __restrict__ dw2p,
                                                          ushort_t* __restrict__ PRh) {
    const int gy0 = blockIdx.x * 16;
    const int c   = blockIdx.y;
    const int b   = blockIdx.z;
    const int tid = threadIdx.x;

    __shared__ float ts[2][20][132];
    __shared__ float us[2][18][132];

    const ushort_t* t1 = Th + ((size_t)b * HID2 + c) * Nn;
    const ushort_t* t2 = Th + ((size_t)b * HID2 + HID + c) * Nn;

    // stage: 2 tensors x 20 rows x 16 segs of 8 px. ts[j] with j = gx+1.
    for (int idx = tid; idx < 640; idx += 256) {
        int ti  = idx / 320;
        int rem = idx - ti * 320;
        int i   = rem >> 4;
        int seg = rem & 15;
        int gy  = gy0 - 2 + i;
        const ushort_t* tp = ti ? t2 : t1;
        float vals[8];
        if (gy >= 0 && gy < Hh) {
            uint4 v = *(const uint4*)(tp + gy * Wb + seg * 8);
            vals[0] = bf2f((ushort_t)(v.x & 0xFFFF)); vals[1] = bf2f((ushort_t)(v.x >> 16));
            vals[2] = bf2f((ushort_t)(v.y & 0xFFFF)); vals[3] = bf2f((ushort_t)(v.y >> 16));
            vals[4] = bf2f((ushort_t)(v.z & 0xFFFF)); vals[5] = bf2f((ushort_t)(v.z >> 16));
            vals[6] = bf2f((ushort_t)(v.w & 0xFFFF)); vals[7] = bf2f((ushort_t)(v.w >> 16));
        } else {
            #pragma unroll
            for (int k = 0; k < 8; ++k) vals[k] = 0.f;
        }
        #pragma unroll
        for (int k = 0; k < 8; ++k) ts[ti][i][1 + seg * 8 + k] = vals[k];
        if (seg == 0)  ts[ti][i][0] = 0.f;
        if (seg == 15) { ts[ti][i][129] = 0.f; ts[ti][i][130] = 0.f; ts[ti][i][131] = 0.f; }
    }
    __syncthreads();

    float wA[9], wB[9], w1[9], w2[9];
    #pragma unroll
    for (int k = 0; k < 9; ++k) {
        wA[k] = dww[c * 9 + k];
        wB[k] = dww[(HID + c) * 9 + k];
        w1[k] = dw1p[c * 9 + k];
        w2[k] = dw2p[c * 9 + k];
    }

    // u-stage: 1152 strips (2 tensors x 18 rows x 32 strips of 4).
    for (int idx = tid; idx < 1152; idx += 256) {
        int ti  = idx / 576;
        int rem = idx - ti * 576;
        int i   = rem >> 5;          // row 0..17, gy = gy0-1+i
        int s   = rem & 31;          // strip, outputs j = 1+4s .. 4+4s
        int gy  = gy0 - 1 + i;
        float o0 = 0.f, o1 = 0.f, o2 = 0.f, o3 = 0.f;
        if (gy >= 0 && gy < Hh) {
            const float* wp = ti ? wB : wA;
            #pragma unroll
            for (int dy = 0; dy < 3; ++dy) {
                const float* row = &ts[ti][i + dy][4 * s];
                float4 a = *(const float4*)row;          // j0-1..j0+2
                float2 bb = *(const float2*)(row + 4);   // j0+3, j0+4
                float w0 = wp[dy * 3 + 0], w1t = wp[dy * 3 + 1], w2t = wp[dy * 3 + 2];
                o0 += w0 * a.x + w1t * a.y + w2t * a.z;
                o1 += w0 * a.y + w1t * a.z + w2t * a.w;
                o2 += w0 * a.z + w1t * a.w + w2t * bb.x;
                o3 += w0 * a.w + w1t * bb.x + w2t * bb.y;
            }
        }
        int j0 = 1 + 4 * s;
        us[ti][i][j0]     = o0;
        us[ti][i][j0 + 1] = o1;
        us[ti][i][j0 + 2] = o2;
        us[ti][i][j0 + 3] = o3;
    }
    // edge zeros: us[ti][i][0] and us[ti][i][129]
    if (tid < 72) {
        int ti = tid / 36;
        int r  = tid - ti * 36;
        int i  = r >> 1;
        us[ti][i][(r & 1) ? 129 : 0] = 0.f;
    }
    __syncthreads();

    // final: 512 strips (16 rows x 32 strips of 4 px).
    ushort_t* outp = PRh + ((size_t)b * HID + c) * Nn;
    for (int idx = tid; idx < 512; idx += 256) {
        int r  = idx >> 5;           // tile row, gy = gy0 + r
        int s  = idx & 31;
        int x0 = 4 * s;
        float s1a[4] = {0.f, 0.f, 0.f, 0.f};
        float s2a[4] = {0.f, 0.f, 0.f, 0.f};
        float c1a[4], c2a[4];
        #pragma unroll
        for (int dy = 0; dy < 3; ++dy) {
            const float* r0 = &us[0][r + dy][x0];
            float4 a0 = *(const float4*)r0;
            float2 b0 = *(const float2*)(r0 + 4);
            const float* r1 = &us[1][r + dy][x0];
            float4 a1 = *(const float4*)r1;
            float2 b1 = *(const float2*)(r1 + 4);
            float w10 = w1[dy * 3], w11 = w1[dy * 3 + 1], w12 = w1[dy * 3 + 2];
            float w20 = w2[dy * 3], w21 = w2[dy * 3 + 1], w22 = w2[dy * 3 + 2];
            s1a[0] += w10 * a0.x + w11 * a0.y + w12 * a0.z;
            s1a[1] += w10 * a0.y + w11 * a0.z + w12 * a0.w;
            s1a[2] += w10 * a0.z + w11 * a0.w + w12 * b0.x;
            s1a[3] += w10 * a0.w + w11 * b0.x + w12 * b0.y;
            s2a[0] += w20 * a1.x + w21 * a1.y + w22 * a1.z;
            s2a[1] += w20 * a1.y + w21 * a1.z + w22 * a1.w;
            s2a[2] += w20 * a1.z + w21 * a1.w + w22 * b1.x;
            s2a[3] += w20 * a1.w + w21 * b1.x + w22 * b1.y;
            if (dy == 1) {
                c1a[0] = a0.y; c1a[1] = a0.z; c1a[2] = a0.w; c1a[3] = b0.x;
                c2a[0] = a1.y; c2a[1] = a1.z; c2a[2] = a1.w; c2a[3] = b1.x;
            }
        }
        uint2 pk;
        float v0 = (fast_tanh(s1a[0]) + c1a[0]) * (fast_tanh(s2a[0]) + c2a[0]);
        float v1 = (fast_tanh(s1a[1]) + c1a[1]) * (fast_tanh(s2a[1]) + c2a[1]);
        float v2 = (fast_tanh(s1a[2]) + c1a[2]) * (fast_tanh(s2a[2]) + c2a[2]);
        float v3 = (fast_tanh(s1a[3]) + c1a[3]) * (fast_tanh(s2a[3]) + c2a[3]);
        pk.x = (unsigned)f2bf(v0) | ((unsigned)f2bf(v1) << 16);
        pk.y = (unsigned)f2bf(v2) | ((unsigned)f2bf(v3) << 16);
        *(uint2*)(outp + (gy0 + r) * Wb + x0) = pk;
    }
}

// f32 IEL tail (tier-2 fallback; per-chunk layout).
__global__ __launch_bounds__(256) void iel_tail_f32_kernel(const float* __restrict__ t1p,
                                                           const float* __restrict__ t2p,
                                                           const float* __restrict__ dwA,
                                                           const float* __restrict__ dwB,
                                                           const float* __restrict__ dw1p,
                                                           const float* __restrict__ dw2p,
                                                           float* __restrict__ prod) {
    const int c = blockIdx.y;
    const int tilesx = Wb / 16;
    const int ty0 = (blockIdx.x / tilesx) * 16;
    const int tx0 = (blockIdx.x % tilesx) * 16;
    const int tid = threadIdx.x;

    __shared__ float ts[2][20][24];
    __shared__ float us[2][18][24];

    const float* t1 = t1p + (size_t)c * Nn;
    const float* t2 = t2p + (size_t)c * Nn;

    for (int idx = tid; idx < 400; idx += 256) {
        int i = idx / 20, j = idx % 20;
        int gy = ty0 - 2 + i, gx = tx0 - 2 + j;
        bool ok = (gy >= 0 && gy < Hh && gx >= 0 && gx < Wb);
        ts[0][i][j] = ok ? t1[gy * Wb + gx] : 0.f;
        ts[1][i][j] = ok ? t2[gy * Wb + gx] : 0.f;
    }
    __syncthreads();

    float wA[9], wB[9], w1[9], w2[9];
    #pragma unroll
    for (int k = 0; k < 9; ++k) {
        wA[k] = dwA[c * 9 + k];
        wB[k] = dwB[c * 9 + k];
        w1[k] = dw1p[c * 9 + k];
        w2[k] = dw2p[c * 9 + k];
    }

    for (int idx = tid; idx < 324; idx += 256) {
        int i = idx / 18, j = idx % 18;
        int gy = ty0 - 1 + i, gx = tx0 - 1 + j;
        float a0 = 0.f, a1 = 0.f;
        if (gy >= 0 && gy < Hh && gx >= 0 && gx < Wb) {
            #pragma unroll
            for (int dy = 0; dy < 3; ++dy)
                #pragma unroll
                for (int dx = 0; dx < 3; ++dx) {
                    a0 += wA[dy * 3 + dx] * ts[0][i + dy][j + dx];
                    a1 += wB[dy * 3 + dx] * ts[1][i + dy][j + dx];
                }
        }
        us[0][i][j] = a0;
        us[1][i][j] = a1;
    }
    __syncthreads();

    int ty = tid >> 4, tx = tid & 15;
    float c1 = us[0][ty + 1][tx + 1];
    float c2 = us[1][ty + 1][tx + 1];
    float s1 = 0.f, s2 = 0.f;
    #pragma unroll
    for (int dy = 0; dy < 3; ++dy)
        #pragma unroll
        for (int dx = 0; dx < 3; ++dx) {
            s1 += w1[dy * 3 + dx] * us[0][ty + dy][tx + dx];
            s2 += w2[dy * 3 + dx] * us[1][ty + dy][tx + dx];
        }
    float x1t = tanhf(s1) + c1;
    float x2t = tanhf(s2) + c2;
    prod[(size_t)c * Nn + (ty0 + ty) * Wb + (tx0 + tx)] = x1t * x2t;
}

// ---------------------------------------------------------------------------
// Host launcher
// ---------------------------------------------------------------------------
extern "C" void kernel_launch(void* const* d_in, const int* in_sizes, int n_in,
                              void* d_out, int out_size, void* d_ws, size_t ws_size,
                              hipStream_t stream) {
    const float* x      = (const float*)d_in[0];
    const float* y      = (const float*)d_in[1];
    const float* ln_w   = (const float*)d_in[2];
    const float* ln_b   = (const float*)d_in[3];
    const float* temp   = (const float*)d_in[4];
    const float* q_w    = (const float*)d_in[5];
    const float* qdw_w  = (const float*)d_in[6];
    const float* kv_w   = (const float*)d_in[7];
    const float* kvdw_w = (const float*)d_in[8];
    const float* po_w   = (const float*)d_in[9];
    const float* g1_w   = (const float*)d_in[10];
    const float* g1_b   = (const float*)d_in[11];
    const float* g2_w   = (const float*)d_in[12];
    const float* g2_b   = (const float*)d_in[13];
    const float* pin_w  = (const float*)d_in[14];
    const float* dw_w   = (const float*)d_in[15];
    const float* dw1_w  = (const float*)d_in[16];
    const float* dw2_w  = (const float*)d_in[17];
    const float* pout_w = (const float*)d_in[18];
    float* out = (float*)d_out;

    // smalls in first 1 MiB
    char* ws = (char*)d_ws;
    float* attn      = (float*)ws;                        // 32 KB
    float* blocksums = (float*)(ws + 32768);              // 1 KB
    int*   dk        = (int*)(ws + 33792);
    ushort_t* qWh  = (ushort_t*)(ws + 34816);             // 128x128
    ushort_t* kvWh = qWh + 16384;                         // 256x128
    ushort_t* poWh = kvWh + 32768;                        // 128x128
    ushort_t* g1Wh = poWh + 16384;                        // 64x128
    ushort_t* Wh1  = g1Wh + 8192;                         // 704x128
    ushort_t* Wh2  = Wh1 + (size_t)MPAD * Cc;             // 128x352
    float* qss = (float*)(ws + 458752);                   // [Bn][128] sumsq(q)
    float* kss = (float*)(ws + 460800);                   // [Bn][128] sumsq(k)
    float* pool    = (float*)(ws + (1u << 20));

    const size_t CN    = (size_t)Cc * Nn;
    const size_t SLOT1 = (size_t)Bn * CN;
    const size_t TIER1_NEED = 65536 + 6 * SLOT1 * 4;

    dim3 blk(256);
    const int PGX = Nn / 1024;

    if (ws_size >= TIER1_NEED) {
        // ---- buffers ----
        float* S3 = pool;                                  // q2 f32 [B][128][Nn]
        float* S4 = pool + 8 * 1024 * 1024;                // k2+v2 f32 [B][256][Nn]
        ushort_t* XNh  = (ushort_t*)(pool + 24 * 1024 * 1024);
        ushort_t* YNh  = XNh + Bn * CN;
        ushort_t* KV1h = YNh + Bn * CN;
        ushort_t* Q1h  = KV1h + 2 * Bn * CN;
        float* gmid    = (float*)Q1h;
        float* partial = gmid;
        ushort_t* AOh  = XNh;

        wconv_pad_rows_kernel<<<dim3(64), blk, 0, stream>>>(q_w, qWh, 128, Cc);
        wconv_pad_rows_kernel<<<dim3(128), blk, 0, stream>>>(kv_w, kvWh, 256, Cc);
        wconv_pad_rows_kernel<<<dim3(64), blk, 0, stream>>>(po_w, poWh, 128, Cc);
        wconv_pad_rows_kernel<<<dim3(32), blk, 0, stream>>>(g1_w, g1Wh, 64, Cc);
        wconv_pad_rows_kernel<<<dim3(MPAD * Cc / 256), blk, 0, stream>>>(pin_w, Wh1, HID2, Cc);
        wconv_pad_cols_kernel<<<dim3(Cc * KPAD2 / 256), blk, 0, stream>>>(pout_w, Wh2, HID, KPAD2);
        zero_f32_kernel<<<dim3(4), blk, 0, stream>>>(qss, 2 * Bn * Cc);  // qss+kss contiguous

        // ---- Phase A ----
        ln_bf16_kernel<<<dim3(Nn / 256, 1, Bn), blk, 0, stream>>>(x, ln_w, ln_b, XNh);
        ln_bf16_kernel<<<dim3(Nn / 256, 1, Bn), blk, 0, stream>>>(y, ln_w, ln_b, YNh);

        gemm_bf16_kernel<<<dim3(Nn / 128, 2, Bn), blk, 0, stream>>>(
            XNh, qWh, nullptr, nullptr, nullptr, Q1h, Cc, Cc, Cc, 0);
        dw3x3_bf16_v3_kernel<<<dim3(Hh / 16, Cc, Bn), blk, 0, stream>>>(
            Q1h, qdw_w, S3, Cc, qss, Cc);

        gemm_bf16_kernel<<<dim3(Nn / 128, 4, Bn), blk, 0, stream>>>(
            YNh, kvWh, nullptr, nullptr, nullptr, KV1h, Cc, Cc, 2 * Cc, 0);
        dw3x3_bf16_v3_kernel<<<dim3(Hh / 16, 2 * Cc, Bn), blk, 0, stream>>>(
            KV1h, kvdw_w, S4, 2 * Cc, kss, Cc);

        gemm_bf16_kernel<<<dim3(Nn / 128, 1, Bn), blk, 0, stream>>>(
            XNh, g1Wh, g1_b, nullptr, gmid, nullptr, Cc, Cc, 64, 1);
        gate2_kernel<<<dim3(Nn / 256, 1, Bn), blk, 0, stream>>>(gmid, g2_w, g2_b, blocksums, 0);
        gate_final_kernel<<<dim3(1), blk, 0, stream>>>(blocksums, dk);

        // L2 norms folded into attn_reduce via qss/kss (no l2norm passes).
        attn_qk_partial_kernel<<<dim3(NS, HEADS, Bn), blk, 0, stream>>>(S3, S4, 2 * Cc, partial);
        attn_reduce_kernel<<<dim3(Bn * HEADS), blk, 0, stream>>>(partial, temp, qss, kss, attn);
        topk_softmax_kernel<<<dim3(Bn * HEADS), dim3(16), 0, stream>>>(attn, dk);
        attn_v_bf16_kernel<<<dim3(Nn / 256, Cc, Bn), blk, 0, stream>>>(
            attn, S4, 2 * Cc, Cc, AOh);

        gemm_bf16_kernel<<<dim3(Nn / 128, 2, Bn), blk, 0, stream>>>(
            AOh, poWh, nullptr, x, out, nullptr, Cc, Cc, Cc, 0);

        // ---- Phase B ----
        ushort_t* ZNh = (ushort_t*)pool;
        ushort_t* Th  = ZNh + Bn * CN;
        ushort_t* PRh = Th + (size_t)Bn * HID2 * Nn;

        ln_bf16_kernel<<<dim3(Nn / 256, 1, Bn), blk, 0, stream>>>(out, ln_w, ln_b, ZNh);

        gemm_bf16_kernel<<<dim3(Nn / 128, MPAD / 64, Bn), blk, 0, stream>>>(
            ZNh, Wh1, nullptr, nullptr, nullptr, Th, Cc, Cc, HID2, 0);

        iel_tail_v4_kernel<<<dim3(Hh / 16, HID, Bn), blk, 0, stream>>>(
            Th, dw_w, dw1_w, dw2_w, PRh);

        gemm_bf16_kernel<<<dim3(Nn / 128, 2, Bn), blk, 0, stream>>>(
            PRh, Wh2, nullptr, out, out, nullptr, HID, KPAD2, Cc, 0);
    } else {
        // ================= Tier 2: per-batch f32 fallback ===================
        float* s0 = pool;
        float* s1 = pool + 1 * CN;
        float* s2 = pool + 2 * CN;
        float* s3 = pool + 3 * CN;
        float* s4 = pool + 4 * CN;
        float* s5 = pool + 5 * CN;

        for (int b = 0; b < Bn; ++b) {
            const float* xb = x + (size_t)b * CN;
            ln_kernel<<<dim3(Nn / 256, 1, 1), blk, 0, stream>>>(xb, ln_w, ln_b, s0);
            conv1x1v_kernel<4><<<dim3(PGX, 16, 1), blk, 0, stream>>>(
                s0, g1_w, Cc, g1_b, nullptr, s1, Cc, 64, 1);
            gate2_kernel<<<dim3(Nn / 256, 1, 1), blk, 0, stream>>>(
                s1, g2_w, g2_b, blocksums, b * 64);
        }
        gate_final_kernel<<<dim3(1), blk, 0, stream>>>(blocksums, dk);

        for (int b = 0; b < Bn; ++b) {
            const float* xb = x + (size_t)b * CN;
            const float* yb = y + (size_t)b * CN;
            float* outb = out + (size_t)b * CN;
            float* attnb = attn + (size_t)b * HEADS * CHh * CHh;

            ln_kernel<<<dim3(Nn / 256, 1, 1), blk, 0, stream>>>(xb, ln_w, ln_b, s0);
            ln_kernel<<<dim3(Nn / 256, 1, 1), blk, 0, stream>>>(yb, ln_w, ln_b, s1);

            conv1x1v_kernel<8><<<dim3(PGX, 16, 1), blk, 0, stream>>>(
                s0, q_w, Cc, nullptr, nullptr, s2, Cc, Cc, 0);
            dw3x3_kernel<<<dim3(Nn / 256, Cc, 1), blk, 0, stream>>>(s2, qdw_w, s3, Cc);
            l2norm_kernel<<<dim3(Cc, 1, 1), blk, 0, stream>>>(s3, Cc);

            conv1x1v_kernel<8><<<dim3(PGX, 16, 1), blk, 0, stream>>>(
                s1, kv_w, Cc, nullptr, nullptr, s2, Cc, Cc, 0);
            dw3x3_kernel<<<dim3(Nn / 256, Cc, 1), blk, 0, stream>>>(s2, kvdw_w, s4, Cc);
            l2norm_kernel<<<dim3(Cc, 1, 1), blk, 0, stream>>>(s4, Cc);

            conv1x1v_kernel<8><<<dim3(PGX, 16, 1), blk, 0, stream>>>(
                s1, kv_w + 128 * 128, Cc, nullptr, nullptr, s2, Cc, Cc, 0);
            dw3x3_kernel<<<dim3(Nn / 256, Cc, 1), blk, 0, stream>>>(s2, kvdw_w + 128 * 9, s5, Cc);

            attn_qk_partial_kernel<<<dim3(NS, HEADS, 1), blk, 0, stream>>>(s3, s4, Cc, s2);
            attn_reduce_kernel<<<dim3(HEADS), blk, 0, stream>>>(s2, temp, nullptr, nullptr, attnb);
            topk_softmax_kernel<<<dim3(HEADS), dim3(16), 0, stream>>>(attnb, dk);
            attn_v_kernel<<<dim3(Nn / 256, Cc, 1), blk, 0, stream>>>(attnb, s5, s2);

            conv1x1v_kernel<8><<<dim3(PGX, 16, 1), blk, 0, stream>>>(
                s2, po_w, Cc, nullptr, xb, outb, Cc, Cc, 0);
        }

        const int CHUNK = 170;
        const size_t TCH = (size_t)CHUNK * Nn;
        float* zn   = pool;
        float* T1   = pool + CN;
        float* T2   = T1 + TCH;
        float* prod = T2 + TCH;
        for (int b = 0; b < Bn; ++b) {
            float* outb = out + (size_t)b * CN;
            ln_kernel<<<dim3(Nn / 256, 1, 1), blk, 0, stream>>>(outb, ln_w, ln_b, zn);
            for (int c0 = 0; c0 < HID; c0 += CHUNK) {
                conv1x1v_kernel<20><<<dim3(PGX, 9, 1), blk, 0, stream>>>(
                    zn, pin_w + (size_t)c0 * Cc, Cc, nullptr, nullptr, T1, Cc, CHUNK, 0);
                conv1x1v_kernel<20><<<dim3(PGX, 9, 1), blk, 0, stream>>>(
                    zn, pin_w + (size_t)(HID + c0) * Cc, Cc, nullptr, nullptr, T2, Cc, CHUNK, 0);
                iel_tail_f32_kernel<<<dim3(64, CHUNK, 1), blk, 0, stream>>>(
                    T1, T2, dw_w + c0 * 9, dw_w + (HID + c0) * 9,
                    dw1_w + c0 * 9, dw2_w + c0 * 9, prod);
                conv1x1v_kernel<8><<<dim3(PGX, 16, 1), blk, 0, stream>>>(
                    prod, pout_w + c0, HID, nullptr, outb, outb, CHUNK, Cc, 0);
            }
        }
    }
}

// Round 9
// 616.371 us; speedup vs baseline: 1.0546x; 1.0205x over previous
//
#include <hip/hip_runtime.h>
#include <math.h>

// Problem constants
static constexpr int Bn    = 4;
static constexpr int Cc    = 128;
static constexpr int Hh    = 128;
static constexpr int Wb    = 128;
static constexpr int Nn    = Hh * Wb;      // 16384
static constexpr int HEADS = 8;
static constexpr int CHh   = 16;
static constexpr int HID   = 340;
static constexpr int HID2  = 680;
static constexpr int NS    = 64;
static constexpr int MPAD  = 704;          // pin M padded (680 -> 44*16)
static constexpr int KPAD2 = 352;          // pout K padded (340 -> 11*32)

typedef unsigned short ushort_t;
typedef __attribute__((ext_vector_type(8))) short short8;
typedef __attribute__((ext_vector_type(4))) float f32x4;

__device__ __forceinline__ ushort_t f2bf(float f) {
    unsigned u = __float_as_uint(f);
    return (ushort_t)((u + 0x7FFFu + ((u >> 16) & 1u)) >> 16);   // RNE
}
__device__ __forceinline__ float bf2f(ushort_t h) {
    return __uint_as_float(((unsigned)h) << 16);
}

// fast tanh: tanh(x) = 1 - 2/(e^{2|x|}+1), sign-restored.
__device__ __forceinline__ float fast_tanh(float x) {
    float a = fabsf(x);
    a = fminf(a, 12.0f);
    float e = __expf(2.0f * a);
    float r = 1.0f - 2.0f * __builtin_amdgcn_rcpf(e + 1.0f);
    return x < 0.0f ? -r : r;
}

// ---------------------------------------------------------------------------
// Conflict-free staging helper:
//   ts[20][136]: ts[i][c] = t(gy0-2+i, c-4), data c = 4..131, zeros at
//   c=0..3 and 132..135. Aligned float4, lane stride 16 B.
// ---------------------------------------------------------------------------
__device__ __forceinline__ void iel7_stage(float (*ts)[136], const ushort_t* __restrict__ tp,
                                           int gy0, int tid) {
    for (int idx = tid; idx < 640; idx += 256) {
        int i = idx >> 5;
        int s = idx & 31;
        int gy = gy0 - 2 + i;
        float4 v; v.x = 0.f; v.y = 0.f; v.z = 0.f; v.w = 0.f;
        if (gy >= 0 && gy < Hh) {
            uint2 u = *(const uint2*)(tp + gy * Wb + 4 * s);
            v.x = bf2f((ushort_t)(u.x & 0xFFFF)); v.y = bf2f((ushort_t)(u.x >> 16));
            v.z = bf2f((ushort_t)(u.y & 0xFFFF)); v.w = bf2f((ushort_t)(u.y >> 16));
        }
        *(float4*)&ts[i][4 + 4 * s] = v;
        if (s == 0) {
            float4 z; z.x = 0.f; z.y = 0.f; z.z = 0.f; z.w = 0.f;
            *(float4*)&ts[i][0] = z;
        }
        if (s == 31) {
            float4 z; z.x = 0.f; z.y = 0.f; z.z = 0.f; z.w = 0.f;
            *(float4*)&ts[i][132] = z;
        }
    }
}

// ---------------------------------------------------------------------------
// LayerNorm over channel axis, f32 out (tier-2). grid: (Nn/256, 1, Bt).
// ---------------------------------------------------------------------------
__global__ __launch_bounds__(256) void ln_kernel(const float* __restrict__ in,
                                                 const float* __restrict__ w,
                                                 const float* __restrict__ bias,
                                                 float* __restrict__ out) {
    int p = blockIdx.x * 256 + threadIdx.x;
    int b = blockIdx.z;
    const float* ib = in + (size_t)b * Cc * Nn + p;
    float s = 0.f, s2 = 0.f;
    #pragma unroll 8
    for (int c = 0; c < Cc; ++c) {
        float v = ib[(size_t)c * Nn];
        s += v; s2 += v * v;
    }
    float mean = s * (1.0f / Cc);
    float var  = s2 * (1.0f / Cc) - mean * mean;
    float inv  = 1.0f / sqrtf(var + 1e-6f);
    float* ob = out + (size_t)b * Cc * Nn + p;
    #pragma unroll 8
    for (int c = 0; c < Cc; ++c) {
        float v = ib[(size_t)c * Nn];
        ob[(size_t)c * Nn] = w[c] * ((v - mean) * inv) + bias[c];
    }
}

// LayerNorm writing bf16 (feeds MFMA GEMMs).
__global__ __launch_bounds__(256) void ln_bf16_kernel(const float* __restrict__ in,
                                                      const float* __restrict__ w,
                                                      const float* __restrict__ bias,
                                                      ushort_t* __restrict__ out) {
    int p = blockIdx.x * 256 + threadIdx.x;
    int b = blockIdx.z;
    const float* ib = in + (size_t)b * Cc * Nn + p;
    float s = 0.f, s2 = 0.f;
    #pragma unroll 8
    for (int c = 0; c < Cc; ++c) {
        float v = ib[(size_t)c * Nn];
        s += v; s2 += v * v;
    }
    float mean = s * (1.0f / Cc);
    float var  = s2 * (1.0f / Cc) - mean * mean;
    float inv  = 1.0f / sqrtf(var + 1e-6f);
    ushort_t* ob = out + (size_t)b * Cc * Nn + p;
    #pragma unroll 8
    for (int c = 0; c < Cc; ++c) {
        float v = ib[(size_t)c * Nn];
        ob[(size_t)c * Nn] = f2bf(w[c] * ((v - mean) * inv) + bias[c]);
    }
}

// ---------------------------------------------------------------------------
// Weight conversion f32 -> bf16 (+ padding variants).
// ---------------------------------------------------------------------------
__global__ __launch_bounds__(256) void wconv_pad_rows_kernel(const float* __restrict__ w,
                                                             ushort_t* __restrict__ o,
                                                             int rows, int K) {
    int idx = blockIdx.x * 256 + threadIdx.x;
    int r = idx / K, k = idx - r * K;
    o[idx] = (r < rows) ? f2bf(w[(size_t)r * K + k]) : (ushort_t)0;
}
__global__ __launch_bounds__(256) void wconv_pad_cols_kernel(const float* __restrict__ w,
                                                             ushort_t* __restrict__ o,
                                                             int K, int Kp) {
    int idx = blockIdx.x * 256 + threadIdx.x;
    int r = idx / Kp, k = idx - r * Kp;
    o[idx] = (k < K) ? f2bf(w[(size_t)r * K + k]) : (ushort_t)0;
}

// Zero a small f32 buffer (for ssq atomics).
__global__ __launch_bounds__(256) void zero_f32_kernel(float* __restrict__ p, int n) {
    int i = blockIdx.x * 256 + threadIdx.x;
    if (i < n) p[i] = 0.f;
}

// ---------------------------------------------------------------------------
// bf16 MFMA GEMM v2: out[b,co,p] = sum_ci W[co,ci] * Z[b,ci,p]
// ---------------------------------------------------------------------------
__global__ __launch_bounds__(256) void gemm_bf16_kernel(const ushort_t* __restrict__ Zh,
                                                        const ushort_t* __restrict__ Wh,
                                                        const float* __restrict__ bias,
                                                        const float* __restrict__ res,
                                                        float* outf,
                                                        ushort_t* outh,
                                                        int Cin, int Kpad, int Mreal,
                                                        int act) {
    const int b    = blockIdx.z;
    const int px0  = blockIdx.x * 128;
    const int co0  = blockIdx.y * 64;
    const int tid  = threadIdx.x;
    const int wv   = tid >> 6;
    const int lane = tid & 63;
    const int n    = lane & 15;
    const int q    = lane >> 4;

    __shared__ ushort_t Bl[128][40];

    const ushort_t* Zb = Zh + (size_t)b * Cin * Nn;

    f32x4 acc[4][2];
    #pragma unroll
    for (int i = 0; i < 4; ++i)
        #pragma unroll
        for (int j = 0; j < 2; ++j) acc[i][j] = (f32x4){0.f, 0.f, 0.f, 0.f};

    for (int k0 = 0; k0 < Kpad; k0 += 32) {
        {
            int r = tid >> 3;        // k row 0..31
            int s = tid & 7;         // 16-px chunk
            int ci = k0 + r;
            ushort_t tmp[16];
            if (ci < Cin) {
                const ushort_t* src = Zb + (size_t)ci * Nn + px0 + s * 16;
                uint4 v0 = *(const uint4*)src;
                uint4 v1 = *(const uint4*)(src + 8);
                tmp[0]  = (ushort_t)(v0.x & 0xFFFF); tmp[1]  = (ushort_t)(v0.x >> 16);
                tmp[2]  = (ushort_t)(v0.y & 0xFFFF); tmp[3]  = (ushort_t)(v0.y >> 16);
                tmp[4]  = (ushort_t)(v0.z & 0xFFFF); tmp[5]  = (ushort_t)(v0.z >> 16);
                tmp[6]  = (ushort_t)(v0.w & 0xFFFF); tmp[7]  = (ushort_t)(v0.w >> 16);
                tmp[8]  = (ushort_t)(v1.x & 0xFFFF); tmp[9]  = (ushort_t)(v1.x >> 16);
                tmp[10] = (ushort_t)(v1.y & 0xFFFF); tmp[11] = (ushort_t)(v1.y >> 16);
                tmp[12] = (ushort_t)(v1.z & 0xFFFF); tmp[13] = (ushort_t)(v1.z >> 16);
                tmp[14] = (ushort_t)(v1.w & 0xFFFF); tmp[15] = (ushort_t)(v1.w >> 16);
            } else {
                #pragma unroll
                for (int i = 0; i < 16; ++i) tmp[i] = 0;
            }
            #pragma unroll
            for (int i = 0; i < 16; ++i) Bl[s * 16 + i][r] = tmp[i];
        }
        __syncthreads();

        short8 bfrag[2];
        #pragma unroll
        for (int px16 = 0; px16 < 2; ++px16)
            bfrag[px16] = *(const short8*)&Bl[wv * 32 + px16 * 16 + n][q * 8];
        #pragma unroll
        for (int mt = 0; mt < 4; ++mt) {
            const ushort_t* wp = Wh + (size_t)(co0 + mt * 16 + n) * Kpad + k0 + q * 8;
            short8 afrag = *(const short8*)wp;
            #pragma unroll
            for (int px16 = 0; px16 < 2; ++px16)
                acc[mt][px16] = __builtin_amdgcn_mfma_f32_16x16x32_bf16(
                    afrag, bfrag[px16], acc[mt][px16], 0, 0, 0);
        }
        __syncthreads();
    }

    #pragma unroll
    for (int px16 = 0; px16 < 2; ++px16) {
        int px = px0 + wv * 32 + px16 * 16 + n;
        #pragma unroll
        for (int mt = 0; mt < 4; ++mt) {
            #pragma unroll
            for (int reg = 0; reg < 4; ++reg) {
                int co = co0 + mt * 16 + q * 4 + reg;
                if (co < Mreal) {
                    float v = acc[mt][px16][reg];
                    if (bias) v += bias[co];
                    if (act == 1) v = fmaxf(v, 0.f);
                    size_t o = ((size_t)b * Mreal + co) * Nn + px;
                    if (res)  v += res[o];
                    if (outf) outf[o] = v;
                    if (outh) outh[o] = f2bf(v);
                }
            }
        }
    }
}

// ---------------------------------------------------------------------------
// Vectorized f32 1x1 conv (tier-2 only).
// ---------------------------------------------------------------------------
template <int TCO>
__global__ __launch_bounds__(256) void conv1x1v_kernel(const float* __restrict__ in,
                                                       const float* __restrict__ wgt,
                                                       int wstride,
                                                       const float* __restrict__ bias,
                                                       const float* __restrict__ res,
                                                       float* __restrict__ out,
                                                       int Cin, int Cout, int act) {
    int pg  = blockIdx.x * 256 + threadIdx.x;
    int b   = blockIdx.z;
    int co0 = blockIdx.y * TCO;

    const float* wrow[TCO];
    #pragma unroll
    for (int i = 0; i < TCO; ++i) {
        int co = co0 + i; if (co > Cout - 1) co = Cout - 1;
        wrow[i] = wgt + (size_t)co * wstride;
    }

    float4 acc[TCO];
    #pragma unroll
    for (int i = 0; i < TCO; ++i) acc[i] = make_float4(0.f, 0.f, 0.f, 0.f);

    const float* ib = in + (size_t)b * Cin * Nn + (size_t)pg * 4;
    #pragma unroll 8
    for (int ci = 0; ci < Cin; ++ci) {
        float4 v = *(const float4*)(ib + (size_t)ci * Nn);
        #pragma unroll
        for (int i = 0; i < TCO; ++i) {
            float w = wrow[i][ci];
            acc[i].x += v.x * w; acc[i].y += v.y * w;
            acc[i].z += v.z * w; acc[i].w += v.w * w;
        }
    }

    #pragma unroll
    for (int i = 0; i < TCO; ++i) {
        int co = co0 + i;
        if (co < Cout) {
            float4 r = acc[i];
            if (bias) { float bb = bias[co]; r.x += bb; r.y += bb; r.z += bb; r.w += bb; }
            if (act == 1) {
                r.x = fmaxf(r.x, 0.f); r.y = fmaxf(r.y, 0.f);
                r.z = fmaxf(r.z, 0.f); r.w = fmaxf(r.w, 0.f);
            }
            size_t o = ((size_t)b * Cout + co) * Nn + (size_t)pg * 4;
            if (res) {
                float4 rv = *(const float4*)(res + o);
                r.x += rv.x; r.y += rv.y; r.z += rv.z; r.w += rv.w;
            }
            *(float4*)(out + o) = r;
        }
    }
}

// ---------------------------------------------------------------------------
// Depthwise 3x3 f32 (tier-2).
// ---------------------------------------------------------------------------
__global__ __launch_bounds__(256) void dw3x3_kernel(const float* __restrict__ in,
                                                    const float* __restrict__ w,
                                                    float* __restrict__ out, int Ct) {
    int p = blockIdx.x * 256 + threadIdx.x;
    int c = blockIdx.y;
    int b = blockIdx.z;
    int y = p >> 7, x = p & (Wb - 1);
    const float* ib = in + ((size_t)b * Ct + c) * Nn;
    float wl[9];
    #pragma unroll
    for (int k = 0; k < 9; ++k) wl[k] = w[c * 9 + k];
    float acc = 0.f;
    #pragma unroll
    for (int dy = 0; dy < 3; ++dy) {
        int yy = y + dy - 1;
        if (yy < 0 || yy >= Hh) continue;
        #pragma unroll
        for (int dx = 0; dx < 3; ++dx) {
            int xx = x + dx - 1;
            if (xx < 0 || xx >= Wb) continue;
            acc += wl[dy * 3 + dx] * ib[yy * Wb + xx];
        }
    }
    out[((size_t)b * Ct + c) * Nn + p] = acc;
}

// ---------------------------------------------------------------------------
// Depthwise 3x3 bf16-in/BF16-OUT v5: conflict-free 4-px-per-lane LDS pattern,
// packed bf16 stores (halves write traffic for q/k/v intermediates),
// barrier-free ssq from the f32 accumulator (pre-rounding).
// grid: (Hh/16, Ct, Bt), block 256. LDS 10880 B.
// ---------------------------------------------------------------------------
__global__ __launch_bounds__(256) void dw3x3_bf16_v5_kernel(const ushort_t* __restrict__ in,
                                                            const float* __restrict__ w,
                                                            ushort_t* __restrict__ out, int Ct,
                                                            float* __restrict__ ssq,
                                                            int nrmC) {
    const int gy0 = blockIdx.x * 16;
    const int c   = blockIdx.y;
    const int b   = blockIdx.z;
    const int tid = threadIdx.x;

    __shared__ float ts[20][136];

    const ushort_t* ib = in + ((size_t)b * Ct + c) * Nn;
    iel7_stage(ts, ib, gy0, tid);
    __syncthreads();

    float wl[9];
    #pragma unroll
    for (int k = 0; k < 9; ++k) wl[k] = w[c * 9 + k];

    ushort_t* ob = out + ((size_t)b * Ct + c) * Nn;
    float s2sum = 0.f;
    #pragma unroll
    for (int it = 0; it < 2; ++it) {
        int idx = tid + it * 256;
        int r = idx >> 5;            // 0..15
        int s = idx & 31;            // 4-px strip
        float a[4] = {0.f, 0.f, 0.f, 0.f};
        #pragma unroll
        for (int dy = 0; dy < 3; ++dy) {
            const float* row = &ts[r + 1 + dy][4 * s];
            float4 e0 = *(const float4*)row;
            float4 e1 = *(const float4*)(row + 4);
            float4 e2 = *(const float4*)(row + 8);
            float e[12] = {e0.x, e0.y, e0.z, e0.w, e1.x, e1.y, e1.z, e1.w,
                           e2.x, e2.y, e2.z, e2.w};
            float w0 = wl[dy * 3], w1 = wl[dy * 3 + 1], w2 = wl[dy * 3 + 2];
            #pragma unroll
            for (int p = 0; p < 4; ++p)
                a[p] += w0 * e[p + 3] + w1 * e[p + 4] + w2 * e[p + 5];
        }
        uint2 pk;
        pk.x = (unsigned)f2bf(a[0]) | ((unsigned)f2bf(a[1]) << 16);
        pk.y = (unsigned)f2bf(a[2]) | ((unsigned)f2bf(a[3]) << 16);
        *(uint2*)(ob + (gy0 + r) * Wb + 4 * s) = pk;
        s2sum += a[0] * a[0] + a[1] * a[1] + a[2] * a[2] + a[3] * a[3];
    }

    if (ssq != nullptr && c < nrmC) {
        #pragma unroll
        for (int o = 32; o > 0; o >>= 1) s2sum += __shfl_xor(s2sum, o, 64);
        if ((tid & 63) == 0) atomicAdd(&ssq[(size_t)b * nrmC + c], s2sum);
    }
}

// ---------------------------------------------------------------------------
// L2 normalize along N (in-place, tier-2). grid: (Cc, 1, Bt).
// ---------------------------------------------------------------------------
__global__ __launch_bounds__(256) void l2norm_kernel(float* __restrict__ data, int cstride) {
    int b = blockIdx.z, c = blockIdx.x;
    float* ptr = data + ((size_t)b * cstride + c) * Nn;
    int t = threadIdx.x;
    float s = 0.f;
    for (int i = t; i < Nn; i += 256) { float v = ptr[i]; s += v * v; }
    __shared__ float red[256];
    red[t] = s; __syncthreads();
    for (int st = 128; st > 0; st >>= 1) { if (t < st) red[t] += red[t + st]; __syncthreads(); }
    float scale = 1.0f / fmaxf(sqrtf(red[0]), 1e-12f);
    for (int i = t; i < Nn; i += 256) ptr[i] *= scale;
}

// ---------------------------------------------------------------------------
// Gate stage 2 + final.
// ---------------------------------------------------------------------------
__global__ __launch_bounds__(256) void gate2_kernel(const float* __restrict__ gmid,
                                                    const float* __restrict__ w2,
                                                    const float* __restrict__ b2,
                                                    float* __restrict__ blocksums,
                                                    int out_off) {
    int p = blockIdx.x * 256 + threadIdx.x;
    int b = blockIdx.z;
    float acc = b2[0];
    const float* ib = gmid + (size_t)b * 64 * Nn + p;
    #pragma unroll 8
    for (int ci = 0; ci < 64; ++ci) acc += ib[(size_t)ci * Nn] * w2[ci];
    float g = 1.0f / (1.0f + expf(-acc));
    __shared__ float red[256];
    int t = threadIdx.x;
    red[t] = g; __syncthreads();
    for (int st = 128; st > 0; st >>= 1) { if (t < st) red[t] += red[t + st]; __syncthreads(); }
    if (t == 0) blocksums[out_off + b * 64 + blockIdx.x] = red[0];
}

__global__ void gate_final_kernel(const float* __restrict__ blocksums,
                                  int* __restrict__ dk_out) {
    __shared__ double sred[256];
    int t = threadIdx.x;
    sred[t] = (double)blocksums[t];
    __syncthreads();
    for (int st = 128; st > 0; st >>= 1) { if (t < st) sred[t] += sred[t + st]; __syncthreads(); }
    if (t == 0) {
        double mean = sred[0] / (double)(Bn * Nn);
        float val = 16.0f * (float)mean;
        int dk = (int)val;
        if (dk < 1) dk = 1;
        if (dk > 16) dk = 16;
        *dk_out = dk;
    }
}

// ---------------------------------------------------------------------------
// QK^T partial, f32 in (tier-2). grid: (NS, HEADS, Bt).
// ---------------------------------------------------------------------------
__global__ __launch_bounds__(256) void attn_qk_partial_kernel(const float* __restrict__ q,
                                                              const float* __restrict__ k,
                                                              int kstride,
                                                              float* __restrict__ partial) {
    int ns = blockIdx.x, h = blockIdx.y, b = blockIdx.z;
    int t = threadIdx.x;
    int c = t >> 4, d = t & 15;
    __shared__ float qs[16][65];
    __shared__ float ks[16][65];
    const float* qb = q + ((size_t)b * Cc + h * CHh) * Nn;
    const float* kb = k + ((size_t)b * kstride + h * CHh) * Nn;
    float acc = 0.f;
    int nbeg = ns * (Nn / NS);
    for (int n0 = nbeg; n0 < nbeg + (Nn / NS); n0 += 64) {
        for (int idx = t; idx < 1024; idx += 256) {
            int r = idx >> 6, col = idx & 63;
            qs[r][col] = qb[(size_t)r * Nn + n0 + col];
            ks[r][col] = kb[(size_t)r * Nn + n0 + col];
        }
        __syncthreads();
        #pragma unroll
        for (int j = 0; j < 64; ++j) acc += qs[c][j] * ks[d][j];
        __syncthreads();
    }
    partial[(((size_t)(b * HEADS + h)) * NS + ns) * 256 + t] = acc;
}

// QK^T partial, bf16 in (tier-1). Same structure; f32 LDS + f32 accumulate.
__global__ __launch_bounds__(256) void attn_qk_partial_h_kernel(const ushort_t* __restrict__ q,
                                                                const ushort_t* __restrict__ k,
                                                                int kstride,
                                                                float* __restrict__ partial) {
    int ns = blockIdx.x, h = blockIdx.y, b = blockIdx.z;
    int t = threadIdx.x;
    int c = t >> 4, d = t & 15;
    __shared__ float qs[16][65];
    __shared__ float ks[16][65];
    const ushort_t* qb = q + ((size_t)b * Cc + h * CHh) * Nn;
    const ushort_t* kb = k + ((size_t)b * kstride + h * CHh) * Nn;
    float acc = 0.f;
    int nbeg = ns * (Nn / NS);
    for (int n0 = nbeg; n0 < nbeg + (Nn / NS); n0 += 64) {
        for (int idx = t; idx < 1024; idx += 256) {
            int r = idx >> 6, col = idx & 63;
            qs[r][col] = bf2f(qb[(size_t)r * Nn + n0 + col]);
            ks[r][col] = bf2f(kb[(size_t)r * Nn + n0 + col]);
        }
        __syncthreads();
        #pragma unroll
        for (int j = 0; j < 64; ++j) acc += qs[c][j] * ks[d][j];
        __syncthreads();
    }
    partial[(((size_t)(b * HEADS + h)) * NS + ns) * 256 + t] = acc;
}

// reduce + temperature + (optional) fused L2-norm scaling.
__global__ __launch_bounds__(256) void attn_reduce_kernel(const float* __restrict__ partial,
                                                          const float* __restrict__ temp,
                                                          const float* __restrict__ qss,
                                                          const float* __restrict__ kss,
                                                          float* __restrict__ attnp) {
    int bh = blockIdx.x;
    int h = bh % HEADS;
    int t = threadIdx.x;
    const float* pp = partial + (size_t)bh * NS * 256 + t;
    float s = 0.f;
    #pragma unroll 8
    for (int ns = 0; ns < NS; ++ns) s += pp[(size_t)ns * 256];
    float scale = temp[h];
    if (qss != nullptr) {
        int b  = bh / HEADS;
        int cQ = h * CHh + (t >> 4);
        int cK = h * CHh + (t & 15);
        float nq = fmaxf(sqrtf(qss[(size_t)b * Cc + cQ]), 1e-12f);
        float nk = fmaxf(sqrtf(kss[(size_t)b * Cc + cK]), 1e-12f);
        scale = scale / (nq * nk);
    }
    attnp[(size_t)bh * 256 + t] = s * scale;
}

__global__ void topk_softmax_kernel(float* __restrict__ attnp, const int* __restrict__ dkp) {
    int bh = blockIdx.x;
    int c = threadIdx.x;
    if (c >= 16) return;
    float* row = attnp + ((size_t)bh * CHh + c) * CHh;
    float a[16];
    #pragma unroll
    for (int d = 0; d < 16; ++d) a[d] = row[d];
    int dk = *dkp;
    unsigned keep = 0;
    float m = -INFINITY;
    #pragma unroll
    for (int d = 0; d < 16; ++d) {
        int rank = 0;
        #pragma unroll
        for (int j = 0; j < 16; ++j)
            rank += (a[j] > a[d]) || (a[j] == a[d] && j < d);
        if (rank < dk) { keep |= (1u << d); m = fmaxf(m, a[d]); }
    }
    float e[16]; float s = 0.f;
    #pragma unroll
    for (int d = 0; d < 16; ++d) {
        e[d] = (keep >> d & 1u) ? expf(a[d] - m) : 0.f;
        s += e[d];
    }
    float invs = 1.0f / s;
    #pragma unroll
    for (int d = 0; d < 16; ++d) row[d] = e[d] * invs;
}

// attn_v: f32 out (tier-2)
__global__ __launch_bounds__(256) void attn_v_kernel(const float* __restrict__ attnp,
                                                     const float* __restrict__ v,
                                                     float* __restrict__ out) {
    int p = blockIdx.x * 256 + threadIdx.x;
    int cg = blockIdx.y;
    int b = blockIdx.z;
    int h = cg >> 4, cr = cg & 15;
    const float* arow = attnp + (((size_t)b * HEADS + h) * CHh + cr) * CHh;
    const float* vb = v + ((size_t)b * Cc + h * CHh) * Nn + p;
    float acc = 0.f;
    #pragma unroll
    for (int d = 0; d < 16; ++d) acc += arow[d] * vb[(size_t)d * Nn];
    out[((size_t)b * Cc + cg) * Nn + p] = acc;
}

// attn_v: bf16 in, bf16 out (tier-1).
__global__ __launch_bounds__(256) void attn_v_bf16_kernel(const float* __restrict__ attnp,
                                                          const ushort_t* __restrict__ v,
                                                          int vstride, int voff,
                                                          ushort_t* __restrict__ out) {
    int p = blockIdx.x * 256 + threadIdx.x;
    int cg = blockIdx.y;
    int b = blockIdx.z;
    int h = cg >> 4, cr = cg & 15;
    const float* arow = attnp + (((size_t)b * HEADS + h) * CHh + cr) * CHh;
    const ushort_t* vb = v + ((size_t)b * vstride + voff + h * CHh) * Nn + p;
    float acc = 0.f;
    #pragma unroll
    for (int d = 0; d < 16; ++d) acc += arow[d] * bf2f(vb[(size_t)d * Nn]);
    out[((size_t)b * Cc + cg) * Nn + p] = f2bf(acc);
}

// ---------------------------------------------------------------------------
// Fused IEL tail v4 + fast_tanh (proven structure).
// ts col j <-> gx = j-1 (j 0..129 valid; j=0 & 129 zero). stride 132.
// grid: (Hh/16, HID, Bt), block 256. LDS ~40 KB.
// ---------------------------------------------------------------------------
__global__ __launch_bounds__(256) void iel_tail_v4_kernel(const ushort_t* __restrict__ Th,
                                                          const float* __restrict__ dww,
                                                          const float* __restrict__ dw1p,
                                                          const float* __restrict__ dw2p,
                                                          ushort_t* __restrict__ PRh) {
    const int gy0 = blockIdx.x * 16;
    const int c   = blockIdx.y;
    const int b   = blockIdx.z;
    const int tid = threadIdx.x;

    __shared__ float ts[2][20][132];
    __shared__ float us[2][18][132];

    const ushort_t* t1 = Th + ((size_t)b * HID2 + c) * Nn;
    const ushort_t* t2 = Th + ((size_t)b * HID2 + HID + c) * Nn;

    // stage: 2 tensors x 20 rows x 16 segs of 8 px. ts[j] with j = gx+1.
    for (int idx = tid; idx < 640; idx += 256) {
        int ti  = idx / 320;
        int rem = idx - ti * 320;
        int i   = rem >> 4;
        int seg = rem & 15;
        int gy  = gy0 - 2 + i;
        const ushort_t* tp = ti ? t2 : t1;
        float vals[8];
        if (gy >= 0 && gy < Hh) {
            uint4 v = *(const uint4*)(tp + gy * Wb + seg * 8);
            vals[0] = bf2f((ushort_t)(v.x & 0xFFFF)); vals[1] = bf2f((ushort_t)(v.x >> 16));
            vals[2] = bf2f((ushort_t)(v.y & 0xFFFF)); vals[3] = bf2f((ushort_t)(v.y >> 16));
            vals[4] = bf2f((ushort_t)(v.z & 0xFFFF)); vals[5] = bf2f((ushort_t)(v.z >> 16));
            vals[6] = bf2f((ushort_t)(v.w & 0xFFFF)); vals[7] = bf2f((ushort_t)(v.w >> 16));
        } else {
            #pragma unroll
            for (int k = 0; k < 8; ++k) vals[k] = 0.f;
        }
        #pragma unroll
        for (int k = 0; k < 8; ++k) ts[ti][i][1 + seg * 8 + k] = vals[k];
        if (seg == 0)  ts[ti][i][0] = 0.f;
        if (seg == 15) { ts[ti][i][129] = 0.f; ts[ti][i][130] = 0.f; ts[ti][i][131] = 0.f; }
    }
    __syncthreads();

    float wA[9], wB[9], w1[9], w2[9];
    #pragma unroll
    for (int k = 0; k < 9; ++k) {
        wA[k] = dww[c * 9 + k];
        wB[k] = dww[(HID + c) * 9 + k];
        w1[k] = dw1p[c * 9 + k];
        w2[k] = dw2p[c * 9 + k];
    }

    // u-stage: 1152 strips (2 tensors x 18 rows x 32 strips of 4).
    for (int idx = tid; idx < 1152; idx += 256) {
        int ti  = idx / 576;
        int rem = idx - ti * 576;
        int i   = rem >> 5;          // row 0..17, gy = gy0-1+i
        int s   = rem & 31;          // strip, outputs j = 1+4s .. 4+4s
        int gy  = gy0 - 1 + i;
        float o0 = 0.f, o1 = 0.f, o2 = 0.f, o3 = 0.f;
        if (gy >= 0 && gy < Hh) {
            const float* wp = ti ? wB : wA;
            #pragma unroll
            for (int dy = 0; dy < 3; ++dy) {
                const float* row = &ts[ti][i + dy][4 * s];
                float4 a = *(const float4*)row;          // j0-1..j0+2
                float2 bb = *(const float2*)(row + 4);   // j0+3, j0+4
                float w0 = wp[dy * 3 + 0], w1t = wp[dy * 3 + 1], w2t = wp[dy * 3 + 2];
                o0 += w0 * a.x + w1t * a.y + w2t * a.z;
                o1 += w0 * a.y + w1t * a.z + w2t * a.w;
                o2 += w0 * a.z + w1t * a.w + w2t * bb.x;
                o3 += w0 * a.w + w1t * bb.x + w2t * bb.y;
            }
        }
        int j0 = 1 + 4 * s;
        us[ti][i][j0]     = o0;
        us[ti][i][j0 + 1] = o1;
        us[ti][i][j0 + 2] = o2;
        us[ti][i][j0 + 3] = o3;
    }
    // edge zeros: us[ti][i][0] and us[ti][i][129]
    if (tid < 72) {
        int ti = tid / 36;
        int r  = tid - ti * 36;
        int i  = r >> 1;
        us[ti][i][(r & 1) ? 129 : 0] = 0.f;
    }
    __syncthreads();

    // final: 512 strips (16 rows x 32 strips of 4 px).
    ushort_t* outp = PRh + ((size_t)b * HID + c) * Nn;
    for (int idx = tid; idx < 512; idx += 256) {
        int r  = idx >> 5;           // tile row, gy = gy0 + r
        int s  = idx & 31;
        int x0 = 4 * s;
        float s1a[4] = {0.f, 0.f, 0.f, 0.f};
        float s2a[4] = {0.f, 0.f, 0.f, 0.f};
        float c1a[4], c2a[4];
        #pragma unroll
        for (int dy = 0; dy < 3; ++dy) {
            const float* r0 = &us[0][r + dy][x0];
            float4 a0 = *(const float4*)r0;
            float2 b0 = *(const float2*)(r0 + 4);
            const float* r1 = &us[1][r + dy][x0];
            float4 a1 = *(const float4*)r1;
            float2 b1 = *(const float2*)(r1 + 4);
            float w10 = w1[dy * 3], w11 = w1[dy * 3 + 1], w12 = w1[dy * 3 + 2];
            float w20 = w2[dy * 3], w21 = w2[dy * 3 + 1], w22 = w2[dy * 3 + 2];
            s1a[0] += w10 * a0.x + w11 * a0.y + w12 * a0.z;
            s1a[1] += w10 * a0.y + w11 * a0.z + w12 * a0.w;
            s1a[2] += w10 * a0.z + w11 * a0.w + w12 * b0.x;
            s1a[3] += w10 * a0.w + w11 * b0.x + w12 * b0.y;
            s2a[0] += w20 * a1.x + w21 * a1.y + w22 * a1.z;
            s2a[1] += w20 * a1.y + w21 * a1.z + w22 * a1.w;
            s2a[2] += w20 * a1.z + w21 * a1.w + w22 * b1.x;
            s2a[3] += w20 * a1.w + w21 * b1.x + w22 * b1.y;
            if (dy == 1) {
                c1a[0] = a0.y; c1a[1] = a0.z; c1a[2] = a0.w; c1a[3] = b0.x;
                c2a[0] = a1.y; c2a[1] = a1.z; c2a[2] = a1.w; c2a[3] = b1.x;
            }
        }
        uint2 pk;
        float v0 = (fast_tanh(s1a[0]) + c1a[0]) * (fast_tanh(s2a[0]) + c2a[0]);
        float v1 = (fast_tanh(s1a[1]) + c1a[1]) * (fast_tanh(s2a[1]) + c2a[1]);
        float v2 = (fast_tanh(s1a[2]) + c1a[2]) * (fast_tanh(s2a[2]) + c2a[2]);
        float v3 = (fast_tanh(s1a[3]) + c1a[3]) * (fast_tanh(s2a[3]) + c2a[3]);
        pk.x = (unsigned)f2bf(v0) | ((unsigned)f2bf(v1) << 16);
        pk.y = (unsigned)f2bf(v2) | ((unsigned)f2bf(v3) << 16);
        *(uint2*)(outp + (gy0 + r) * Wb + x0) = pk;
    }
}

// f32 IEL tail (tier-2 fallback; per-chunk layout).
__global__ __launch_bounds__(256) void iel_tail_f32_kernel(const float* __restrict__ t1p,
                                                           const float* __restrict__ t2p,
                                                           const float* __restrict__ dwA,
                                                           const float* __restrict__ dwB,
                                                           const float* __restrict__ dw1p,
                                                           const float* __restrict__ dw2p,
                                                           float* __restrict__ prod) {
    const int c = blockIdx.y;
    const int tilesx = Wb / 16;
    const int ty0 = (blockIdx.x / tilesx) * 16;
    const int tx0 = (blockIdx.x % tilesx) * 16;
    const int tid = threadIdx.x;

    __shared__ float ts[2][20][24];
    __shared__ float us[2][18][24];

    const float* t1 = t1p + (size_t)c * Nn;
    const float* t2 = t2p + (size_t)c * Nn;

    for (int idx = tid; idx < 400; idx += 256) {
        int i = idx / 20, j = idx % 20;
        int gy = ty0 - 2 + i, gx = tx0 - 2 + j;
        bool ok = (gy >= 0 && gy < Hh && gx >= 0 && gx < Wb);
        ts[0][i][j] = ok ? t1[gy * Wb + gx] : 0.f;
        ts[1][i][j] = ok ? t2[gy * Wb + gx] : 0.f;
    }
    __syncthreads();

    float wA[9], wB[9], w1[9], w2[9];
    #pragma unroll
    for (int k = 0; k < 9; ++k) {
        wA[k] = dwA[c * 9 + k];
        wB[k] = dwB[c * 9 + k];
        w1[k] = dw1p[c * 9 + k];
        w2[k] = dw2p[c * 9 + k];
    }

    for (int idx = tid; idx < 324; idx += 256) {
        int i = idx / 18, j = idx % 18;
        int gy = ty0 - 1 + i, gx = tx0 - 1 + j;
        float a0 = 0.f, a1 = 0.f;
        if (gy >= 0 && gy < Hh && gx >= 0 && gx < Wb) {
            #pragma unroll
            for (int dy = 0; dy < 3; ++dy)
                #pragma unroll
                for (int dx = 0; dx < 3; ++dx) {
                    a0 += wA[dy * 3 + dx] * ts[0][i + dy][j + dx];
                    a1 += wB[dy * 3 + dx] * ts[1][i + dy][j + dx];
                }
        }
        us[0][i][j] = a0;
        us[1][i][j] = a1;
    }
    __syncthreads();

    int ty = tid >> 4, tx = tid & 15;
    float c1 = us[0][ty + 1][tx + 1];
    float c2 = us[1][ty + 1][tx + 1];
    float s1 = 0.f, s2 = 0.f;
    #pragma unroll
    for (int dy = 0; dy < 3; ++dy)
        #pragma unroll
        for (int dx = 0; dx < 3; ++dx) {
            s1 += w1[dy * 3 + dx] * us[0][ty + dy][tx + dx];
            s2 += w2[dy * 3 + dx] * us[1][ty + dy][tx + dx];
        }
    float x1t = tanhf(s1) + c1;
    float x2t = tanhf(s2) + c2;
    prod[(size_t)c * Nn + (ty0 + ty) * Wb + (tx0 + tx)] = x1t * x2t;
}

// ---------------------------------------------------------------------------
// Host launcher
// ---------------------------------------------------------------------------
extern "C" void kernel_launch(void* const* d_in, const int* in_sizes, int n_in,
                              void* d_out, int out_size, void* d_ws, size_t ws_size,
                              hipStream_t stream) {
    const float* x      = (const float*)d_in[0];
    const float* y      = (const float*)d_in[1];
    const float* ln_w   = (const float*)d_in[2];
    const float* ln_b   = (const float*)d_in[3];
    const float* temp   = (const float*)d_in[4];
    const float* q_w    = (const float*)d_in[5];
    const float* qdw_w  = (const float*)d_in[6];
    const float* kv_w   = (const float*)d_in[7];
    const float* kvdw_w = (const float*)d_in[8];
    const float* po_w   = (const float*)d_in[9];
    const float* g1_w   = (const float*)d_in[10];
    const float* g1_b   = (const float*)d_in[11];
    const float* g2_w   = (const float*)d_in[12];
    const float* g2_b   = (const float*)d_in[13];
    const float* pin_w  = (const float*)d_in[14];
    const float* dw_w   = (const float*)d_in[15];
    const float* dw1_w  = (const float*)d_in[16];
    const float* dw2_w  = (const float*)d_in[17];
    const float* pout_w = (const float*)d_in[18];
    float* out = (float*)d_out;

    // smalls in first 1 MiB
    char* ws = (char*)d_ws;
    float* attn      = (float*)ws;                        // 32 KB
    float* blocksums = (float*)(ws + 32768);              // 1 KB
    int*   dk        = (int*)(ws + 33792);
    ushort_t* qWh  = (ushort_t*)(ws + 34816);             // 128x128
    ushort_t* kvWh = qWh + 16384;                         // 256x128
    ushort_t* poWh = kvWh + 32768;                        // 128x128
    ushort_t* g1Wh = poWh + 16384;                        // 64x128
    ushort_t* Wh1  = g1Wh + 8192;                         // 704x128
    ushort_t* Wh2  = Wh1 + (size_t)MPAD * Cc;             // 128x352
    float* qss = (float*)(ws + 458752);                   // [Bn][128] sumsq(q)
    float* kss = (float*)(ws + 460800);                   // [Bn][128] sumsq(k)
    float* pool    = (float*)(ws + (1u << 20));

    const size_t CN    = (size_t)Cc * Nn;
    const size_t SLOT1 = (size_t)Bn * CN;
    const size_t TIER1_NEED = 65536 + 6 * SLOT1 * 4;

    dim3 blk(256);
    const int PGX = Nn / 1024;

    if (ws_size >= TIER1_NEED) {
        // ---- buffers ----
        ushort_t* S3h = (ushort_t*)pool;                   // q2 bf16 [B][128][Nn], 16.8 MB
        ushort_t* S4h = (ushort_t*)(pool + 8 * 1024 * 1024); // k2+v2 bf16 [B][256][Nn], 33.6 MB
        ushort_t* XNh  = (ushort_t*)(pool + 24 * 1024 * 1024);
        ushort_t* YNh  = XNh + Bn * CN;
        ushort_t* KV1h = YNh + Bn * CN;
        ushort_t* Q1h  = KV1h + 2 * Bn * CN;
        float* gmid    = (float*)Q1h;
        float* partial = gmid;
        ushort_t* AOh  = XNh;

        wconv_pad_rows_kernel<<<dim3(64), blk, 0, stream>>>(q_w, qWh, 128, Cc);
        wconv_pad_rows_kernel<<<dim3(128), blk, 0, stream>>>(kv_w, kvWh, 256, Cc);
        wconv_pad_rows_kernel<<<dim3(64), blk, 0, stream>>>(po_w, poWh, 128, Cc);
        wconv_pad_rows_kernel<<<dim3(32), blk, 0, stream>>>(g1_w, g1Wh, 64, Cc);
        wconv_pad_rows_kernel<<<dim3(MPAD * Cc / 256), blk, 0, stream>>>(pin_w, Wh1, HID2, Cc);
        wconv_pad_cols_kernel<<<dim3(Cc * KPAD2 / 256), blk, 0, stream>>>(pout_w, Wh2, HID, KPAD2);
        zero_f32_kernel<<<dim3(4), blk, 0, stream>>>(qss, 2 * Bn * Cc);  // qss+kss contiguous

        // ---- Phase A ----
        ln_bf16_kernel<<<dim3(Nn / 256, 1, Bn), blk, 0, stream>>>(x, ln_w, ln_b, XNh);
        ln_bf16_kernel<<<dim3(Nn / 256, 1, Bn), blk, 0, stream>>>(y, ln_w, ln_b, YNh);

        gemm_bf16_kernel<<<dim3(Nn / 128, 2, Bn), blk, 0, stream>>>(
            XNh, qWh, nullptr, nullptr, nullptr, Q1h, Cc, Cc, Cc, 0);
        dw3x3_bf16_v5_kernel<<<dim3(Hh / 16, Cc, Bn), blk, 0, stream>>>(
            Q1h, qdw_w, S3h, Cc, qss, Cc);

        gemm_bf16_kernel<<<dim3(Nn / 128, 4, Bn), blk, 0, stream>>>(
            YNh, kvWh, nullptr, nullptr, nullptr, KV1h, Cc, Cc, 2 * Cc, 0);
        dw3x3_bf16_v5_kernel<<<dim3(Hh / 16, 2 * Cc, Bn), blk, 0, stream>>>(
            KV1h, kvdw_w, S4h, 2 * Cc, kss, Cc);

        gemm_bf16_kernel<<<dim3(Nn / 128, 1, Bn), blk, 0, stream>>>(
            XNh, g1Wh, g1_b, nullptr, gmid, nullptr, Cc, Cc, 64, 1);
        gate2_kernel<<<dim3(Nn / 256, 1, Bn), blk, 0, stream>>>(gmid, g2_w, g2_b, blocksums, 0);
        gate_final_kernel<<<dim3(1), blk, 0, stream>>>(blocksums, dk);

        // L2 norms folded into attn_reduce via qss/kss (no l2norm passes).
        attn_qk_partial_h_kernel<<<dim3(NS, HEADS, Bn), blk, 0, stream>>>(
            S3h, S4h, 2 * Cc, partial);
        attn_reduce_kernel<<<dim3(Bn * HEADS), blk, 0, stream>>>(partial, temp, qss, kss, attn);
        topk_softmax_kernel<<<dim3(Bn * HEADS), dim3(16), 0, stream>>>(attn, dk);
        attn_v_bf16_kernel<<<dim3(Nn / 256, Cc, Bn), blk, 0, stream>>>(
            attn, S4h, 2 * Cc, Cc, AOh);

        gemm_bf16_kernel<<<dim3(Nn / 128, 2, Bn), blk, 0, stream>>>(
            AOh, poWh, nullptr, x, out, nullptr, Cc, Cc, Cc, 0);

        // ---- Phase B ----
        ushort_t* ZNh = (ushort_t*)pool;
        ushort_t* Th  = ZNh + Bn * CN;
        ushort_t* PRh = Th + (size_t)Bn * HID2 * Nn;

        ln_bf16_kernel<<<dim3(Nn / 256, 1, Bn), blk, 0, stream>>>(out, ln_w, ln_b, ZNh);

        gemm_bf16_kernel<<<dim3(Nn / 128, MPAD / 64, Bn), blk, 0, stream>>>(
            ZNh, Wh1, nullptr, nullptr, nullptr, Th, Cc, Cc, HID2, 0);

        iel_tail_v4_kernel<<<dim3(Hh / 16, HID, Bn), blk, 0, stream>>>(
            Th, dw_w, dw1_w, dw2_w, PRh);

        gemm_bf16_kernel<<<dim3(Nn / 128, 2, Bn), blk, 0, stream>>>(
            PRh, Wh2, nullptr, out, out, nullptr, HID, KPAD2, Cc, 0);
    } else {
        // ================= Tier 2: per-batch f32 fallback ===================
        float* s0 = pool;
        float* s1 = pool + 1 * CN;
        float* s2 = pool + 2 * CN;
        float* s3 = pool + 3 * CN;
        float* s4 = pool + 4 * CN;
        float* s5 = pool + 5 * CN;

        for (int b = 0; b < Bn; ++b) {
            const float* xb = x + (size_t)b * CN;
            ln_kernel<<<dim3(Nn / 256, 1, 1), blk, 0, stream>>>(xb, ln_w, ln_b, s0);
            conv1x1v_kernel<4><<<dim3(PGX, 16, 1), blk, 0, stream>>>(
                s0, g1_w, Cc, g1_b, nullptr, s1, Cc, 64, 1);
            gate2_kernel<<<dim3(Nn / 256, 1, 1), blk, 0, stream>>>(
                s1, g2_w, g2_b, blocksums, b * 64);
        }
        gate_final_kernel<<<dim3(1), blk, 0, stream>>>(blocksums, dk);

        for (int b = 0; b < Bn; ++b) {
            const float* xb = x + (size_t)b * CN;
            const float* yb = y + (size_t)b * CN;
            float* outb = out + (size_t)b * CN;
            float* attnb = attn + (size_t)b * HEADS * CHh * CHh;

            ln_kernel<<<dim3(Nn / 256, 1, 1), blk, 0, stream>>>(xb, ln_w, ln_b, s0);
            ln_kernel<<<dim3(Nn / 256, 1, 1), blk, 0, stream>>>(yb, ln_w, ln_b, s1);

            conv1x1v_kernel<8><<<dim3(PGX, 16, 1), blk, 0, stream>>>(
                s0, q_w, Cc, nullptr, nullptr, s2, Cc, Cc, 0);
            dw3x3_kernel<<<dim3(Nn / 256, Cc, 1), blk, 0, stream>>>(s2, qdw_w, s3, Cc);
            l2norm_kernel<<<dim3(Cc, 1, 1), blk, 0, stream>>>(s3, Cc);

            conv1x1v_kernel<8><<<dim3(PGX, 16, 1), blk, 0, stream>>>(
                s1, kv_w, Cc, nullptr, nullptr, s2, Cc, Cc, 0);
            dw3x3_kernel<<<dim3(Nn / 256, Cc, 1), blk, 0, stream>>>(s2, kvdw_w, s4, Cc);
            l2norm_kernel<<<dim3(Cc, 1, 1), blk, 0, stream>>>(s4, Cc);

            conv1x1v_kernel<8><<<dim3(PGX, 16, 1), blk, 0, stream>>>(
                s1, kv_w + 128 * 128, Cc, nullptr, nullptr, s2, Cc, Cc, 0);
            dw3x3_kernel<<<dim3(Nn / 256, Cc, 1), blk, 0, stream>>>(s2, kvdw_w + 128 * 9, s5, Cc);

            attn_qk_partial_kernel<<<dim3(NS, HEADS, 1), blk, 0, stream>>>(s3, s4, Cc, s2);
            attn_reduce_kernel<<<dim3(HEADS), blk, 0, stream>>>(s2, temp, nullptr, nullptr, attnb);
            topk_softmax_kernel<<<dim3(HEADS), dim3(16), 0, stream>>>(attnb, dk);
            attn_v_kernel<<<dim3(Nn / 256, Cc, 1), blk, 0, stream>>>(attnb, s5, s2);

            conv1x1v_kernel<8><<<dim3(PGX, 16, 1), blk, 0, stream>>>(
                s2, po_w, Cc, nullptr, xb, outb, Cc, Cc, 0);
        }

        const int CHUNK = 170;
        const size_t TCH = (size_t)CHUNK * Nn;
        float* zn   = pool;
        float* T1   = pool + CN;
        float* T2   = T1 + TCH;
        float* prod = T2 + TCH;
        for (int b = 0; b < Bn; ++b) {
            float* outb = out + (size_t)b * CN;
            ln_kernel<<<dim3(Nn / 256, 1, 1), blk, 0, stream>>>(outb, ln_w, ln_b, zn);
            for (int c0 = 0; c0 < HID; c0 += CHUNK) {
                conv1x1v_kernel<20><<<dim3(PGX, 9, 1), blk, 0, stream>>>(
                    zn, pin_w + (size_t)c0 * Cc, Cc, nullptr, nullptr, T1, Cc, CHUNK, 0);
                conv1x1v_kernel<20><<<dim3(PGX, 9, 1), blk, 0, stream>>>(
                    zn, pin_w + (size_t)(HID + c0) * Cc, Cc, nullptr, nullptr, T2, Cc, CHUNK, 0);
                iel_tail_f32_kernel<<<dim3(64, CHUNK, 1), blk, 0, stream>>>(
                    T1, T2, dw_w + c0 * 9, dw_w + (HID + c0) * 9,
                    dw1_w + c0 * 9, dw2_w + c0 * 9, prod);
                conv1x1v_kernel<8><<<dim3(PGX, 16, 1), blk, 0, stream>>>(
                    prod, pout_w + c0, HID, nullptr, outb, outb, CHUNK, Cc, 0);
            }
        }
    }
}

// Round 10
// 611.121 us; speedup vs baseline: 1.0636x; 1.0086x over previous
//
#include <hip/hip_runtime.h>
#include <math.h>

// Problem constants
static constexpr int Bn    = 4;
static constexpr int Cc    = 128;
static constexpr int Hh    = 128;
static constexpr int Wb    = 128;
static constexpr int Nn    = Hh * Wb;      // 16384
static constexpr int HEADS = 8;
static constexpr int CHh   = 16;
static constexpr int HID   = 340;
static constexpr int HID2  = 680;
static constexpr int NS    = 64;
static constexpr int MPAD  = 704;          // pin M padded (680 -> 44*16)
static constexpr int KPAD2 = 352;          // pout K padded (340 -> 11*32)

typedef unsigned short ushort_t;
typedef __attribute__((ext_vector_type(8))) short short8;
typedef __attribute__((ext_vector_type(4))) float f32x4;

__device__ __forceinline__ ushort_t f2bf(float f) {
    unsigned u = __float_as_uint(f);
    return (ushort_t)((u + 0x7FFFu + ((u >> 16) & 1u)) >> 16);   // RNE
}
__device__ __forceinline__ float bf2f(ushort_t h) {
    return __uint_as_float(((unsigned)h) << 16);
}

// fast tanh: tanh(x) = 1 - 2/(e^{2|x|}+1), sign-restored.
__device__ __forceinline__ float fast_tanh(float x) {
    float a = fabsf(x);
    a = fminf(a, 12.0f);
    float e = __expf(2.0f * a);
    float r = 1.0f - 2.0f * __builtin_amdgcn_rcpf(e + 1.0f);
    return x < 0.0f ? -r : r;
}

// ---------------------------------------------------------------------------
// Conflict-free staging helper:
//   ts[20][136]: ts[i][c] = t(gy0-2+i, c-4), data c = 4..131, zeros at
//   c=0..3 and 132..135. Aligned float4, lane stride 16 B.
// ---------------------------------------------------------------------------
__device__ __forceinline__ void iel7_stage(float (*ts)[136], const ushort_t* __restrict__ tp,
                                           int gy0, int tid) {
    for (int idx = tid; idx < 640; idx += 256) {
        int i = idx >> 5;
        int s = idx & 31;
        int gy = gy0 - 2 + i;
        float4 v; v.x = 0.f; v.y = 0.f; v.z = 0.f; v.w = 0.f;
        if (gy >= 0 && gy < Hh) {
            uint2 u = *(const uint2*)(tp + gy * Wb + 4 * s);
            v.x = bf2f((ushort_t)(u.x & 0xFFFF)); v.y = bf2f((ushort_t)(u.x >> 16));
            v.z = bf2f((ushort_t)(u.y & 0xFFFF)); v.w = bf2f((ushort_t)(u.y >> 16));
        }
        *(float4*)&ts[i][4 + 4 * s] = v;
        if (s == 0) {
            float4 z; z.x = 0.f; z.y = 0.f; z.z = 0.f; z.w = 0.f;
            *(float4*)&ts[i][0] = z;
        }
        if (s == 31) {
            float4 z; z.x = 0.f; z.y = 0.f; z.z = 0.f; z.w = 0.f;
            *(float4*)&ts[i][132] = z;
        }
    }
}

// ---------------------------------------------------------------------------
// LayerNorm over channel axis, f32 out (tier-2). grid: (Nn/256, 1, Bt).
// ---------------------------------------------------------------------------
__global__ __launch_bounds__(256) void ln_kernel(const float* __restrict__ in,
                                                 const float* __restrict__ w,
                                                 const float* __restrict__ bias,
                                                 float* __restrict__ out) {
    int p = blockIdx.x * 256 + threadIdx.x;
    int b = blockIdx.z;
    const float* ib = in + (size_t)b * Cc * Nn + p;
    float s = 0.f, s2 = 0.f;
    #pragma unroll 8
    for (int c = 0; c < Cc; ++c) {
        float v = ib[(size_t)c * Nn];
        s += v; s2 += v * v;
    }
    float mean = s * (1.0f / Cc);
    float var  = s2 * (1.0f / Cc) - mean * mean;
    float inv  = 1.0f / sqrtf(var + 1e-6f);
    float* ob = out + (size_t)b * Cc * Nn + p;
    #pragma unroll 8
    for (int c = 0; c < Cc; ++c) {
        float v = ib[(size_t)c * Nn];
        ob[(size_t)c * Nn] = w[c] * ((v - mean) * inv) + bias[c];
    }
}

// ---------------------------------------------------------------------------
// LayerNorm writing bf16, v2: 2 px per thread (float2 loads, packed uint
// stores) + 2-way channel split with LDS stat combine. Same f32 statistics.
// grid: (Nn/256, 1, Bt), block 256 (= 128 px-pairs x 2 channel halves).
// ---------------------------------------------------------------------------
__global__ __launch_bounds__(256) void ln_bf16_v2_kernel(const float* __restrict__ in,
                                                         const float* __restrict__ w,
                                                         const float* __restrict__ bias,
                                                         ushort_t* __restrict__ out) {
    const int lp = threadIdx.x & 127;      // local pair 0..127
    const int q  = threadIdx.x >> 7;       // channel half 0/1
    const int b  = blockIdx.z;
    const int px = (blockIdx.x * 128 + lp) * 2;
    const float* ib = in + (size_t)b * Cc * Nn + px;
    const int c0 = q * 64;

    float sA = 0.f, sB = 0.f, s2A = 0.f, s2B = 0.f;
    #pragma unroll 8
    for (int c = 0; c < 64; ++c) {
        float2 v = *(const float2*)(ib + (size_t)(c0 + c) * Nn);
        sA += v.x; s2A += v.x * v.x;
        sB += v.y; s2B += v.y * v.y;
    }

    __shared__ float2 redS[2][128];
    __shared__ float2 redQ[2][128];
    float2 sv; sv.x = sA; sv.y = sB;
    float2 qv; qv.x = s2A; qv.y = s2B;
    redS[q][lp] = sv;
    redQ[q][lp] = qv;
    __syncthreads();
    float2 St, Qt;
    St.x = redS[0][lp].x + redS[1][lp].x;
    St.y = redS[0][lp].y + redS[1][lp].y;
    Qt.x = redQ[0][lp].x + redQ[1][lp].x;
    Qt.y = redQ[0][lp].y + redQ[1][lp].y;

    float meanA = St.x * (1.0f / Cc);
    float meanB = St.y * (1.0f / Cc);
    float varA  = Qt.x * (1.0f / Cc) - meanA * meanA;
    float varB  = Qt.y * (1.0f / Cc) - meanB * meanB;
    float invA  = 1.0f / sqrtf(varA + 1e-6f);
    float invB  = 1.0f / sqrtf(varB + 1e-6f);

    ushort_t* ob = out + (size_t)b * Cc * Nn + px;
    #pragma unroll 8
    for (int c = 0; c < 64; ++c) {
        int ch = c0 + c;
        float2 v = *(const float2*)(ib + (size_t)ch * Nn);
        float wa = w[ch], ba = bias[ch];
        float oA = wa * ((v.x - meanA) * invA) + ba;
        float oB = wa * ((v.y - meanB) * invB) + ba;
        unsigned pk = (unsigned)f2bf(oA) | ((unsigned)f2bf(oB) << 16);
        *(unsigned*)(ob + (size_t)ch * Nn) = pk;
    }
}

// ---------------------------------------------------------------------------
// Weight conversion f32 -> bf16 (+ padding variants).
// ---------------------------------------------------------------------------
__global__ __launch_bounds__(256) void wconv_pad_rows_kernel(const float* __restrict__ w,
                                                             ushort_t* __restrict__ o,
                                                             int rows, int K) {
    int idx = blockIdx.x * 256 + threadIdx.x;
    int r = idx / K, k = idx - r * K;
    o[idx] = (r < rows) ? f2bf(w[(size_t)r * K + k]) : (ushort_t)0;
}
__global__ __launch_bounds__(256) void wconv_pad_cols_kernel(const float* __restrict__ w,
                                                             ushort_t* __restrict__ o,
                                                             int K, int Kp) {
    int idx = blockIdx.x * 256 + threadIdx.x;
    int r = idx / Kp, k = idx - r * Kp;
    o[idx] = (k < K) ? f2bf(w[(size_t)r * K + k]) : (ushort_t)0;
}

// Zero a small f32 buffer (for ssq atomics).
__global__ __launch_bounds__(256) void zero_f32_kernel(float* __restrict__ p, int n) {
    int i = blockIdx.x * 256 + threadIdx.x;
    if (i < n) p[i] = 0.f;
}

// ---------------------------------------------------------------------------
// bf16 MFMA GEMM v2: out[b,co,p] = sum_ci W[co,ci] * Z[b,ci,p]
// ---------------------------------------------------------------------------
__global__ __launch_bounds__(256) void gemm_bf16_kernel(const ushort_t* __restrict__ Zh,
                                                        const ushort_t* __restrict__ Wh,
                                                        const float* __restrict__ bias,
                                                        const float* __restrict__ res,
                                                        float* outf,
                                                        ushort_t* outh,
                                                        int Cin, int Kpad, int Mreal,
                                                        int act) {
    const int b    = blockIdx.z;
    const int px0  = blockIdx.x * 128;
    const int co0  = blockIdx.y * 64;
    const int tid  = threadIdx.x;
    const int wv   = tid >> 6;
    const int lane = tid & 63;
    const int n    = lane & 15;
    const int q    = lane >> 4;

    __shared__ ushort_t Bl[128][40];

    const ushort_t* Zb = Zh + (size_t)b * Cin * Nn;

    f32x4 acc[4][2];
    #pragma unroll
    for (int i = 0; i < 4; ++i)
        #pragma unroll
        for (int j = 0; j < 2; ++j) acc[i][j] = (f32x4){0.f, 0.f, 0.f, 0.f};

    for (int k0 = 0; k0 < Kpad; k0 += 32) {
        {
            int r = tid >> 3;        // k row 0..31
            int s = tid & 7;         // 16-px chunk
            int ci = k0 + r;
            ushort_t tmp[16];
            if (ci < Cin) {
                const ushort_t* src = Zb + (size_t)ci * Nn + px0 + s * 16;
                uint4 v0 = *(const uint4*)src;
                uint4 v1 = *(const uint4*)(src + 8);
                tmp[0]  = (ushort_t)(v0.x & 0xFFFF); tmp[1]  = (ushort_t)(v0.x >> 16);
                tmp[2]  = (ushort_t)(v0.y & 0xFFFF); tmp[3]  = (ushort_t)(v0.y >> 16);
                tmp[4]  = (ushort_t)(v0.z & 0xFFFF); tmp[5]  = (ushort_t)(v0.z >> 16);
                tmp[6]  = (ushort_t)(v0.w & 0xFFFF); tmp[7]  = (ushort_t)(v0.w >> 16);
                tmp[8]  = (ushort_t)(v1.x & 0xFFFF); tmp[9]  = (ushort_t)(v1.x >> 16);
                tmp[10] = (ushort_t)(v1.y & 0xFFFF); tmp[11] = (ushort_t)(v1.y >> 16);
                tmp[12] = (ushort_t)(v1.z & 0xFFFF); tmp[13] = (ushort_t)(v1.z >> 16);
                tmp[14] = (ushort_t)(v1.w & 0xFFFF); tmp[15] = (ushort_t)(v1.w >> 16);
            } else {
                #pragma unroll
                for (int i = 0; i < 16; ++i) tmp[i] = 0;
            }
            #pragma unroll
            for (int i = 0; i < 16; ++i) Bl[s * 16 + i][r] = tmp[i];
        }
        __syncthreads();

        short8 bfrag[2];
        #pragma unroll
        for (int px16 = 0; px16 < 2; ++px16)
            bfrag[px16] = *(const short8*)&Bl[wv * 32 + px16 * 16 + n][q * 8];
        #pragma unroll
        for (int mt = 0; mt < 4; ++mt) {
            const ushort_t* wp = Wh + (size_t)(co0 + mt * 16 + n) * Kpad + k0 + q * 8;
            short8 afrag = *(const short8*)wp;
            #pragma unroll
            for (int px16 = 0; px16 < 2; ++px16)
                acc[mt][px16] = __builtin_amdgcn_mfma_f32_16x16x32_bf16(
                    afrag, bfrag[px16], acc[mt][px16], 0, 0, 0);
        }
        __syncthreads();
    }

    #pragma unroll
    for (int px16 = 0; px16 < 2; ++px16) {
        int px = px0 + wv * 32 + px16 * 16 + n;
        #pragma unroll
        for (int mt = 0; mt < 4; ++mt) {
            #pragma unroll
            for (int reg = 0; reg < 4; ++reg) {
                int co = co0 + mt * 16 + q * 4 + reg;
                if (co < Mreal) {
                    float v = acc[mt][px16][reg];
                    if (bias) v += bias[co];
                    if (act == 1) v = fmaxf(v, 0.f);
                    size_t o = ((size_t)b * Mreal + co) * Nn + px;
                    if (res)  v += res[o];
                    if (outf) outf[o] = v;
                    if (outh) outh[o] = f2bf(v);
                }
            }
        }
    }
}

// ---------------------------------------------------------------------------
// Vectorized f32 1x1 conv (tier-2 only).
// ---------------------------------------------------------------------------
template <int TCO>
__global__ __launch_bounds__(256) void conv1x1v_kernel(const float* __restrict__ in,
                                                       const float* __restrict__ wgt,
                                                       int wstride,
                                                       const float* __restrict__ bias,
                                                       const float* __restrict__ res,
                                                       float* __restrict__ out,
                                                       int Cin, int Cout, int act) {
    int pg  = blockIdx.x * 256 + threadIdx.x;
    int b   = blockIdx.z;
    int co0 = blockIdx.y * TCO;

    const float* wrow[TCO];
    #pragma unroll
    for (int i = 0; i < TCO; ++i) {
        int co = co0 + i; if (co > Cout - 1) co = Cout - 1;
        wrow[i] = wgt + (size_t)co * wstride;
    }

    float4 acc[TCO];
    #pragma unroll
    for (int i = 0; i < TCO; ++i) acc[i] = make_float4(0.f, 0.f, 0.f, 0.f);

    const float* ib = in + (size_t)b * Cin * Nn + (size_t)pg * 4;
    #pragma unroll 8
    for (int ci = 0; ci < Cin; ++ci) {
        float4 v = *(const float4*)(ib + (size_t)ci * Nn);
        #pragma unroll
        for (int i = 0; i < TCO; ++i) {
            float w = wrow[i][ci];
            acc[i].x += v.x * w; acc[i].y += v.y * w;
            acc[i].z += v.z * w; acc[i].w += v.w * w;
        }
    }

    #pragma unroll
    for (int i = 0; i < TCO; ++i) {
        int co = co0 + i;
        if (co < Cout) {
            float4 r = acc[i];
            if (bias) { float bb = bias[co]; r.x += bb; r.y += bb; r.z += bb; r.w += bb; }
            if (act == 1) {
                r.x = fmaxf(r.x, 0.f); r.y = fmaxf(r.y, 0.f);
                r.z = fmaxf(r.z, 0.f); r.w = fmaxf(r.w, 0.f);
            }
            size_t o = ((size_t)b * Cout + co) * Nn + (size_t)pg * 4;
            if (res) {
                float4 rv = *(const float4*)(res + o);
                r.x += rv.x; r.y += rv.y; r.z += rv.z; r.w += rv.w;
            }
            *(float4*)(out + o) = r;
        }
    }
}

// ---------------------------------------------------------------------------
// Depthwise 3x3 f32 (tier-2).
// ---------------------------------------------------------------------------
__global__ __launch_bounds__(256) void dw3x3_kernel(const float* __restrict__ in,
                                                    const float* __restrict__ w,
                                                    float* __restrict__ out, int Ct) {
    int p = blockIdx.x * 256 + threadIdx.x;
    int c = blockIdx.y;
    int b = blockIdx.z;
    int y = p >> 7, x = p & (Wb - 1);
    const float* ib = in + ((size_t)b * Ct + c) * Nn;
    float wl[9];
    #pragma unroll
    for (int k = 0; k < 9; ++k) wl[k] = w[c * 9 + k];
    float acc = 0.f;
    #pragma unroll
    for (int dy = 0; dy < 3; ++dy) {
        int yy = y + dy - 1;
        if (yy < 0 || yy >= Hh) continue;
        #pragma unroll
        for (int dx = 0; dx < 3; ++dx) {
            int xx = x + dx - 1;
            if (xx < 0 || xx >= Wb) continue;
            acc += wl[dy * 3 + dx] * ib[yy * Wb + xx];
        }
    }
    out[((size_t)b * Ct + c) * Nn + p] = acc;
}

// ---------------------------------------------------------------------------
// Depthwise 3x3 bf16-in/BF16-OUT v5: conflict-free 4-px-per-lane LDS pattern,
// packed bf16 stores, barrier-free ssq from the f32 accumulator.
// grid: (Hh/16, Ct, Bt), block 256. LDS 10880 B.
// ---------------------------------------------------------------------------
__global__ __launch_bounds__(256) void dw3x3_bf16_v5_kernel(const ushort_t* __restrict__ in,
                                                            const float* __restrict__ w,
                                                            ushort_t* __restrict__ out, int Ct,
                                                            float* __restrict__ ssq,
                                                            int nrmC) {
    const int gy0 = blockIdx.x * 16;
    const int c   = blockIdx.y;
    const int b   = blockIdx.z;
    const int tid = threadIdx.x;

    __shared__ float ts[20][136];

    const ushort_t* ib = in + ((size_t)b * Ct + c) * Nn;
    iel7_stage(ts, ib, gy0, tid);
    __syncthreads();

    float wl[9];
    #pragma unroll
    for (int k = 0; k < 9; ++k) wl[k] = w[c * 9 + k];

    ushort_t* ob = out + ((size_t)b * Ct + c) * Nn;
    float s2sum = 0.f;
    #pragma unroll
    for (int it = 0; it < 2; ++it) {
        int idx = tid + it * 256;
        int r = idx >> 5;            // 0..15
        int s = idx & 31;            // 4-px strip
        float a[4] = {0.f, 0.f, 0.f, 0.f};
        #pragma unroll
        for (int dy = 0; dy < 3; ++dy) {
            const float* row = &ts[r + 1 + dy][4 * s];
            float4 e0 = *(const float4*)row;
            float4 e1 = *(const float4*)(row + 4);
            float4 e2 = *(const float4*)(row + 8);
            float e[12] = {e0.x, e0.y, e0.z, e0.w, e1.x, e1.y, e1.z, e1.w,
                           e2.x, e2.y, e2.z, e2.w};
            float w0 = wl[dy * 3], w1 = wl[dy * 3 + 1], w2 = wl[dy * 3 + 2];
            #pragma unroll
            for (int p = 0; p < 4; ++p)
                a[p] += w0 * e[p + 3] + w1 * e[p + 4] + w2 * e[p + 5];
        }
        uint2 pk;
        pk.x = (unsigned)f2bf(a[0]) | ((unsigned)f2bf(a[1]) << 16);
        pk.y = (unsigned)f2bf(a[2]) | ((unsigned)f2bf(a[3]) << 16);
        *(uint2*)(ob + (gy0 + r) * Wb + 4 * s) = pk;
        s2sum += a[0] * a[0] + a[1] * a[1] + a[2] * a[2] + a[3] * a[3];
    }

    if (ssq != nullptr && c < nrmC) {
        #pragma unroll
        for (int o = 32; o > 0; o >>= 1) s2sum += __shfl_xor(s2sum, o, 64);
        if ((tid & 63) == 0) atomicAdd(&ssq[(size_t)b * nrmC + c], s2sum);
    }
}

// ---------------------------------------------------------------------------
// L2 normalize along N (in-place, tier-2). grid: (Cc, 1, Bt).
// ---------------------------------------------------------------------------
__global__ __launch_bounds__(256) void l2norm_kernel(float* __restrict__ data, int cstride) {
    int b = blockIdx.z, c = blockIdx.x;
    float* ptr = data + ((size_t)b * cstride + c) * Nn;
    int t = threadIdx.x;
    float s = 0.f;
    for (int i = t; i < Nn; i += 256) { float v = ptr[i]; s += v * v; }
    __shared__ float red[256];
    red[t] = s; __syncthreads();
    for (int st = 128; st > 0; st >>= 1) { if (t < st) red[t] += red[t + st]; __syncthreads(); }
    float scale = 1.0f / fmaxf(sqrtf(red[0]), 1e-12f);
    for (int i = t; i < Nn; i += 256) ptr[i] *= scale;
}

// ---------------------------------------------------------------------------
// Gate stage 2 + final.
// ---------------------------------------------------------------------------
__global__ __launch_bounds__(256) void gate2_kernel(const float* __restrict__ gmid,
                                                    const float* __restrict__ w2,
                                                    const float* __restrict__ b2,
                                                    float* __restrict__ blocksums,
                                                    int out_off) {
    int p = blockIdx.x * 256 + threadIdx.x;
    int b = blockIdx.z;
    float acc = b2[0];
    const float* ib = gmid + (size_t)b * 64 * Nn + p;
    #pragma unroll 8
    for (int ci = 0; ci < 64; ++ci) acc += ib[(size_t)ci * Nn] * w2[ci];
    float g = 1.0f / (1.0f + expf(-acc));
    __shared__ float red[256];
    int t = threadIdx.x;
    red[t] = g; __syncthreads();
    for (int st = 128; st > 0; st >>= 1) { if (t < st) red[t] += red[t + st]; __syncthreads(); }
    if (t == 0) blocksums[out_off + b * 64 + blockIdx.x] = red[0];
}

__global__ void gate_final_kernel(const float* __restrict__ blocksums,
                                  int* __restrict__ dk_out) {
    __shared__ double sred[256];
    int t = threadIdx.x;
    sred[t] = (double)blocksums[t];
    __syncthreads();
    for (int st = 128; st > 0; st >>= 1) { if (t < st) sred[t] += sred[t + st]; __syncthreads(); }
    if (t == 0) {
        double mean = sred[0] / (double)(Bn * Nn);
        float val = 16.0f * (float)mean;
        int dk = (int)val;
        if (dk < 1) dk = 1;
        if (dk > 16) dk = 16;
        *dk_out = dk;
    }
}

// ---------------------------------------------------------------------------
// QK^T partial, f32 in (tier-2). grid: (NS, HEADS, Bt).
// ---------------------------------------------------------------------------
__global__ __launch_bounds__(256) void attn_qk_partial_kernel(const float* __restrict__ q,
                                                              const float* __restrict__ k,
                                                              int kstride,
                                                              float* __restrict__ partial) {
    int ns = blockIdx.x, h = blockIdx.y, b = blockIdx.z;
    int t = threadIdx.x;
    int c = t >> 4, d = t & 15;
    __shared__ float qs[16][65];
    __shared__ float ks[16][65];
    const float* qb = q + ((size_t)b * Cc + h * CHh) * Nn;
    const float* kb = k + ((size_t)b * kstride + h * CHh) * Nn;
    float acc = 0.f;
    int nbeg = ns * (Nn / NS);
    for (int n0 = nbeg; n0 < nbeg + (Nn / NS); n0 += 64) {
        for (int idx = t; idx < 1024; idx += 256) {
            int r = idx >> 6, col = idx & 63;
            qs[r][col] = qb[(size_t)r * Nn + n0 + col];
            ks[r][col] = kb[(size_t)r * Nn + n0 + col];
        }
        __syncthreads();
        #pragma unroll
        for (int j = 0; j < 64; ++j) acc += qs[c][j] * ks[d][j];
        __syncthreads();
    }
    partial[(((size_t)(b * HEADS + h)) * NS + ns) * 256 + t] = acc;
}

// QK^T partial, bf16 in (tier-1). Same structure; f32 LDS + f32 accumulate.
__global__ __launch_bounds__(256) void attn_qk_partial_h_kernel(const ushort_t* __restrict__ q,
                                                                const ushort_t* __restrict__ k,
                                                                int kstride,
                                                                float* __restrict__ partial) {
    int ns = blockIdx.x, h = blockIdx.y, b = blockIdx.z;
    int t = threadIdx.x;
    int c = t >> 4, d = t & 15;
    __shared__ float qs[16][65];
    __shared__ float ks[16][65];
    const ushort_t* qb = q + ((size_t)b * Cc + h * CHh) * Nn;
    const ushort_t* kb = k + ((size_t)b * kstride + h * CHh) * Nn;
    float acc = 0.f;
    int nbeg = ns * (Nn / NS);
    for (int n0 = nbeg; n0 < nbeg + (Nn / NS); n0 += 64) {
        for (int idx = t; idx < 1024; idx += 256) {
            int r = idx >> 6, col = idx & 63;
            qs[r][col] = bf2f(qb[(size_t)r * Nn + n0 + col]);
            ks[r][col] = bf2f(kb[(size_t)r * Nn + n0 + col]);
        }
        __syncthreads();
        #pragma unroll
        for (int j = 0; j < 64; ++j) acc += qs[c][j] * ks[d][j];
        __syncthreads();
    }
    partial[(((size_t)(b * HEADS + h)) * NS + ns) * 256 + t] = acc;
}

// reduce + temperature + (optional) fused L2-norm scaling.
__global__ __launch_bounds__(256) void attn_reduce_kernel(const float* __restrict__ partial,
                                                          const float* __restrict__ temp,
                                                          const float* __restrict__ qss,
                                                          const float* __restrict__ kss,
                                                          float* __restrict__ attnp) {
    int bh = blockIdx.x;
    int h = bh % HEADS;
    int t = threadIdx.x;
    const float* pp = partial + (size_t)bh * NS * 256 + t;
    float s = 0.f;
    #pragma unroll 8
    for (int ns = 0; ns < NS; ++ns) s += pp[(size_t)ns * 256];
    float scale = temp[h];
    if (qss != nullptr) {
        int b  = bh / HEADS;
        int cQ = h * CHh + (t >> 4);
        int cK = h * CHh + (t & 15);
        float nq = fmaxf(sqrtf(qss[(size_t)b * Cc + cQ]), 1e-12f);
        float nk = fmaxf(sqrtf(kss[(size_t)b * Cc + cK]), 1e-12f);
        scale = scale / (nq * nk);
    }
    attnp[(size_t)bh * 256 + t] = s * scale;
}

__global__ void topk_softmax_kernel(float* __restrict__ attnp, const int* __restrict__ dkp) {
    int bh = blockIdx.x;
    int c = threadIdx.x;
    if (c >= 16) return;
    float* row = attnp + ((size_t)bh * CHh + c) * CHh;
    float a[16];
    #pragma unroll
    for (int d = 0; d < 16; ++d) a[d] = row[d];
    int dk = *dkp;
    unsigned keep = 0;
    float m = -INFINITY;
    #pragma unroll
    for (int d = 0; d < 16; ++d) {
        int rank = 0;
        #pragma unroll
        for (int j = 0; j < 16; ++j)
            rank += (a[j] > a[d]) || (a[j] == a[d] && j < d);
        if (rank < dk) { keep |= (1u << d); m = fmaxf(m, a[d]); }
    }
    float e[16]; float s = 0.f;
    #pragma unroll
    for (int d = 0; d < 16; ++d) {
        e[d] = (keep >> d & 1u) ? expf(a[d] - m) : 0.f;
        s += e[d];
    }
    float invs = 1.0f / s;
    #pragma unroll
    for (int d = 0; d < 16; ++d) row[d] = e[d] * invs;
}

// attn_v: f32 out (tier-2)
__global__ __launch_bounds__(256) void attn_v_kernel(const float* __restrict__ attnp,
                                                     const float* __restrict__ v,
                                                     float* __restrict__ out) {
    int p = blockIdx.x * 256 + threadIdx.x;
    int cg = blockIdx.y;
    int b = blockIdx.z;
    int h = cg >> 4, cr = cg & 15;
    const float* arow = attnp + (((size_t)b * HEADS + h) * CHh + cr) * CHh;
    const float* vb = v + ((size_t)b * Cc + h * CHh) * Nn + p;
    float acc = 0.f;
    #pragma unroll
    for (int d = 0; d < 16; ++d) acc += arow[d] * vb[(size_t)d * Nn];
    out[((size_t)b * Cc + cg) * Nn + p] = acc;
}

// attn_v v2: bf16 in, bf16 out, 2 px per thread (uint loads/stores).
// grid: (Nn/512, Cc, Bt), block 256.
__global__ __launch_bounds__(256) void attn_v_bf16_v2_kernel(const float* __restrict__ attnp,
                                                             const ushort_t* __restrict__ v,
                                                             int vstride, int voff,
                                                             ushort_t* __restrict__ out) {
    int p2 = blockIdx.x * 256 + threadIdx.x;   // pair index
    int px = p2 * 2;
    int cg = blockIdx.y;
    int b = blockIdx.z;
    int h = cg >> 4, cr = cg & 15;
    const float* arow = attnp + (((size_t)b * HEADS + h) * CHh + cr) * CHh;
    const ushort_t* vb = v + ((size_t)b * vstride + voff + h * CHh) * Nn + px;
    float a0 = 0.f, a1 = 0.f;
    #pragma unroll
    for (int d = 0; d < 16; ++d) {
        unsigned u = *(const unsigned*)(vb + (size_t)d * Nn);
        float w = arow[d];
        a0 += w * bf2f((ushort_t)(u & 0xFFFF));
        a1 += w * bf2f((ushort_t)(u >> 16));
    }
    unsigned pk = (unsigned)f2bf(a0) | ((unsigned)f2bf(a1) << 16);
    *(unsigned*)(out + ((size_t)b * Cc + cg) * Nn + px) = pk;
}

// ---------------------------------------------------------------------------
// Fused IEL tail v4 + fast_tanh (proven structure).
// ts col j <-> gx = j-1 (j 0..129 valid; j=0 & 129 zero). stride 132.
// grid: (Hh/16, HID, Bt), block 256. LDS ~40 KB.
// ---------------------------------------------------------------------------
__global__ __launch_bounds__(256) void iel_tail_v4_kernel(const ushort_t* __restrict__ Th,
                                                          const float* __restrict__ dww,
                                                          const float* __restrict__ dw1p,
                                                          const float* __restrict__ dw2p,
                                                          ushort_t* __restrict__ PRh) {
    const int gy0 = blockIdx.x * 16;
    const int c   = blockIdx.y;
    const int b   = blockIdx.z;
    const int tid = threadIdx.x;

    __shared__ float ts[2][20][132];
    __shared__ float us[2][18][132];

    const ushort_t* t1 = Th + ((size_t)b * HID2 + c) * Nn;
    const ushort_t* t2 = Th + ((size_t)b * HID2 + HID + c) * Nn;

    // stage: 2 tensors x 20 rows x 16 segs of 8 px. ts[j] with j = gx+1.
    for (int idx = tid; idx < 640; idx += 256) {
        int ti  = idx / 320;
        int rem = idx - ti * 320;
        int i   = rem >> 4;
        int seg = rem & 15;
        int gy  = gy0 - 2 + i;
        const ushort_t* tp = ti ? t2 : t1;
        float vals[8];
        if (gy >= 0 && gy < Hh) {
            uint4 v = *(const uint4*)(tp + gy * Wb + seg * 8);
            vals[0] = bf2f((ushort_t)(v.x & 0xFFFF)); vals[1] = bf2f((ushort_t)(v.x >> 16));
            vals[2] = bf2f((ushort_t)(v.y & 0xFFFF)); vals[3] = bf2f((ushort_t)(v.y >> 16));
            vals[4] = bf2f((ushort_t)(v.z & 0xFFFF)); vals[5] = bf2f((ushort_t)(v.z >> 16));
            vals[6] = bf2f((ushort_t)(v.w & 0xFFFF)); vals[7] = bf2f((ushort_t)(v.w >> 16));
        } else {
            #pragma unroll
            for (int k = 0; k < 8; ++k) vals[k] = 0.f;
        }
        #pragma unroll
        for (int k = 0; k < 8; ++k) ts[ti][i][1 + seg * 8 + k] = vals[k];
        if (seg == 0)  ts[ti][i][0] = 0.f;
        if (seg == 15) { ts[ti][i][129] = 0.f; ts[ti][i][130] = 0.f; ts[ti][i][131] = 0.f; }
    }
    __syncthreads();

    float wA[9], wB[9], w1[9], w2[9];
    #pragma unroll
    for (int k = 0; k < 9; ++k) {
        wA[k] = dww[c * 9 + k];
        wB[k] = dww[(HID + c) * 9 + k];
        w1[k] = dw1p[c * 9 + k];
        w2[k] = dw2p[c * 9 + k];
    }

    // u-stage: 1152 strips (2 tensors x 18 rows x 32 strips of 4).
    for (int idx = tid; idx < 1152; idx += 256) {
        int ti  = idx / 576;
        int rem = idx - ti * 576;
        int i   = rem >> 5;          // row 0..17, gy = gy0-1+i
        int s   = rem & 31;          // strip, outputs j = 1+4s .. 4+4s
        int gy  = gy0 - 1 + i;
        float o0 = 0.f, o1 = 0.f, o2 = 0.f, o3 = 0.f;
        if (gy >= 0 && gy < Hh) {
            const float* wp = ti ? wB : wA;
            #pragma unroll
            for (int dy = 0; dy < 3; ++dy) {
                const float* row = &ts[ti][i + dy][4 * s];
                float4 a = *(const float4*)row;          // j0-1..j0+2
                float2 bb = *(const float2*)(row + 4);   // j0+3, j0+4
                float w0 = wp[dy * 3 + 0], w1t = wp[dy * 3 + 1], w2t = wp[dy * 3 + 2];
                o0 += w0 * a.x + w1t * a.y + w2t * a.z;
                o1 += w0 * a.y + w1t * a.z + w2t * a.w;
                o2 += w0 * a.z + w1t * a.w + w2t * bb.x;
                o3 += w0 * a.w + w1t * bb.x + w2t * bb.y;
            }
        }
        int j0 = 1 + 4 * s;
        us[ti][i][j0]     = o0;
        us[ti][i][j0 + 1] = o1;
        us[ti][i][j0 + 2] = o2;
        us[ti][i][j0 + 3] = o3;
    }
    // edge zeros: us[ti][i][0] and us[ti][i][129]
    if (tid < 72) {
        int ti = tid / 36;
        int r  = tid - ti * 36;
        int i  = r >> 1;
        us[ti][i][(r & 1) ? 129 : 0] = 0.f;
    }
    __syncthreads();

    // final: 512 strips (16 rows x 32 strips of 4 px).
    ushort_t* outp = PRh + ((size_t)b * HID + c) * Nn;
    for (int idx = tid; idx < 512; idx += 256) {
        int r  = idx >> 5;           // tile row, gy = gy0 + r
        int s  = idx & 31;
        int x0 = 4 * s;
        float s1a[4] = {0.f, 0.f, 0.f, 0.f};
        float s2a[4] = {0.f, 0.f, 0.f, 0.f};
        float c1a[4], c2a[4];
        #pragma unroll
        for (int dy = 0; dy < 3; ++dy) {
            const float* r0 = &us[0][r + dy][x0];
            float4 a0 = *(const float4*)r0;
            float2 b0 = *(const float2*)(r0 + 4);
            const float* r1 = &us[1][r + dy][x0];
            float4 a1 = *(const float4*)r1;
            float2 b1 = *(const float2*)(r1 + 4);
            float w10 = w1[dy * 3], w11 = w1[dy * 3 + 1], w12 = w1[dy * 3 + 2];
            float w20 = w2[dy * 3], w21 = w2[dy * 3 + 1], w22 = w2[dy * 3 + 2];
            s1a[0] += w10 * a0.x + w11 * a0.y + w12 * a0.z;
            s1a[1] += w10 * a0.y + w11 * a0.z + w12 * a0.w;
            s1a[2] += w10 * a0.z + w11 * a0.w + w12 * b0.x;
            s1a[3] += w10 * a0.w + w11 * b0.x + w12 * b0.y;
            s2a[0] += w20 * a1.x + w21 * a1.y + w22 * a1.z;
            s2a[1] += w20 * a1.y + w21 * a1.z + w22 * a1.w;
            s2a[2] += w20 * a1.z + w21 * a1.w + w22 * b1.x;
            s2a[3] += w20 * a1.w + w21 * b1.x + w22 * b1.y;
            if (dy == 1) {
                c1a[0] = a0.y; c1a[1] = a0.z; c1a[2] = a0.w; c1a[3] = b0.x;
                c2a[0] = a1.y; c2a[1] = a1.z; c2a[2] = a1.w; c2a[3] = b1.x;
            }
        }
        uint2 pk;
        float v0 = (fast_tanh(s1a[0]) + c1a[0]) * (fast_tanh(s2a[0]) + c2a[0]);
        float v1 = (fast_tanh(s1a[1]) + c1a[1]) * (fast_tanh(s2a[1]) + c2a[1]);
        float v2 = (fast_tanh(s1a[2]) + c1a[2]) * (fast_tanh(s2a[2]) + c2a[2]);
        float v3 = (fast_tanh(s1a[3]) + c1a[3]) * (fast_tanh(s2a[3]) + c2a[3]);
        pk.x = (unsigned)f2bf(v0) | ((unsigned)f2bf(v1) << 16);
        pk.y = (unsigned)f2bf(v2) | ((unsigned)f2bf(v3) << 16);
        *(uint2*)(outp + (gy0 + r) * Wb + x0) = pk;
    }
}

// f32 IEL tail (tier-2 fallback; per-chunk layout).
__global__ __launch_bounds__(256) void iel_tail_f32_kernel(const float* __restrict__ t1p,
                                                           const float* __restrict__ t2p,
                                                           const float* __restrict__ dwA,
                                                           const float* __restrict__ dwB,
                                                           const float* __restrict__ dw1p,
                                                           const float* __restrict__ dw2p,
                                                           float* __restrict__ prod) {
    const int c = blockIdx.y;
    const int tilesx = Wb / 16;
    const int ty0 = (blockIdx.x / tilesx) * 16;
    const int tx0 = (blockIdx.x % tilesx) * 16;
    const int tid = threadIdx.x;

    __shared__ float ts[2][20][24];
    __shared__ float us[2][18][24];

    const float* t1 = t1p + (size_t)c * Nn;
    const float* t2 = t2p + (size_t)c * Nn;

    for (int idx = tid; idx < 400; idx += 256) {
        int i = idx / 20, j = idx % 20;
        int gy = ty0 - 2 + i, gx = tx0 - 2 + j;
        bool ok = (gy >= 0 && gy < Hh && gx >= 0 && gx < Wb);
        ts[0][i][j] = ok ? t1[gy * Wb + gx] : 0.f;
        ts[1][i][j] = ok ? t2[gy * Wb + gx] : 0.f;
    }
    __syncthreads();

    float wA[9], wB[9], w1[9], w2[9];
    #pragma unroll
    for (int k = 0; k < 9; ++k) {
        wA[k] = dwA[c * 9 + k];
        wB[k] = dwB[c * 9 + k];
        w1[k] = dw1p[c * 9 + k];
        w2[k] = dw2p[c * 9 + k];
    }

    for (int idx = tid; idx < 324; idx += 256) {
        int i = idx / 18, j = idx % 18;
        int gy = ty0 - 1 + i, gx = tx0 - 1 + j;
        float a0 = 0.f, a1 = 0.f;
        if (gy >= 0 && gy < Hh && gx >= 0 && gx < Wb) {
            #pragma unroll
            for (int dy = 0; dy < 3; ++dy)
                #pragma unroll
                for (int dx = 0; dx < 3; ++dx) {
                    a0 += wA[dy * 3 + dx] * ts[0][i + dy][j + dx];
                    a1 += wB[dy * 3 + dx] * ts[1][i + dy][j + dx];
                }
        }
        us[0][i][j] = a0;
        us[1][i][j] = a1;
    }
    __syncthreads();

    int ty = tid >> 4, tx = tid & 15;
    float c1 = us[0][ty + 1][tx + 1];
    float c2 = us[1][ty + 1][tx + 1];
    float s1 = 0.f, s2 = 0.f;
    #pragma unroll
    for (int dy = 0; dy < 3; ++dy)
        #pragma unroll
        for (int dx = 0; dx < 3; ++dx) {
            s1 += w1[dy * 3 + dx] * us[0][ty + dy][tx + dx];
            s2 += w2[dy * 3 + dx] * us[1][ty + dy][tx + dx];
        }
    float x1t = tanhf(s1) + c1;
    float x2t = tanhf(s2) + c2;
    prod[(size_t)c * Nn + (ty0 + ty) * Wb + (tx0 + tx)] = x1t * x2t;
}

// ---------------------------------------------------------------------------
// Host launcher
// ---------------------------------------------------------------------------
extern "C" void kernel_launch(void* const* d_in, const int* in_sizes, int n_in,
                              void* d_out, int out_size, void* d_ws, size_t ws_size,
                              hipStream_t stream) {
    const float* x      = (const float*)d_in[0];
    const float* y      = (const float*)d_in[1];
    const float* ln_w   = (const float*)d_in[2];
    const float* ln_b   = (const float*)d_in[3];
    const float* temp   = (const float*)d_in[4];
    const float* q_w    = (const float*)d_in[5];
    const float* qdw_w  = (const float*)d_in[6];
    const float* kv_w   = (const float*)d_in[7];
    const float* kvdw_w = (const float*)d_in[8];
    const float* po_w   = (const float*)d_in[9];
    const float* g1_w   = (const float*)d_in[10];
    const float* g1_b   = (const float*)d_in[11];
    const float* g2_w   = (const float*)d_in[12];
    const float* g2_b   = (const float*)d_in[13];
    const float* pin_w  = (const float*)d_in[14];
    const float* dw_w   = (const float*)d_in[15];
    const float* dw1_w  = (const float*)d_in[16];
    const float* dw2_w  = (const float*)d_in[17];
    const float* pout_w = (const float*)d_in[18];
    float* out = (float*)d_out;

    // smalls in first 1 MiB
    char* ws = (char*)d_ws;
    float* attn      = (float*)ws;                        // 32 KB
    float* blocksums = (float*)(ws + 32768);              // 1 KB
    int*   dk        = (int*)(ws + 33792);
    ushort_t* qWh  = (ushort_t*)(ws + 34816);             // 128x128
    ushort_t* kvWh = qWh + 16384;                         // 256x128
    ushort_t* poWh = kvWh + 32768;                        // 128x128
    ushort_t* g1Wh = poWh + 16384;                        // 64x128
    ushort_t* Wh1  = g1Wh + 8192;                         // 704x128
    ushort_t* Wh2  = Wh1 + (size_t)MPAD * Cc;             // 128x352
    float* qss = (float*)(ws + 458752);                   // [Bn][128] sumsq(q)
    float* kss = (float*)(ws + 460800);                   // [Bn][128] sumsq(k)
    float* pool    = (float*)(ws + (1u << 20));

    const size_t CN    = (size_t)Cc * Nn;
    const size_t SLOT1 = (size_t)Bn * CN;
    const size_t TIER1_NEED = 65536 + 6 * SLOT1 * 4;

    dim3 blk(256);
    const int PGX = Nn / 1024;

    if (ws_size >= TIER1_NEED) {
        // ---- buffers ----
        ushort_t* S3h = (ushort_t*)pool;                   // q2 bf16 [B][128][Nn]
        ushort_t* S4h = (ushort_t*)(pool + 8 * 1024 * 1024); // k2+v2 bf16 [B][256][Nn]
        ushort_t* XNh  = (ushort_t*)(pool + 24 * 1024 * 1024);
        ushort_t* YNh  = XNh + Bn * CN;
        ushort_t* KV1h = YNh + Bn * CN;
        ushort_t* Q1h  = KV1h + 2 * Bn * CN;
        float* gmid    = (float*)Q1h;
        float* partial = gmid;
        ushort_t* AOh  = XNh;

        wconv_pad_rows_kernel<<<dim3(64), blk, 0, stream>>>(q_w, qWh, 128, Cc);
        wconv_pad_rows_kernel<<<dim3(128), blk, 0, stream>>>(kv_w, kvWh, 256, Cc);
        wconv_pad_rows_kernel<<<dim3(64), blk, 0, stream>>>(po_w, poWh, 128, Cc);
        wconv_pad_rows_kernel<<<dim3(32), blk, 0, stream>>>(g1_w, g1Wh, 64, Cc);
        wconv_pad_rows_kernel<<<dim3(MPAD * Cc / 256), blk, 0, stream>>>(pin_w, Wh1, HID2, Cc);
        wconv_pad_cols_kernel<<<dim3(Cc * KPAD2 / 256), blk, 0, stream>>>(pout_w, Wh2, HID, KPAD2);
        zero_f32_kernel<<<dim3(4), blk, 0, stream>>>(qss, 2 * Bn * Cc);  // qss+kss contiguous

        // ---- Phase A ----
        ln_bf16_v2_kernel<<<dim3(Nn / 256, 1, Bn), blk, 0, stream>>>(x, ln_w, ln_b, XNh);
        ln_bf16_v2_kernel<<<dim3(Nn / 256, 1, Bn), blk, 0, stream>>>(y, ln_w, ln_b, YNh);

        gemm_bf16_kernel<<<dim3(Nn / 128, 2, Bn), blk, 0, stream>>>(
            XNh, qWh, nullptr, nullptr, nullptr, Q1h, Cc, Cc, Cc, 0);
        dw3x3_bf16_v5_kernel<<<dim3(Hh / 16, Cc, Bn), blk, 0, stream>>>(
            Q1h, qdw_w, S3h, Cc, qss, Cc);

        gemm_bf16_kernel<<<dim3(Nn / 128, 4, Bn), blk, 0, stream>>>(
            YNh, kvWh, nullptr, nullptr, nullptr, KV1h, Cc, Cc, 2 * Cc, 0);
        dw3x3_bf16_v5_kernel<<<dim3(Hh / 16, 2 * Cc, Bn), blk, 0, stream>>>(
            KV1h, kvdw_w, S4h, 2 * Cc, kss, Cc);

        gemm_bf16_kernel<<<dim3(Nn / 128, 1, Bn), blk, 0, stream>>>(
            XNh, g1Wh, g1_b, nullptr, gmid, nullptr, Cc, Cc, 64, 1);
        gate2_kernel<<<dim3(Nn / 256, 1, Bn), blk, 0, stream>>>(gmid, g2_w, g2_b, blocksums, 0);
        gate_final_kernel<<<dim3(1), blk, 0, stream>>>(blocksums, dk);

        // L2 norms folded into attn_reduce via qss/kss (no l2norm passes).
        attn_qk_partial_h_kernel<<<dim3(NS, HEADS, Bn), blk, 0, stream>>>(
            S3h, S4h, 2 * Cc, partial);
        attn_reduce_kernel<<<dim3(Bn * HEADS), blk, 0, stream>>>(partial, temp, qss, kss, attn);
        topk_softmax_kernel<<<dim3(Bn * HEADS), dim3(16), 0, stream>>>(attn, dk);
        attn_v_bf16_v2_kernel<<<dim3(Nn / 512, Cc, Bn), blk, 0, stream>>>(
            attn, S4h, 2 * Cc, Cc, AOh);

        gemm_bf16_kernel<<<dim3(Nn / 128, 2, Bn), blk, 0, stream>>>(
            AOh, poWh, nullptr, x, out, nullptr, Cc, Cc, Cc, 0);

        // ---- Phase B ----
        ushort_t* ZNh = (ushort_t*)pool;
        ushort_t* Th  = ZNh + Bn * CN;
        ushort_t* PRh = Th + (size_t)Bn * HID2 * Nn;

        ln_bf16_v2_kernel<<<dim3(Nn / 256, 1, Bn), blk, 0, stream>>>(out, ln_w, ln_b, ZNh);

        gemm_bf16_kernel<<<dim3(Nn / 128, MPAD / 64, Bn), blk, 0, stream>>>(
            ZNh, Wh1, nullptr, nullptr, nullptr, Th, Cc, Cc, HID2, 0);

        iel_tail_v4_kernel<<<dim3(Hh / 16, HID, Bn), blk, 0, stream>>>(
            Th, dw_w, dw1_w, dw2_w, PRh);

        gemm_bf16_kernel<<<dim3(Nn / 128, 2, Bn), blk, 0, stream>>>(
            PRh, Wh2, nullptr, out, out, nullptr, HID, KPAD2, Cc, 0);
    } else {
        // ================= Tier 2: per-batch f32 fallback ===================
        float* s0 = pool;
        float* s1 = pool + 1 * CN;
        float* s2 = pool + 2 * CN;
        float* s3 = pool + 3 * CN;
        float* s4 = pool + 4 * CN;
        float* s5 = pool + 5 * CN;

        for (int b = 0; b < Bn; ++b) {
            const float* xb = x + (size_t)b * CN;
            ln_kernel<<<dim3(Nn / 256, 1, 1), blk, 0, stream>>>(xb, ln_w, ln_b, s0);
            conv1x1v_kernel<4><<<dim3(PGX, 16, 1), blk, 0, stream>>>(
                s0, g1_w, Cc, g1_b, nullptr, s1, Cc, 64, 1);
            gate2_kernel<<<dim3(Nn / 256, 1, 1), blk, 0, stream>>>(
                s1, g2_w, g2_b, blocksums, b * 64);
        }
        gate_final_kernel<<<dim3(1), blk, 0, stream>>>(blocksums, dk);

        for (int b = 0; b < Bn; ++b) {
            const float* xb = x + (size_t)b * CN;
            const float* yb = y + (size_t)b * CN;
            float* outb = out + (size_t)b * CN;
            float* attnb = attn + (size_t)b * HEADS * CHh * CHh;

            ln_kernel<<<dim3(Nn / 256, 1, 1), blk, 0, stream>>>(xb, ln_w, ln_b, s0);
            ln_kernel<<<dim3(Nn / 256, 1, 1), blk, 0, stream>>>(yb, ln_w, ln_b, s1);

            conv1x1v_kernel<8><<<dim3(PGX, 16, 1), blk, 0, stream>>>(
                s0, q_w, Cc, nullptr, nullptr, s2, Cc, Cc, 0);
            dw3x3_kernel<<<dim3(Nn / 256, Cc, 1), blk, 0, stream>>>(s2, qdw_w, s3, Cc);
            l2norm_kernel<<<dim3(Cc, 1, 1), blk, 0, stream>>>(s3, Cc);

            conv1x1v_kernel<8><<<dim3(PGX, 16, 1), blk, 0, stream>>>(
                s1, kv_w, Cc, nullptr, nullptr, s2, Cc, Cc, 0);
            dw3x3_kernel<<<dim3(Nn / 256, Cc, 1), blk, 0, stream>>>(s2, kvdw_w, s4, Cc);
            l2norm_kernel<<<dim3(Cc, 1, 1), blk, 0, stream>>>(s4, Cc);

            conv1x1v_kernel<8><<<dim3(PGX, 16, 1), blk, 0, stream>>>(
                s1, kv_w + 128 * 128, Cc, nullptr, nullptr, s2, Cc, Cc, 0);
            dw3x3_kernel<<<dim3(Nn / 256, Cc, 1), blk, 0, stream>>>(s2, kvdw_w + 128 * 9, s5, Cc);

            attn_qk_partial_kernel<<<dim3(NS, HEADS, 1), blk, 0, stream>>>(s3, s4, Cc, s2);
            attn_reduce_kernel<<<dim3(HEADS), blk, 0, stream>>>(s2, temp, nullptr, nullptr, attnb);
            topk_softmax_kernel<<<dim3(HEADS), dim3(16), 0, stream>>>(attnb, dk);
            attn_v_kernel<<<dim3(Nn / 256, Cc, 1), blk, 0, stream>>>(attnb, s5, s2);

            conv1x1v_kernel<8><<<dim3(PGX, 16, 1), blk, 0, stream>>>(
                s2, po_w, Cc, nullptr, xb, outb, Cc, Cc, 0);
        }

        const int CHUNK = 170;
        const size_t TCH = (size_t)CHUNK * Nn;
        float* zn   = pool;
        float* T1   = pool + CN;
        float* T2   = T1 + TCH;
        float* prod = T2 + TCH;
        for (int b = 0; b < Bn; ++b) {
            float* outb = out + (size_t)b * CN;
            ln_kernel<<<dim3(Nn / 256, 1, 1), blk, 0, stream>>>(outb, ln_w, ln_b, zn);
            for (int c0 = 0; c0 < HID; c0 += CHUNK) {
                conv1x1v_kernel<20><<<dim3(PGX, 9, 1), blk, 0, stream>>>(
                    zn, pin_w + (size_t)c0 * Cc, Cc, nullptr, nullptr, T1, Cc, CHUNK, 0);
                conv1x1v_kernel<20><<<dim3(PGX, 9, 1), blk, 0, stream>>>(
                    zn, pin_w + (size_t)(HID + c0) * Cc, Cc, nullptr, nullptr, T2, Cc, CHUNK, 0);
                iel_tail_f32_kernel<<<dim3(64, CHUNK, 1), blk, 0, stream>>>(
                    T1, T2, dw_w + c0 * 9, dw_w + (HID + c0) * 9,
                    dw1_w + c0 * 9, dw2_w + c0 * 9, prod);
                conv1x1v_kernel<8><<<dim3(PGX, 16, 1), blk, 0, stream>>>(
                    prod, pout_w + c0, HID, nullptr, outb, outb, CHUNK, Cc, 0);
            }
        }
    }
}